// Round 1
// baseline (39484.854 us; speedup 1.0000x reference)
//
#include <hip/hip_runtime.h>

// BigARDecoder: persistent-kernel LSTM scan on MI355X.
// B=64, T=256, IN=256, H=1024, G=256, O=64, D=4, GO=320.
//
// Strategy: fuse adapter matmuls into cell weight matrices (precompute GEMMs
// once per launch, bf16 MFMA), then run the 255-step scan in ONE persistent
// kernel (84 workgroups) with 5 barrier-separated phases per step:
//   [in-cell], B1..B4 (inner cells, 1 GEMM each via W_eff), merged[out-cell(t)
//   + in-cell(t+1)].  Cross-WG state (h/c) moves via agent-scope relaxed
//   atomics (coherence-point), so weights stay L2/L3-cached.

typedef unsigned int u32;
typedef unsigned long long u64;
typedef unsigned short u16;
typedef __attribute__((ext_vector_type(8))) __bf16 bf16x8;
typedef __attribute__((ext_vector_type(4))) float f32x4;

#define DEVI __device__ __forceinline__

union FRAG { bf16x8 v; u16 s[8]; u64 q[2]; };
union P4 { u64 q; u16 s[4]; };
union F4 { u64 q[2]; float f[4]; };

DEVI u16 f2bf(float x){ u32 u = __float_as_uint(x); return (u16)((u + 0x7fffu + ((u>>16)&1u)) >> 16); }
DEVI float sigm(float x){ return 1.0f/(1.0f + __expf(-x)); }
DEVI float tanh_(float x){ return 2.0f/(1.0f + __expf(-2.0f*x)) - 1.0f; }
DEVI u64 ald(const void* p){ return __hip_atomic_load((const u64*)p, __ATOMIC_RELAXED, __HIP_MEMORY_SCOPE_AGENT); }
DEVI void ast(void* p, u64 v){ __hip_atomic_store((u64*)p, v, __ATOMIC_RELAXED, __HIP_MEMORY_SCOPE_AGENT); }

#define MFMA16(a,b,c) __builtin_amdgcn_mfma_f32_16x16x32_bf16(a, b, c, 0, 0, 0)

#define NWG 84

DEVI void gbar(u32* bar, int slot){
  __syncthreads();                      // compiler drains vm/lgkm before s_barrier
  if (threadIdx.x == 0){
    __hip_atomic_fetch_add(&bar[slot], 1u, __ATOMIC_RELEASE, __HIP_MEMORY_SCOPE_AGENT);
    while (__hip_atomic_load(&bar[slot], __ATOMIC_RELAXED, __HIP_MEMORY_SCOPE_AGENT) < (u32)NWG)
      __builtin_amdgcn_s_sleep(4);
    asm volatile("" ::: "memory");
  }
  __syncthreads();
}

// ---------------------------------------------------------------------------
// Persistent scan kernel. 84 WGs x 256 threads (4 waves = 4 b-tiles of 16).
// WGs 0..63: hidden-unit tiles (16 jj each). WGs 64..83: out-cell / ccA tiles.
// ---------------------------------------------------------------------------
__global__ __launch_bounds__(256, 1) void k_scan(
    const float* __restrict__ m_true,
    const u16* __restrict__ Wcell, const u16* __restrict__ Win_h,
    const u16* __restrict__ Win_x, const u16* __restrict__ Wout,
    const u16* __restrict__ WccA,
    const float* __restrict__ b_in, const float* __restrict__ b_cell,
    const float* __restrict__ cAb, const float* __restrict__ b_out,
    const float* __restrict__ b_cc,
    u16* hS, u16* cS, float* cF, float* ccB, float* outp, u32* bar)
{
  const int wg = blockIdx.x;
  const int tid = threadIdx.x;
  const int wave = tid >> 6, lane = tid & 63;
  const int bl = lane & 15, kg = lane >> 4;
  const int b = (wave << 4) + bl;          // batch row this lane owns in B-frags / D cols
  const int swz = (bl & 7) << 4;           // XOR swizzle (rows used are == bl mod 8)
  __shared__ u16 ldsW[20480];              // 40 KB: max tile 80 rows x 256 u16

  // stage: copy pre-swizzled blocked weight chunk (nseg x 1KB) global->LDS.
  auto stage = [&](const u16* src, int nseg){
    int ns = nseg >> 2;
    const u16* g = src + ((size_t)(wave*ns) << 9) + (lane << 3);
    u16* l = ldsW + ((size_t)(wave*ns) << 9) + (lane << 3);
    for (int s = 0; s < ns; ++s){
      FRAG t;
      t.q[0] = *(const u64*)g; t.q[1] = *(const u64*)(g + 4);
      *(bf16x8*)l = t.v;
      g += 512; l += 512;
    }
  };
  auto af512 = [&](int row, int kb) -> bf16x8 {   // A-frag, 512B rows
    return *(const bf16x8*)((const char*)ldsW + row*512 + (kb ^ swz));
  };
  auto af128 = [&](int row, int kb) -> bf16x8 {   // A-frag, 128B rows (x chunk1)
    return *(const bf16x8*)((const char*)ldsW + row*128 + (kb ^ swz));
  };

  // ---- in-cell phase (wg<64): gates = W_in_h@h + W_in_x@x_t + b; EW with c_prev=cF
  auto phase_incell = [&](int t, const u16* hIn, u16* hOut, u16* cOut){
    f32x4 A0={0,0,0,0}, A1={0,0,0,0}, A2={0,0,0,0}, A3={0,0,0,0};
    const u16* Wb = Win_h + ((size_t)wg << 16);
    for (int c = 0; c < 4; ++c){
      __syncthreads();
      stage(Wb + (c << 14), 32);
      __syncthreads();
      const char* hp = (const char*)(hIn + ((size_t)b << 10) + (c << 8) + (kg << 3));
      #pragma unroll
      for (int ks = 0; ks < 8; ++ks){
        FRAG bh; bh.q[0] = ald(hp + ks*64); bh.q[1] = ald(hp + ks*64 + 8);
        int kb = (ks << 6) + (kg << 4);
        FRAG a;
        a.v = af512(bl, kb);      A0 = MFMA16(a.v, bh.v, A0);
        a.v = af512(16 + bl, kb); A1 = MFMA16(a.v, bh.v, A1);
        a.v = af512(32 + bl, kb); A2 = MFMA16(a.v, bh.v, A2);
        a.v = af512(48 + bl, kb); A3 = MFMA16(a.v, bh.v, A3);
      }
    }
    // x part: x_t = m_true[b][255-t][:320], read f32 + cast
    const float* xr = m_true + (size_t)b*81920 + (size_t)(255 - t)*320;
    __syncthreads();
    stage(Win_x + (size_t)wg*20480, 32);
    __syncthreads();
    #pragma unroll
    for (int ks = 0; ks < 8; ++ks){
      int k = (ks << 5) + (kg << 3);
      f32x4 x0 = *(const f32x4*)(xr + k);
      f32x4 x1 = *(const f32x4*)(xr + k + 4);
      FRAG bx;
      bx.s[0]=f2bf(x0[0]); bx.s[1]=f2bf(x0[1]); bx.s[2]=f2bf(x0[2]); bx.s[3]=f2bf(x0[3]);
      bx.s[4]=f2bf(x1[0]); bx.s[5]=f2bf(x1[1]); bx.s[6]=f2bf(x1[2]); bx.s[7]=f2bf(x1[3]);
      int kb = (ks << 6) + (kg << 4);
      FRAG a;
      a.v = af512(bl, kb);      A0 = MFMA16(a.v, bx.v, A0);
      a.v = af512(16 + bl, kb); A1 = MFMA16(a.v, bx.v, A1);
      a.v = af512(32 + bl, kb); A2 = MFMA16(a.v, bx.v, A2);
      a.v = af512(48 + bl, kb); A3 = MFMA16(a.v, bx.v, A3);
    }
    __syncthreads();
    stage(Win_x + (size_t)wg*20480 + 16384, 8);
    __syncthreads();
    #pragma unroll
    for (int ks = 0; ks < 2; ++ks){
      int k = 256 + (ks << 5) + (kg << 3);
      f32x4 x0 = *(const f32x4*)(xr + k);
      f32x4 x1 = *(const f32x4*)(xr + k + 4);
      FRAG bx;
      bx.s[0]=f2bf(x0[0]); bx.s[1]=f2bf(x0[1]); bx.s[2]=f2bf(x0[2]); bx.s[3]=f2bf(x0[3]);
      bx.s[4]=f2bf(x1[0]); bx.s[5]=f2bf(x1[1]); bx.s[6]=f2bf(x1[2]); bx.s[7]=f2bf(x1[3]);
      int kb = (ks << 6) + (kg << 4);
      FRAG a;
      a.v = af128(bl, kb);      A0 = MFMA16(a.v, bx.v, A0);
      a.v = af128(16 + bl, kb); A1 = MFMA16(a.v, bx.v, A1);
      a.v = af128(32 + bl, kb); A2 = MFMA16(a.v, bx.v, A2);
      a.v = af128(48 + bl, kb); A3 = MFMA16(a.v, bx.v, A3);
    }
    int jj = (wg << 4) + (kg << 2);
    F4 cp4;
    const char* cfp = (const char*)(cF + ((size_t)b << 10) + jj);
    cp4.q[0] = ald(cfp); cp4.q[1] = ald(cfp + 8);
    P4 hw, cw;
    #pragma unroll
    for (int r = 0; r < 4; ++r){
      float gi = A0[r] + b_in[jj + r];
      float gf = A1[r] + b_in[1024 + jj + r];
      float gg = A2[r] + b_in[2048 + jj + r];
      float go = A3[r] + b_in[3072 + jj + r];
      float cn = sigm(gf)*cp4.f[r] + sigm(gi)*tanh_(gg);
      hw.s[r] = f2bf(sigm(go)*tanh_(cn));
      cw.s[r] = f2bf(cn);
    }
    ast(hOut + ((size_t)b << 10) + jj, hw.q);
    ast(cOut + ((size_t)b << 10) + jj, cw.q);
  };

  // ---- inner cell phase i (wg<64): gates = W_eff_i@h; c1 = cA_i@c; EW
  auto phase_cell = [&](int i, const u16* hIn, const u16* cIn, u16* hOut, u16* cOut, bool last){
    f32x4 A0={0,0,0,0}, A1={0,0,0,0}, A2={0,0,0,0}, A3={0,0,0,0}, A4={0,0,0,0};
    const u16* Wb = Wcell + (size_t)(i*64 + wg) * 81920;
    for (int c = 0; c < 4; ++c){
      __syncthreads();
      stage(Wb + c*20480, 40);
      __syncthreads();
      const char* hp = (const char*)(hIn + ((size_t)b << 10) + (c << 8) + (kg << 3));
      const char* cp = (const char*)(cIn + ((size_t)b << 10) + (c << 8) + (kg << 3));
      #pragma unroll
      for (int ks = 0; ks < 8; ++ks){
        FRAG bh; bh.q[0] = ald(hp + ks*64); bh.q[1] = ald(hp + ks*64 + 8);
        FRAG bc; bc.q[0] = ald(cp + ks*64); bc.q[1] = ald(cp + ks*64 + 8);
        int kb = (ks << 6) + (kg << 4);
        FRAG a;
        a.v = af512(bl, kb);      A0 = MFMA16(a.v, bh.v, A0);
        a.v = af512(16 + bl, kb); A1 = MFMA16(a.v, bh.v, A1);
        a.v = af512(32 + bl, kb); A2 = MFMA16(a.v, bh.v, A2);
        a.v = af512(48 + bl, kb); A3 = MFMA16(a.v, bh.v, A3);
        a.v = af512(64 + bl, kb); A4 = MFMA16(a.v, bc.v, A4);
      }
    }
    int jj = (wg << 4) + (kg << 2);
    P4 hw, cw; F4 cf4;
    #pragma unroll
    for (int r = 0; r < 4; ++r){
      float gi = A0[r] + b_cell[i*4096 + jj + r];
      float gf = A1[r] + b_cell[i*4096 + 1024 + jj + r];
      float gg = A2[r] + b_cell[i*4096 + 2048 + jj + r];
      float go = A3[r] + b_cell[i*4096 + 3072 + jj + r];
      float c1 = A4[r] + cAb[i*1024 + jj + r];
      float cn = sigm(gf)*c1 + sigm(gi)*tanh_(gg);
      hw.s[r] = f2bf(sigm(go)*tanh_(cn));
      cw.s[r] = f2bf(cn);
      cf4.f[r] = cn;
    }
    ast(hOut + ((size_t)b << 10) + jj, hw.q);
    ast(cOut + ((size_t)b << 10) + jj, cw.q);
    if (last){
      char* cfp = (char*)(cF + ((size_t)b << 10) + jj);
      ast(cfp, cf4.q[0]); ast(cfp + 8, cf4.q[1]);
    }
  };

  // ---- ccA phase (wg 64..83, runs with cell i==3): cc = lastCA@c + b_cc
  auto phase_ccA = [&](const u16* cIn){
    f32x4 A = {0,0,0,0};
    int w2 = wg - 64;
    const u16* Wb = WccA + ((size_t)w2 << 14);
    for (int c = 0; c < 4; ++c){
      __syncthreads();
      stage(Wb + (c << 12), 8);
      __syncthreads();
      const char* cp = (const char*)(cIn + ((size_t)b << 10) + (c << 8) + (kg << 3));
      #pragma unroll
      for (int ks = 0; ks < 8; ++ks){
        FRAG bc; bc.q[0] = ald(cp + ks*64); bc.q[1] = ald(cp + ks*64 + 8);
        int kb = (ks << 6) + (kg << 4);
        FRAG a; a.v = af512(bl, kb);
        A = MFMA16(a.v, bc.v, A);
      }
    }
    int jjo = (w2 << 4) + (kg << 2);
    F4 v;
    #pragma unroll
    for (int r = 0; r < 4; ++r) v.f[r] = A[r] + b_cc[jjo + r];
    char* cp2 = (char*)(ccB + (size_t)b*320 + jjo);
    ast(cp2, v.q[0]); ast(cp2 + 8, v.q[1]);
  };

  // ---- out-cell phase (wg 64..83): gates = W_out_eff@h2_4 + b; c = cc; -> d_out
  auto phase_out = [&](int t, const u16* hIn){
    f32x4 A0={0,0,0,0}, A1={0,0,0,0}, A2={0,0,0,0}, A3={0,0,0,0};
    int w2 = wg - 64;
    const u16* Wb = Wout + ((size_t)w2 << 16);
    for (int c = 0; c < 4; ++c){
      __syncthreads();
      stage(Wb + (c << 14), 32);
      __syncthreads();
      const char* hp = (const char*)(hIn + ((size_t)b << 10) + (c << 8) + (kg << 3));
      #pragma unroll
      for (int ks = 0; ks < 8; ++ks){
        FRAG bh; bh.q[0] = ald(hp + ks*64); bh.q[1] = ald(hp + ks*64 + 8);
        int kb = (ks << 6) + (kg << 4);
        FRAG a;
        a.v = af512(bl, kb);      A0 = MFMA16(a.v, bh.v, A0);
        a.v = af512(16 + bl, kb); A1 = MFMA16(a.v, bh.v, A1);
        a.v = af512(32 + bl, kb); A2 = MFMA16(a.v, bh.v, A2);
        a.v = af512(48 + bl, kb); A3 = MFMA16(a.v, bh.v, A3);
      }
    }
    int jjo = (w2 << 4) + (kg << 2);
    F4 cc4;
    const char* ccp = (const char*)(ccB + (size_t)b*320 + jjo);
    cc4.q[0] = ald(ccp); cc4.q[1] = ald(ccp + 8);
    f32x4 ho;
    #pragma unroll
    for (int r = 0; r < 4; ++r){
      float gi = A0[r] + b_out[jjo + r];
      float gf = A1[r] + b_out[320 + jjo + r];
      float gg = A2[r] + b_out[640 + jjo + r];
      float go = A3[r] + b_out[960 + jjo + r];
      float cn = sigm(gf)*cc4.f[r] + sigm(gi)*tanh_(gg);
      ho[r] = sigm(go)*tanh_(cn);
    }
    *(f32x4*)(outp + (size_t)b*81920 + (size_t)(t+1)*320 + jjo) = ho;
  };

  // ---- main schedule: phase p writes state buf[p&1], reads buf[1-(p&1)]
  u16* hB0 = hS;        u16* hB1 = hS + 65536;
  u16* cB0 = cS;        u16* cB1 = cS + 65536;

  if (wg < 64) phase_incell(0, hB1, hB0, cB0);   // h0 preloaded into hB1, c0 into cF
  gbar(bar, 0);
  int p = 1;
  #pragma unroll 1
  for (int t = 0; t < 255; ++t){
    #pragma unroll 1
    for (int i = 0; i < 4; ++i){
      u16* hIn = (p & 1) ? hB0 : hB1;  u16* cIn = (p & 1) ? cB0 : cB1;
      u16* hOut = (p & 1) ? hB1 : hB0; u16* cOut = (p & 1) ? cB1 : cB0;
      if (wg < 64)      phase_cell(i, hIn, cIn, hOut, cOut, i == 3);
      else if (i == 3)  phase_ccA(cIn);
      gbar(bar, p); ++p;
    }
    u16* hIn = (p & 1) ? hB0 : hB1;
    u16* hOut = (p & 1) ? hB1 : hB0; u16* cOut = (p & 1) ? cB1 : cB0;
    if (wg >= 64)       phase_out(t, hIn);
    else if (t < 254)   phase_incell(t + 1, hIn, hOut, cOut);
    gbar(bar, p); ++p;
  }
}

// ---------------------------------------------------------------------------
// Precompute kernels
// ---------------------------------------------------------------------------

// Generic dense layer for the init MLPs. wave -> output unit o, lane -> batch b.
__global__ __launch_bounds__(256) void k_dense(const float* __restrict__ X, int xmode,
    const float* __restrict__ W, const float* __restrict__ bias,
    int OD, int ID, int act, int omode, float* outF, u16* outB)
{
  int o = blockIdx.x*4 + (threadIdx.x >> 6);
  if (o >= OD) return;
  int lane = threadIdx.x & 63;
  const float* wr = W + (size_t)o*ID;
  float acc = 0.f;
  if (xmode == 0){ for (int k = 0; k < ID; ++k) acc = fmaf(wr[k], X[(size_t)lane*ID + k], acc); }
  else           { for (int k = 0; k < ID; ++k) acc = fmaf(wr[k], X[(size_t)k*64 + lane], acc); }
  acc += bias[o];
  if (act) acc = acc * sigm(acc);  // SiLU
  if (omode == 0)      outF[(size_t)o*64 + lane] = acc;                 // scratch [OD][64]
  else if (omode == 1) outB[(size_t)lane*1024 + o] = f2bf(acc);         // h0 -> hS[1] bf16
  else if (omode == 2) outF[(size_t)lane*1024 + o] = acc;               // c0 -> cF f32
  else                 outF[(size_t)lane*81920 + 256 + o] = acc;        // x_last -> m_hat[:,0,256:]
}

__global__ void k_zero0(float* out){ out[(size_t)blockIdx.x*81920 + threadIdx.x] = 0.f; }

// transpose f32 [M][N] -> bf16 [N][M]
__global__ __launch_bounds__(256) void k_tr(const float* __restrict__ in, u16* __restrict__ out, int M, int N){
  __shared__ u16 t[64][65];
  int m0 = blockIdx.x << 6, n0 = blockIdx.y << 6;
  int c = threadIdx.x & 63, rq = threadIdx.x >> 6;
  for (int rr = 0; rr < 16; ++rr){
    int r = (rq << 4) + rr;
    t[r][c] = f2bf(in[(size_t)(m0 + r)*N + n0 + c]);
  }
  __syncthreads();
  for (int rr = 0; rr < 16; ++rr){
    int r = (rq << 4) + rr;
    out[(size_t)(n0 + r)*M + m0 + c] = t[c][r];
  }
}

// OUT[j][k2] = (Wih ? Wih[j][k2] : 0) + sum_m Whh[j][m]*BT[k2][m], written into
// the blocked+swizzled bf16 layout.  mode0: cells (dst rows g*16+jj%16, 80-row
// blocks); mode1: out-cell (64-row blocks); mode2: lastCA (16-row blocks).
__global__ __launch_bounds__(256) void k_fuse(const float* __restrict__ Whh, const float* __restrict__ Wih,
    const u16* __restrict__ BT, int KM, int mode, u16* __restrict__ dst)
{
  int bx = blockIdx.x, by = blockIdx.y, bz = blockIdx.z;
  int lane = threadIdx.x & 63, wv = threadIdx.x >> 6;
  int bl = lane & 15, kg = lane >> 4;
  int jbase = (mode == 0) ? bz*1024 : ((mode == 1) ? bz*320 : 0);
  int jrow = jbase + bx*16 + bl;
  int k2c = by*64 + wv*16 + bl;
  f32x4 acc = {0,0,0,0};
  for (int m0 = 0; m0 < KM; m0 += 32){
    f32x4 wa0 = *(const f32x4*)(Whh + (size_t)jrow*KM + m0 + (kg << 3));
    f32x4 wa1 = *(const f32x4*)(Whh + (size_t)jrow*KM + m0 + (kg << 3) + 4);
    FRAG a;
    a.s[0]=f2bf(wa0[0]); a.s[1]=f2bf(wa0[1]); a.s[2]=f2bf(wa0[2]); a.s[3]=f2bf(wa0[3]);
    a.s[4]=f2bf(wa1[0]); a.s[5]=f2bf(wa1[1]); a.s[6]=f2bf(wa1[2]); a.s[7]=f2bf(wa1[3]);
    FRAG bb; bb.v = *(const bf16x8*)(BT + (size_t)k2c*KM + m0 + (kg << 3));
    acc = MFMA16(a.v, bb.v, acc);
  }
  #pragma unroll
  for (int r = 0; r < 4; ++r){
    int jl = (kg << 2) + r;                 // j within 16-tile (D row)
    int jg = jbase + bx*16 + jl;
    float v = acc[r];
    if (mode < 2) v += Wih[(size_t)jg*1024 + k2c];
    int re = (mode == 2) ? jl : (bz*16 + jl);
    int c = k2c >> 8, kl = k2c & 255;
    size_t pos;
    if (mode == 0)      pos = (size_t)bx*81920 + c*20480 + re*256 + (kl ^ ((re&7)<<3));
    else if (mode == 1) pos = (size_t)bx*65536 + c*16384 + re*256 + (kl ^ ((re&7)<<3));
    else                pos = (size_t)bx*16384 + c*4096  + re*256 + (kl ^ ((re&7)<<3));
    dst[pos] = f2bf(v);
  }
}

// pack in_Whh [4096][1024] -> blocked bf16
__global__ void k_pack_winh(const float* __restrict__ src, u16* __restrict__ dst){
  int id = blockIdx.x*256 + threadIdx.x;
  int j = id >> 10, k = id & 1023;
  int g = j >> 10, jj = j & 1023;
  int w = jj >> 4, r = (g << 4) + (jj & 15);
  int c = k >> 8, kl = k & 255;
  dst[(size_t)w*65536 + c*16384 + r*256 + (kl ^ ((r&7)<<3))] = f2bf(src[id]);
}

// pack in_Wih [4096][320] -> blocked bf16 (chunk0: 256 k, chunk1: 64 k)
__global__ void k_pack_winx(const float* __restrict__ src, u16* __restrict__ dst){
  int j = blockIdx.x, k = threadIdx.x;   // block 320
  int g = j >> 10, jj = j & 1023;
  int w = jj >> 4, r = (g << 4) + (jj & 15);
  float v = src[(size_t)j*320 + k];
  size_t pos;
  if (k < 256) pos = (size_t)w*20480 + r*256 + (k ^ ((r&7)<<3));
  else         pos = (size_t)w*20480 + 16384 + r*64 + ((k - 256) ^ ((r&7)<<3));
  dst[pos] = f2bf(v);
}

// pack cA_W[i] [1024][1024] into Wcell_i rows 64..79
__global__ void k_pack_ca(const float* __restrict__ src, u16* __restrict__ dst){
  int id = blockIdx.x*256 + threadIdx.x;
  int jj = id >> 10, k = id & 1023;
  int w = jj >> 4, r = 64 + (jj & 15);
  int c = k >> 8, kl = k & 255;
  dst[(size_t)w*81920 + c*20480 + r*256 + (kl ^ ((r&7)<<3))] = f2bf(src[id]);
}

// o[j] = (A ? A[j,:]@x : 0) + a1[j] + a2[j]   (wave per j, f32)
__global__ __launch_bounds__(256) void k_bias(const float* __restrict__ A, const float* __restrict__ x,
    const float* __restrict__ a1, const float* __restrict__ a2, float* __restrict__ o, int NJ, int K)
{
  int j = blockIdx.x*4 + (threadIdx.x >> 6);
  if (j >= NJ) return;
  int lane = threadIdx.x & 63;
  float acc = 0.f;
  if (A) for (int k = lane; k < K; k += 64) acc += A[(size_t)j*K + k]*x[k];
  for (int off = 32; off; off >>= 1) acc += __shfl_down(acc, off);
  if (lane == 0) o[j] = acc + (a1 ? a1[j] : 0.f) + (a2 ? a2[j] : 0.f);
}

// ---------------------------------------------------------------------------
extern "C" void kernel_launch(void* const* d_in, const int* in_sizes, int n_in,
                              void* d_out, int out_size, void* d_ws, size_t ws_size,
                              hipStream_t stream)
{
  (void)in_sizes; (void)n_in; (void)out_size;
  const float* z      = (const float*)d_in[0];
  const float* m_true = (const float*)d_in[1];
  const float* eh_W1=(const float*)d_in[2],  *eh_b1=(const float*)d_in[3];
  const float* eh_W2=(const float*)d_in[4],  *eh_b2=(const float*)d_in[5];
  const float* eh_W3=(const float*)d_in[6],  *eh_b3=(const float*)d_in[7];
  const float* ec_W1=(const float*)d_in[8],  *ec_b1=(const float*)d_in[9];
  const float* ec_W2=(const float*)d_in[10], *ec_b2=(const float*)d_in[11];
  const float* ec_W3=(const float*)d_in[12], *ec_b3=(const float*)d_in[13];
  const float* ex_W1=(const float*)d_in[14], *ex_b1=(const float*)d_in[15];
  const float* ex_W2=(const float*)d_in[16], *ex_b2=(const float*)d_in[17];
  const float* ex_W3=(const float*)d_in[18], *ex_b3=(const float*)d_in[19];
  const float* in_Wih=(const float*)d_in[20], *in_Whh=(const float*)d_in[21];
  const float* in_bih=(const float*)d_in[22], *in_bhh=(const float*)d_in[23];
  const float* r_Wih=(const float*)d_in[24],  *r_Whh=(const float*)d_in[25];
  const float* r_bih=(const float*)d_in[26],  *r_bhh=(const float*)d_in[27];
  const float* hA_W=(const float*)d_in[28],   *hA_b=(const float*)d_in[29];
  const float* cA_W=(const float*)d_in[30],   *cA_b=(const float*)d_in[31];
  const float* lastH_W=(const float*)d_in[32], *lastH_b=(const float*)d_in[33];
  const float* lastC_W=(const float*)d_in[34], *lastC_b=(const float*)d_in[35];
  const float* out_Wih=(const float*)d_in[36], *out_Whh=(const float*)d_in[37];
  const float* out_bih=(const float*)d_in[38], *out_bhh=(const float*)d_in[39];
  float* out = (float*)d_out;

  char* wsb = (char*)d_ws;
  size_t off = 0;
  auto alloc = [&](size_t bytes)->char*{
    char* p = wsb + off; off = (off + bytes + 255) & ~(size_t)255; return p;
  };
  u32* bar    = (u32*)alloc(2048*4);
  u16* hS     = (u16*)alloc(2*64*1024*2);
  u16* cS     = (u16*)alloc(2*64*1024*2);
  float* cF   = (float*)alloc(64*1024*4);
  float* ccB  = (float*)alloc(64*320*4);
  float* b_in = (float*)alloc(4096*4);
  float* b_cell=(float*)alloc(4*4096*4);
  float* b_out= (float*)alloc(1280*4);
  float* b_cc = (float*)alloc(320*4);
  float* t1   = (float*)alloc(1024*64*4);
  float* t2   = (float*)alloc(1024*64*4);
  u16* Tbuf   = (u16*)alloc((size_t)1024*1024*2);
  u16* Win_h  = (u16*)alloc((size_t)64*65536*2);
  u16* Win_x  = (u16*)alloc((size_t)64*20480*2);
  u16* Wcell  = (u16*)alloc((size_t)4*64*81920*2);
  u16* Wout   = (u16*)alloc((size_t)20*65536*2);
  u16* WccA   = (u16*)alloc((size_t)20*16384*2);
  if (off > ws_size) return;   // insufficient workspace -> visible failure

  hipMemsetAsync(bar, 0, 2048*4, stream);

  // init MLPs: h0 -> hS[1] (bf16), c0 -> cF (f32), x_last -> m_hat[:,0,256:]
  k_dense<<<256,256,0,stream>>>(z, 0, eh_W1, eh_b1, 1024, 256, 1, 0, t1, nullptr);
  k_dense<<<256,256,0,stream>>>(t1,1, eh_W2, eh_b2, 1024,1024, 1, 0, t2, nullptr);
  k_dense<<<256,256,0,stream>>>(t2,1, eh_W3, eh_b3, 1024,1024, 0, 1, nullptr, hS + 65536);
  k_dense<<<256,256,0,stream>>>(z, 0, ec_W1, ec_b1, 1024, 256, 1, 0, t1, nullptr);
  k_dense<<<256,256,0,stream>>>(t1,1, ec_W2, ec_b2, 1024,1024, 1, 0, t2, nullptr);
  k_dense<<<256,256,0,stream>>>(t2,1, ec_W3, ec_b3, 1024,1024, 0, 2, cF, nullptr);
  k_dense<<<256,256,0,stream>>>(z, 0, ex_W1, ex_b1, 1024, 256, 1, 0, t1, nullptr);
  k_dense<<<256,256,0,stream>>>(t1,1, ex_W2, ex_b2, 1024,1024, 1, 0, t2, nullptr);
  k_dense<<<16 ,256,0,stream>>>(t2,1, ex_W3, ex_b3,   64,1024, 0, 3, out, nullptr);
  k_zero0<<<64,256,0,stream>>>(out);

  // weight packing (bf16, blocked + XOR-swizzled)
  k_pack_winh<<<16384,256,0,stream>>>(in_Whh, Win_h);
  k_pack_winx<<<4096,320,0,stream>>>(in_Wih, Win_x);
  for (int i = 0; i < 4; ++i)
    k_pack_ca<<<4096,256,0,stream>>>(cA_W + (size_t)i*1024*1024, Wcell + (size_t)i*64*81920);

  // fused weights: W_eff_i = r_Wih_i + r_Whh_i @ hA_W_i ; W_out_eff ; lastCA
  for (int i = 0; i < 4; ++i){
    k_tr<<<dim3(16,16),256,0,stream>>>(hA_W + (size_t)i*1024*1024, Tbuf, 1024, 1024);
    k_fuse<<<dim3(64,16,4),256,0,stream>>>(r_Whh + (size_t)i*4096*1024,
                                           r_Wih + (size_t)i*4096*1024,
                                           Tbuf, 1024, 0, Wcell + (size_t)i*64*81920);
  }
  k_tr<<<dim3(5,16),256,0,stream>>>(lastH_W, Tbuf, 320, 1024);
  k_fuse<<<dim3(20,16,4),256,0,stream>>>(out_Whh, out_Wih, Tbuf, 320, 1, Wout);
  k_tr<<<dim3(16,16),256,0,stream>>>(cA_W + (size_t)3*1024*1024, Tbuf, 1024, 1024);
  k_fuse<<<dim3(20,16,1),256,0,stream>>>(lastC_W, nullptr, Tbuf, 1024, 2, WccA);

  // fused biases
  k_bias<<<1024,256,0,stream>>>(nullptr, nullptr, in_bih, in_bhh, b_in, 4096, 0);
  for (int i = 0; i < 4; ++i)
    k_bias<<<1024,256,0,stream>>>(r_Whh + (size_t)i*4096*1024, hA_b + i*1024,
                                  r_bih + i*4096, r_bhh + i*4096, b_cell + i*4096, 4096, 1024);
  k_bias<<<320,256,0,stream>>>(out_Whh, lastH_b, out_bih, out_bhh, b_out, 1280, 320);
  k_bias<<<80 ,256,0,stream>>>(lastC_W, cA_b + 3*1024, lastC_b, nullptr, b_cc, 320, 1024);

  // the scan
  k_scan<<<NWG,256,0,stream>>>(m_true, Wcell, Win_h, Win_x, Wout, WccA,
                               b_in, b_cell, cA_b, b_out, b_cc,
                               hS, cS, cF, ccB, out, bar);
}

// Round 2
// 34030.765 us; speedup vs baseline: 1.1603x; 1.1603x over previous
//
#include <hip/hip_runtime.h>

// BigARDecoder: persistent-kernel LSTM scan on MI355X.
// B=64, T=256, IN=256, H=1024, G=256, O=64, D=4, GO=320.
//
// R2: async global_load_lds staging, double-buffered LDS (2x40KB), counted
// s_waitcnt vmcnt(N) + raw s_barrier per chunk (T3/T4), one-chunk-ahead
// prefetch of both weights and h/c state fragments. Fixes the 29us/phase
// serial-staging latency stall (MfmaUtil was 0.98%).

typedef unsigned int u32;
typedef unsigned long long u64;
typedef unsigned short u16;
typedef __attribute__((ext_vector_type(8))) __bf16 bf16x8;
typedef __attribute__((ext_vector_type(4))) float f32x4;

#define DEVI __device__ __forceinline__

union FRAG { bf16x8 v; u16 s[8]; u64 q[2]; };
union P4 { u64 q; u16 s[4]; };
union F4 { u64 q[2]; float f[4]; };

DEVI u16 f2bf(float x){ u32 u = __float_as_uint(x); return (u16)((u + 0x7fffu + ((u>>16)&1u)) >> 16); }
DEVI float sigm(float x){ return 1.0f/(1.0f + __expf(-x)); }
DEVI float tanh_(float x){ return 2.0f/(1.0f + __expf(-2.0f*x)) - 1.0f; }
DEVI u64 ald(const void* p){ return __hip_atomic_load((const u64*)p, __ATOMIC_RELAXED, __HIP_MEMORY_SCOPE_AGENT); }
DEVI void ast(void* p, u64 v){ __hip_atomic_store((u64*)p, v, __ATOMIC_RELAXED, __HIP_MEMORY_SCOPE_AGENT); }

#define MFMA16(a,b,c) __builtin_amdgcn_mfma_f32_16x16x32_bf16(a, b, c, 0, 0, 0)

#define NWG 84
#define SCHEDB() __builtin_amdgcn_sched_barrier(0)
// drain this wave's chunk asyncs (N = #VMEM issued after them), then WG barrier
#define VBAR(n) do{ SCHEDB(); \
  asm volatile("s_waitcnt vmcnt(" #n ")" ::: "memory"); \
  SCHEDB(); __builtin_amdgcn_s_barrier(); SCHEDB(); }while(0)

DEVI void gbar(u32* bar, int slot){
  __syncthreads();
  if (threadIdx.x == 0){
    __hip_atomic_fetch_add(&bar[slot], 1u, __ATOMIC_RELEASE, __HIP_MEMORY_SCOPE_AGENT);
    while (__hip_atomic_load(&bar[slot], __ATOMIC_RELAXED, __HIP_MEMORY_SCOPE_AGENT) < (u32)NWG)
      __builtin_amdgcn_s_sleep(2);
    asm volatile("" ::: "memory");
  }
  __syncthreads();
}

// ---------------------------------------------------------------------------
// Persistent scan kernel. 84 WGs x 256 threads (4 waves = 4 b-tiles of 16).
// WGs 0..63: hidden-unit tiles (16 jj each). WGs 64..83: out-cell / ccA tiles.
// ---------------------------------------------------------------------------
__global__ __launch_bounds__(256, 1) void k_scan(
    const float* __restrict__ m_true,
    const u16* __restrict__ Wcell, const u16* __restrict__ Win_h,
    const u16* __restrict__ Win_x, const u16* __restrict__ Wout,
    const u16* __restrict__ WccA,
    const float* __restrict__ b_in, const float* __restrict__ b_cell,
    const float* __restrict__ cAb, const float* __restrict__ b_out,
    const float* __restrict__ b_cc,
    u16* hS, u16* cS, float* cF, float* ccB, float* outp, u32* bar)
{
  const int wg = blockIdx.x;
  const int tid = threadIdx.x;
  const int wave = tid >> 6, lane = tid & 63;
  const int bl = lane & 15, kg = lane >> 4;
  const int b = (wave << 4) + bl;
  const int swz = (bl & 7) << 4;
  __shared__ u16 ldsW[40960];              // 2 x 40KB double buffer

  // async stage: spw 1KB-segments per wave, linear LDS dest (pre-swizzled src)
  auto stage_async = [&](const u16* src, u16* lb, int spw){
    const u16* g = src + ((size_t)(wave*spw) << 9) + (lane << 3);
    u16* l = lb + ((wave*spw) << 9);
    for (int s = 0; s < spw; ++s){
      __builtin_amdgcn_global_load_lds(
          (const __attribute__((address_space(1))) void*)g,
          (__attribute__((address_space(3))) void*)l, 16, 0, 0);
      g += 512; l += 512;
    }
    SCHEDB();
  };
  auto afL = [&](const u16* lb, int row, int kb) -> bf16x8 {   // A-frag, 512B rows
    return *(const bf16x8*)((const char*)lb + row*512 + (kb ^ swz));
  };

  // ---- in-cell phase (wg<64): gates = W_in_h@h + W_in_x@x_t + b; c_prev=cF
  auto phase_incell = [&](int t, const u16* hIn, u16* hOut, u16* cOut){
    f32x4 A0={0,0,0,0}, A1={0,0,0,0}, A2={0,0,0,0}, A3={0,0,0,0};
    // preload+convert x_t fragments (retired before staging starts counting)
    const float* xr = m_true + (size_t)b*81920 + (size_t)(255 - t)*320;
    FRAG xf[10];
    #pragma unroll
    for (int ks = 0; ks < 10; ++ks){
      int k = (ks << 5) + (kg << 3);
      f32x4 x0 = *(const f32x4*)(xr + k);
      f32x4 x1 = *(const f32x4*)(xr + k + 4);
      xf[ks].s[0]=f2bf(x0[0]); xf[ks].s[1]=f2bf(x0[1]); xf[ks].s[2]=f2bf(x0[2]); xf[ks].s[3]=f2bf(x0[3]);
      xf[ks].s[4]=f2bf(x1[0]); xf[ks].s[5]=f2bf(x1[1]); xf[ks].s[6]=f2bf(x1[2]); xf[ks].s[7]=f2bf(x1[3]);
    }
    SCHEDB();
    const u16* Wb = Win_h + ((size_t)wg << 16);
    const char* hp0 = (const char*)(hIn + ((size_t)b << 10) + (kg << 3));
    u64 sh[2][16];
    stage_async(Wb, ldsW, 8);
    #pragma unroll
    for (int ks = 0; ks < 8; ++ks){
      sh[0][2*ks]   = ald(hp0 + ks*64);
      sh[0][2*ks+1] = ald(hp0 + ks*64 + 8);
    }
    SCHEDB();
    #pragma unroll
    for (int c = 0; c < 4; ++c){
      const u16* lb = ldsW + (c & 1)*20480;
      VBAR(16);
      if (c < 3){
        stage_async(Wb + (size_t)(c+1)*16384, ldsW + ((c+1)&1)*20480, 8);
        #pragma unroll
        for (int ks = 0; ks < 8; ++ks){
          sh[(c+1)&1][2*ks]   = ald(hp0 + (c+1)*512 + ks*64);
          sh[(c+1)&1][2*ks+1] = ald(hp0 + (c+1)*512 + ks*64 + 8);
        }
        SCHEDB();
      } else {
        stage_async(Win_x + (size_t)wg*20480, ldsW, 10);   // x chunk -> buf0
      }
      #pragma unroll
      for (int ks = 0; ks < 8; ++ks){
        FRAG bh; bh.q[0] = sh[c&1][2*ks]; bh.q[1] = sh[c&1][2*ks+1];
        int kb = (ks << 6) + (kg << 4);
        FRAG a;
        a.v = afL(lb, bl, kb);      A0 = MFMA16(a.v, bh.v, A0);
        a.v = afL(lb, 16 + bl, kb); A1 = MFMA16(a.v, bh.v, A1);
        a.v = afL(lb, 32 + bl, kb); A2 = MFMA16(a.v, bh.v, A2);
        a.v = afL(lb, 48 + bl, kb); A3 = MFMA16(a.v, bh.v, A3);
      }
    }
    // x part (buf0): 32KB chunkA rows[64]x512B + 8KB chunkB rows[64]x128B
    VBAR(0);
    #pragma unroll
    for (int ks = 0; ks < 8; ++ks){
      int kb = (ks << 6) + (kg << 4);
      FRAG a;
      a.v = afL(ldsW, bl, kb);      A0 = MFMA16(a.v, xf[ks].v, A0);
      a.v = afL(ldsW, 16 + bl, kb); A1 = MFMA16(a.v, xf[ks].v, A1);
      a.v = afL(ldsW, 32 + bl, kb); A2 = MFMA16(a.v, xf[ks].v, A2);
      a.v = afL(ldsW, 48 + bl, kb); A3 = MFMA16(a.v, xf[ks].v, A3);
    }
    #pragma unroll
    for (int ks = 0; ks < 2; ++ks){
      int kb = (ks << 6) + (kg << 4);
      FRAG a;
      a.v = *(const bf16x8*)((const char*)ldsW + 32768 + bl*128        + (kb ^ swz)); A0 = MFMA16(a.v, xf[8+ks].v, A0);
      a.v = *(const bf16x8*)((const char*)ldsW + 32768 + (16+bl)*128   + (kb ^ swz)); A1 = MFMA16(a.v, xf[8+ks].v, A1);
      a.v = *(const bf16x8*)((const char*)ldsW + 32768 + (32+bl)*128   + (kb ^ swz)); A2 = MFMA16(a.v, xf[8+ks].v, A2);
      a.v = *(const bf16x8*)((const char*)ldsW + 32768 + (48+bl)*128   + (kb ^ swz)); A3 = MFMA16(a.v, xf[8+ks].v, A3);
    }
    int jj = (wg << 4) + (kg << 2);
    F4 cp4;
    const char* cfp = (const char*)(cF + ((size_t)b << 10) + jj);
    cp4.q[0] = ald(cfp); cp4.q[1] = ald(cfp + 8);
    P4 hw, cw;
    #pragma unroll
    for (int r = 0; r < 4; ++r){
      float gi = A0[r] + b_in[jj + r];
      float gf = A1[r] + b_in[1024 + jj + r];
      float gg = A2[r] + b_in[2048 + jj + r];
      float go = A3[r] + b_in[3072 + jj + r];
      float cn = sigm(gf)*cp4.f[r] + sigm(gi)*tanh_(gg);
      hw.s[r] = f2bf(sigm(go)*tanh_(cn));
      cw.s[r] = f2bf(cn);
    }
    ast(hOut + ((size_t)b << 10) + jj, hw.q);
    ast(cOut + ((size_t)b << 10) + jj, cw.q);
  };

  // ---- inner cell phase i (wg<64): gates = W_eff_i@h; c1 = cA_i@c; EW
  auto phase_cell = [&](int i, const u16* hIn, const u16* cIn, u16* hOut, u16* cOut, bool last){
    f32x4 A0={0,0,0,0}, A1={0,0,0,0}, A2={0,0,0,0}, A3={0,0,0,0}, A4={0,0,0,0};
    const u16* Wb = Wcell + (size_t)(i*64 + wg) * 81920;
    const char* hp0 = (const char*)(hIn + ((size_t)b << 10) + (kg << 3));
    const char* cp0 = (const char*)(cIn + ((size_t)b << 10) + (kg << 3));
    u64 sh[2][16], sc[2][16];
    stage_async(Wb, ldsW, 10);
    #pragma unroll
    for (int ks = 0; ks < 8; ++ks){
      sh[0][2*ks]   = ald(hp0 + ks*64);
      sh[0][2*ks+1] = ald(hp0 + ks*64 + 8);
      sc[0][2*ks]   = ald(cp0 + ks*64);
      sc[0][2*ks+1] = ald(cp0 + ks*64 + 8);
    }
    SCHEDB();
    #pragma unroll
    for (int c = 0; c < 4; ++c){
      const u16* lb = ldsW + (c & 1)*20480;
      VBAR(32);
      if (c < 3){
        stage_async(Wb + (size_t)(c+1)*20480, ldsW + ((c+1)&1)*20480, 10);
        #pragma unroll
        for (int ks = 0; ks < 8; ++ks){
          sh[(c+1)&1][2*ks]   = ald(hp0 + (c+1)*512 + ks*64);
          sh[(c+1)&1][2*ks+1] = ald(hp0 + (c+1)*512 + ks*64 + 8);
          sc[(c+1)&1][2*ks]   = ald(cp0 + (c+1)*512 + ks*64);
          sc[(c+1)&1][2*ks+1] = ald(cp0 + (c+1)*512 + ks*64 + 8);
        }
        SCHEDB();
      }
      #pragma unroll
      for (int ks = 0; ks < 8; ++ks){
        FRAG bh; bh.q[0] = sh[c&1][2*ks]; bh.q[1] = sh[c&1][2*ks+1];
        FRAG bc; bc.q[0] = sc[c&1][2*ks]; bc.q[1] = sc[c&1][2*ks+1];
        int kb = (ks << 6) + (kg << 4);
        FRAG a;
        a.v = afL(lb, bl, kb);      A0 = MFMA16(a.v, bh.v, A0);
        a.v = afL(lb, 16 + bl, kb); A1 = MFMA16(a.v, bh.v, A1);
        a.v = afL(lb, 32 + bl, kb); A2 = MFMA16(a.v, bh.v, A2);
        a.v = afL(lb, 48 + bl, kb); A3 = MFMA16(a.v, bh.v, A3);
        a.v = afL(lb, 64 + bl, kb); A4 = MFMA16(a.v, bc.v, A4);
      }
    }
    int jj = (wg << 4) + (kg << 2);
    P4 hw, cw; F4 cf4;
    #pragma unroll
    for (int r = 0; r < 4; ++r){
      float gi = A0[r] + b_cell[i*4096 + jj + r];
      float gf = A1[r] + b_cell[i*4096 + 1024 + jj + r];
      float gg = A2[r] + b_cell[i*4096 + 2048 + jj + r];
      float go = A3[r] + b_cell[i*4096 + 3072 + jj + r];
      float c1 = A4[r] + cAb[i*1024 + jj + r];
      float cn = sigm(gf)*c1 + sigm(gi)*tanh_(gg);
      hw.s[r] = f2bf(sigm(go)*tanh_(cn));
      cw.s[r] = f2bf(cn);
      cf4.f[r] = cn;
    }
    ast(hOut + ((size_t)b << 10) + jj, hw.q);
    ast(cOut + ((size_t)b << 10) + jj, cw.q);
    if (last){
      char* cfp = (char*)(cF + ((size_t)b << 10) + jj);
      ast(cfp, cf4.q[0]); ast(cfp + 8, cf4.q[1]);
    }
  };

  // ---- ccA phase (wg 64..83, with cell i==3): cc = lastCA@c + b_cc
  auto phase_ccA = [&](const u16* cIn){
    f32x4 A = {0,0,0,0};
    int w2 = wg - 64;
    const u16* Wb = WccA + ((size_t)w2 << 14);
    const char* cp0 = (const char*)(cIn + ((size_t)b << 10) + (kg << 3));
    u64 sc[2][16];
    stage_async(Wb, ldsW, 2);
    #pragma unroll
    for (int ks = 0; ks < 8; ++ks){
      sc[0][2*ks]   = ald(cp0 + ks*64);
      sc[0][2*ks+1] = ald(cp0 + ks*64 + 8);
    }
    SCHEDB();
    #pragma unroll
    for (int c = 0; c < 4; ++c){
      const u16* lb = ldsW + (c & 1)*20480;
      VBAR(16);
      if (c < 3){
        stage_async(Wb + (size_t)(c+1)*4096, ldsW + ((c+1)&1)*20480, 2);
        #pragma unroll
        for (int ks = 0; ks < 8; ++ks){
          sc[(c+1)&1][2*ks]   = ald(cp0 + (c+1)*512 + ks*64);
          sc[(c+1)&1][2*ks+1] = ald(cp0 + (c+1)*512 + ks*64 + 8);
        }
        SCHEDB();
      }
      #pragma unroll
      for (int ks = 0; ks < 8; ++ks){
        FRAG bc; bc.q[0] = sc[c&1][2*ks]; bc.q[1] = sc[c&1][2*ks+1];
        int kb = (ks << 6) + (kg << 4);
        FRAG a; a.v = afL(lb, bl, kb);
        A = MFMA16(a.v, bc.v, A);
      }
    }
    int jjo = (w2 << 4) + (kg << 2);
    F4 v;
    #pragma unroll
    for (int r = 0; r < 4; ++r) v.f[r] = A[r] + b_cc[jjo + r];
    char* cp2 = (char*)(ccB + (size_t)b*320 + jjo);
    ast(cp2, v.q[0]); ast(cp2 + 8, v.q[1]);
  };

  // ---- out-cell phase (wg 64..83): gates = W_out_eff@h2_4 + b; c = cc
  auto phase_out = [&](int t, const u16* hIn){
    f32x4 A0={0,0,0,0}, A1={0,0,0,0}, A2={0,0,0,0}, A3={0,0,0,0};
    int w2 = wg - 64;
    const u16* Wb = Wout + ((size_t)w2 << 16);
    const char* hp0 = (const char*)(hIn + ((size_t)b << 10) + (kg << 3));
    u64 sh[2][16];
    stage_async(Wb, ldsW, 8);
    #pragma unroll
    for (int ks = 0; ks < 8; ++ks){
      sh[0][2*ks]   = ald(hp0 + ks*64);
      sh[0][2*ks+1] = ald(hp0 + ks*64 + 8);
    }
    SCHEDB();
    #pragma unroll
    for (int c = 0; c < 4; ++c){
      const u16* lb = ldsW + (c & 1)*20480;
      VBAR(16);
      if (c < 3){
        stage_async(Wb + (size_t)(c+1)*16384, ldsW + ((c+1)&1)*20480, 8);
        #pragma unroll
        for (int ks = 0; ks < 8; ++ks){
          sh[(c+1)&1][2*ks]   = ald(hp0 + (c+1)*512 + ks*64);
          sh[(c+1)&1][2*ks+1] = ald(hp0 + (c+1)*512 + ks*64 + 8);
        }
        SCHEDB();
      }
      #pragma unroll
      for (int ks = 0; ks < 8; ++ks){
        FRAG bh; bh.q[0] = sh[c&1][2*ks]; bh.q[1] = sh[c&1][2*ks+1];
        int kb = (ks << 6) + (kg << 4);
        FRAG a;
        a.v = afL(lb, bl, kb);      A0 = MFMA16(a.v, bh.v, A0);
        a.v = afL(lb, 16 + bl, kb); A1 = MFMA16(a.v, bh.v, A1);
        a.v = afL(lb, 32 + bl, kb); A2 = MFMA16(a.v, bh.v, A2);
        a.v = afL(lb, 48 + bl, kb); A3 = MFMA16(a.v, bh.v, A3);
      }
    }
    int jjo = (w2 << 4) + (kg << 2);
    F4 cc4;
    const char* ccp = (const char*)(ccB + (size_t)b*320 + jjo);
    cc4.q[0] = ald(ccp); cc4.q[1] = ald(ccp + 8);
    f32x4 ho;
    #pragma unroll
    for (int r = 0; r < 4; ++r){
      float gi = A0[r] + b_out[jjo + r];
      float gf = A1[r] + b_out[320 + jjo + r];
      float gg = A2[r] + b_out[640 + jjo + r];
      float go = A3[r] + b_out[960 + jjo + r];
      float cn = sigm(gf)*cc4.f[r] + sigm(gi)*tanh_(gg);
      ho[r] = sigm(go)*tanh_(cn);
    }
    *(f32x4*)(outp + (size_t)b*81920 + (size_t)(t+1)*320 + jjo) = ho;
  };

  // ---- main schedule
  u16* hB0 = hS;        u16* hB1 = hS + 65536;
  u16* cB0 = cS;        u16* cB1 = cS + 65536;

  if (wg < 64) phase_incell(0, hB1, hB0, cB0);
  gbar(bar, 0);
  int p = 1;
  #pragma unroll 1
  for (int t = 0; t < 255; ++t){
    #pragma unroll 1
    for (int i = 0; i < 4; ++i){
      u16* hIn = (p & 1) ? hB0 : hB1;  u16* cIn = (p & 1) ? cB0 : cB1;
      u16* hOut = (p & 1) ? hB1 : hB0; u16* cOut = (p & 1) ? cB1 : cB0;
      if (wg < 64)      phase_cell(i, hIn, cIn, hOut, cOut, i == 3);
      else if (i == 3)  phase_ccA(cIn);
      gbar(bar, p); ++p;
    }
    u16* hIn = (p & 1) ? hB0 : hB1;
    u16* hOut = (p & 1) ? hB1 : hB0; u16* cOut = (p & 1) ? cB1 : cB0;
    if (wg >= 64)       phase_out(t, hIn);
    else if (t < 254)   phase_incell(t + 1, hIn, hOut, cOut);
    gbar(bar, p); ++p;
  }
}

// ---------------------------------------------------------------------------
// Precompute kernels (unchanged)
// ---------------------------------------------------------------------------

__global__ __launch_bounds__(256) void k_dense(const float* __restrict__ X, int xmode,
    const float* __restrict__ W, const float* __restrict__ bias,
    int OD, int ID, int act, int omode, float* outF, u16* outB)
{
  int o = blockIdx.x*4 + (threadIdx.x >> 6);
  if (o >= OD) return;
  int lane = threadIdx.x & 63;
  const float* wr = W + (size_t)o*ID;
  float acc = 0.f;
  if (xmode == 0){ for (int k = 0; k < ID; ++k) acc = fmaf(wr[k], X[(size_t)lane*ID + k], acc); }
  else           { for (int k = 0; k < ID; ++k) acc = fmaf(wr[k], X[(size_t)k*64 + lane], acc); }
  acc += bias[o];
  if (act) acc = acc * sigm(acc);
  if (omode == 0)      outF[(size_t)o*64 + lane] = acc;
  else if (omode == 1) outB[(size_t)lane*1024 + o] = f2bf(acc);
  else if (omode == 2) outF[(size_t)lane*1024 + o] = acc;
  else                 outF[(size_t)lane*81920 + 256 + o] = acc;
}

__global__ void k_zero0(float* out){ out[(size_t)blockIdx.x*81920 + threadIdx.x] = 0.f; }

__global__ __launch_bounds__(256) void k_tr(const float* __restrict__ in, u16* __restrict__ out, int M, int N){
  __shared__ u16 t[64][65];
  int m0 = blockIdx.x << 6, n0 = blockIdx.y << 6;
  int c = threadIdx.x & 63, rq = threadIdx.x >> 6;
  for (int rr = 0; rr < 16; ++rr){
    int r = (rq << 4) + rr;
    t[r][c] = f2bf(in[(size_t)(m0 + r)*N + n0 + c]);
  }
  __syncthreads();
  for (int rr = 0; rr < 16; ++rr){
    int r = (rq << 4) + rr;
    out[(size_t)(n0 + r)*M + m0 + c] = t[c][r];
  }
}

__global__ __launch_bounds__(256) void k_fuse(const float* __restrict__ Whh, const float* __restrict__ Wih,
    const u16* __restrict__ BT, int KM, int mode, u16* __restrict__ dst)
{
  int bx = blockIdx.x, by = blockIdx.y, bz = blockIdx.z;
  int lane = threadIdx.x & 63, wv = threadIdx.x >> 6;
  int bl = lane & 15, kg = lane >> 4;
  int jbase = (mode == 0) ? bz*1024 : ((mode == 1) ? bz*320 : 0);
  int jrow = jbase + bx*16 + bl;
  int k2c = by*64 + wv*16 + bl;
  f32x4 acc = {0,0,0,0};
  for (int m0 = 0; m0 < KM; m0 += 32){
    f32x4 wa0 = *(const f32x4*)(Whh + (size_t)jrow*KM + m0 + (kg << 3));
    f32x4 wa1 = *(const f32x4*)(Whh + (size_t)jrow*KM + m0 + (kg << 3) + 4);
    FRAG a;
    a.s[0]=f2bf(wa0[0]); a.s[1]=f2bf(wa0[1]); a.s[2]=f2bf(wa0[2]); a.s[3]=f2bf(wa0[3]);
    a.s[4]=f2bf(wa1[0]); a.s[5]=f2bf(wa1[1]); a.s[6]=f2bf(wa1[2]); a.s[7]=f2bf(wa1[3]);
    FRAG bb; bb.v = *(const bf16x8*)(BT + (size_t)k2c*KM + m0 + (kg << 3));
    acc = MFMA16(a.v, bb.v, acc);
  }
  #pragma unroll
  for (int r = 0; r < 4; ++r){
    int jl = (kg << 2) + r;
    int jg = jbase + bx*16 + jl;
    float v = acc[r];
    if (mode < 2) v += Wih[(size_t)jg*1024 + k2c];
    int re = (mode == 2) ? jl : (bz*16 + jl);
    int c = k2c >> 8, kl = k2c & 255;
    size_t pos;
    if (mode == 0)      pos = (size_t)bx*81920 + c*20480 + re*256 + (kl ^ ((re&7)<<3));
    else if (mode == 1) pos = (size_t)bx*65536 + c*16384 + re*256 + (kl ^ ((re&7)<<3));
    else                pos = (size_t)bx*16384 + c*4096  + re*256 + (kl ^ ((re&7)<<3));
    dst[pos] = f2bf(v);
  }
}

__global__ void k_pack_winh(const float* __restrict__ src, u16* __restrict__ dst){
  int id = blockIdx.x*256 + threadIdx.x;
  int j = id >> 10, k = id & 1023;
  int g = j >> 10, jj = j & 1023;
  int w = jj >> 4, r = (g << 4) + (jj & 15);
  int c = k >> 8, kl = k & 255;
  dst[(size_t)w*65536 + c*16384 + r*256 + (kl ^ ((r&7)<<3))] = f2bf(src[id]);
}

__global__ void k_pack_winx(const float* __restrict__ src, u16* __restrict__ dst){
  int j = blockIdx.x, k = threadIdx.x;
  int g = j >> 10, jj = j & 1023;
  int w = jj >> 4, r = (g << 4) + (jj & 15);
  float v = src[(size_t)j*320 + k];
  size_t pos;
  if (k < 256) pos = (size_t)w*20480 + r*256 + (k ^ ((r&7)<<3));
  else         pos = (size_t)w*20480 + 16384 + r*64 + ((k - 256) ^ ((r&7)<<3));
  dst[pos] = f2bf(v);
}

__global__ void k_pack_ca(const float* __restrict__ src, u16* __restrict__ dst){
  int id = blockIdx.x*256 + threadIdx.x;
  int jj = id >> 10, k = id & 1023;
  int w = jj >> 4, r = 64 + (jj & 15);
  int c = k >> 8, kl = k & 255;
  dst[(size_t)w*81920 + c*20480 + r*256 + (kl ^ ((r&7)<<3))] = f2bf(src[id]);
}

__global__ __launch_bounds__(256) void k_bias(const float* __restrict__ A, const float* __restrict__ x,
    const float* __restrict__ a1, const float* __restrict__ a2, float* __restrict__ o, int NJ, int K)
{
  int j = blockIdx.x*4 + (threadIdx.x >> 6);
  if (j >= NJ) return;
  int lane = threadIdx.x & 63;
  float acc = 0.f;
  if (A) for (int k = lane; k < K; k += 64) acc += A[(size_t)j*K + k]*x[k];
  for (int off = 32; off; off >>= 1) acc += __shfl_down(acc, off);
  if (lane == 0) o[j] = acc + (a1 ? a1[j] : 0.f) + (a2 ? a2[j] : 0.f);
}

// ---------------------------------------------------------------------------
extern "C" void kernel_launch(void* const* d_in, const int* in_sizes, int n_in,
                              void* d_out, int out_size, void* d_ws, size_t ws_size,
                              hipStream_t stream)
{
  (void)in_sizes; (void)n_in; (void)out_size;
  const float* z      = (const float*)d_in[0];
  const float* m_true = (const float*)d_in[1];
  const float* eh_W1=(const float*)d_in[2],  *eh_b1=(const float*)d_in[3];
  const float* eh_W2=(const float*)d_in[4],  *eh_b2=(const float*)d_in[5];
  const float* eh_W3=(const float*)d_in[6],  *eh_b3=(const float*)d_in[7];
  const float* ec_W1=(const float*)d_in[8],  *ec_b1=(const float*)d_in[9];
  const float* ec_W2=(const float*)d_in[10], *ec_b2=(const float*)d_in[11];
  const float* ec_W3=(const float*)d_in[12], *ec_b3=(const float*)d_in[13];
  const float* ex_W1=(const float*)d_in[14], *ex_b1=(const float*)d_in[15];
  const float* ex_W2=(const float*)d_in[16], *ex_b2=(const float*)d_in[17];
  const float* ex_W3=(const float*)d_in[18], *ex_b3=(const float*)d_in[19];
  const float* in_Wih=(const float*)d_in[20], *in_Whh=(const float*)d_in[21];
  const float* in_bih=(const float*)d_in[22], *in_bhh=(const float*)d_in[23];
  const float* r_Wih=(const float*)d_in[24],  *r_Whh=(const float*)d_in[25];
  const float* r_bih=(const float*)d_in[26],  *r_bhh=(const float*)d_in[27];
  const float* hA_W=(const float*)d_in[28],   *hA_b=(const float*)d_in[29];
  const float* cA_W=(const float*)d_in[30],   *cA_b=(const float*)d_in[31];
  const float* lastH_W=(const float*)d_in[32], *lastH_b=(const float*)d_in[33];
  const float* lastC_W=(const float*)d_in[34], *lastC_b=(const float*)d_in[35];
  const float* out_Wih=(const float*)d_in[36], *out_Whh=(const float*)d_in[37];
  const float* out_bih=(const float*)d_in[38], *out_bhh=(const float*)d_in[39];
  float* out = (float*)d_out;

  char* wsb = (char*)d_ws;
  size_t off = 0;
  auto alloc = [&](size_t bytes)->char*{
    char* p = wsb + off; off = (off + bytes + 255) & ~(size_t)255; return p;
  };
  u32* bar    = (u32*)alloc(2048*4);
  u16* hS     = (u16*)alloc(2*64*1024*2);
  u16* cS     = (u16*)alloc(2*64*1024*2);
  float* cF   = (float*)alloc(64*1024*4);
  float* ccB  = (float*)alloc(64*320*4);
  float* b_in = (float*)alloc(4096*4);
  float* b_cell=(float*)alloc(4*4096*4);
  float* b_out= (float*)alloc(1280*4);
  float* b_cc = (float*)alloc(320*4);
  float* t1   = (float*)alloc(1024*64*4);
  float* t2   = (float*)alloc(1024*64*4);
  u16* Tbuf   = (u16*)alloc((size_t)1024*1024*2);
  u16* Win_h  = (u16*)alloc((size_t)64*65536*2);
  u16* Win_x  = (u16*)alloc((size_t)64*20480*2);
  u16* Wcell  = (u16*)alloc((size_t)4*64*81920*2);
  u16* Wout   = (u16*)alloc((size_t)20*65536*2);
  u16* WccA   = (u16*)alloc((size_t)20*16384*2);
  if (off > ws_size) return;

  hipMemsetAsync(bar, 0, 2048*4, stream);

  k_dense<<<256,256,0,stream>>>(z, 0, eh_W1, eh_b1, 1024, 256, 1, 0, t1, nullptr);
  k_dense<<<256,256,0,stream>>>(t1,1, eh_W2, eh_b2, 1024,1024, 1, 0, t2, nullptr);
  k_dense<<<256,256,0,stream>>>(t2,1, eh_W3, eh_b3, 1024,1024, 0, 1, nullptr, hS + 65536);
  k_dense<<<256,256,0,stream>>>(z, 0, ec_W1, ec_b1, 1024, 256, 1, 0, t1, nullptr);
  k_dense<<<256,256,0,stream>>>(t1,1, ec_W2, ec_b2, 1024,1024, 1, 0, t2, nullptr);
  k_dense<<<256,256,0,stream>>>(t2,1, ec_W3, ec_b3, 1024,1024, 0, 2, cF, nullptr);
  k_dense<<<256,256,0,stream>>>(z, 0, ex_W1, ex_b1, 1024, 256, 1, 0, t1, nullptr);
  k_dense<<<256,256,0,stream>>>(t1,1, ex_W2, ex_b2, 1024,1024, 1, 0, t2, nullptr);
  k_dense<<<16 ,256,0,stream>>>(t2,1, ex_W3, ex_b3,   64,1024, 0, 3, out, nullptr);
  k_zero0<<<64,256,0,stream>>>(out);

  k_pack_winh<<<16384,256,0,stream>>>(in_Whh, Win_h);
  k_pack_winx<<<4096,320,0,stream>>>(in_Wih, Win_x);
  for (int i = 0; i < 4; ++i)
    k_pack_ca<<<4096,256,0,stream>>>(cA_W + (size_t)i*1024*1024, Wcell + (size_t)i*64*81920);

  for (int i = 0; i < 4; ++i){
    k_tr<<<dim3(16,16),256,0,stream>>>(hA_W + (size_t)i*1024*1024, Tbuf, 1024, 1024);
    k_fuse<<<dim3(64,16,4),256,0,stream>>>(r_Whh + (size_t)i*4096*1024,
                                           r_Wih + (size_t)i*4096*1024,
                                           Tbuf, 1024, 0, Wcell + (size_t)i*64*81920);
  }
  k_tr<<<dim3(5,16),256,0,stream>>>(lastH_W, Tbuf, 320, 1024);
  k_fuse<<<dim3(20,16,4),256,0,stream>>>(out_Whh, out_Wih, Tbuf, 320, 1, Wout);
  k_tr<<<dim3(16,16),256,0,stream>>>(cA_W + (size_t)3*1024*1024, Tbuf, 1024, 1024);
  k_fuse<<<dim3(20,16,1),256,0,stream>>>(lastC_W, nullptr, Tbuf, 1024, 2, WccA);

  k_bias<<<1024,256,0,stream>>>(nullptr, nullptr, in_bih, in_bhh, b_in, 4096, 0);
  for (int i = 0; i < 4; ++i)
    k_bias<<<1024,256,0,stream>>>(r_Whh + (size_t)i*4096*1024, hA_b + i*1024,
                                  r_bih + i*4096, r_bhh + i*4096, b_cell + i*4096, 4096, 1024);
  k_bias<<<320,256,0,stream>>>(out_Whh, lastH_b, out_bih, out_bhh, b_out, 1280, 320);
  k_bias<<<80 ,256,0,stream>>>(lastC_W, cA_b + 3*1024, lastC_b, nullptr, b_cc, 320, 1024);

  k_scan<<<NWG,256,0,stream>>>(m_true, Wcell, Win_h, Win_x, Wout, WccA,
                               b_in, b_cell, cA_b, b_out, b_cc,
                               hS, cS, cF, ccB, out, bar);
}

// Round 3
// 28620.636 us; speedup vs baseline: 1.3796x; 1.1890x over previous
//
#include <hip/hip_runtime.h>

// BigARDecoder: persistent-kernel LSTM scan on MI355X.
// B=64, T=256, IN=256, H=1024, G=256, O=64, D=4, GO=320.
//
// R3: distributed RELAXED barrier (per-WG arrive lines + master WG + 21
// replicated go-lines) replacing the centralized release-counter barrier
// (~22us/phase fixed cost). Next-phase chunk0 weights prefetch under the
// barrier wait. Literal counted vmcnt + raw s_barrier chunk pipeline.
// Biases staged to LDS once.

typedef unsigned int u32;
typedef unsigned long long u64;
typedef unsigned short u16;
typedef __attribute__((ext_vector_type(8))) __bf16 bf16x8;
typedef __attribute__((ext_vector_type(4))) float f32x4;

#define DEVI __device__ __forceinline__

union FRAG { bf16x8 v; u16 s[8]; u64 q[2]; };
union P4 { u64 q; u16 s[4]; };
union F4 { u64 q[2]; float f[4]; };

DEVI u16 f2bf(float x){ u32 u = __float_as_uint(x); return (u16)((u + 0x7fffu + ((u>>16)&1u)) >> 16); }
DEVI float sigm(float x){ return 1.0f/(1.0f + __expf(-x)); }
DEVI float tanh_(float x){ return 2.0f/(1.0f + __expf(-2.0f*x)) - 1.0f; }
DEVI u64 ald(const void* p){ return __hip_atomic_load((const u64*)p, __ATOMIC_RELAXED, __HIP_MEMORY_SCOPE_AGENT); }
DEVI void ast(void* p, u64 v){ __hip_atomic_store((u64*)p, v, __ATOMIC_RELAXED, __HIP_MEMORY_SCOPE_AGENT); }

#define MFMA16(a,b,c) __builtin_amdgcn_mfma_f32_16x16x32_bf16(a, b, c, 0, 0, 0)

#define NCOMP 84
#define NWG 85
#define NREP 21
#define NEPOCH 1276

#define SCHEDB() __builtin_amdgcn_sched_barrier(0)
#define WAITV(n) do{ SCHEDB(); \
  asm volatile("s_waitcnt vmcnt(" #n ")" ::: "memory"); \
  SCHEDB(); }while(0)
#define BARW() do{ __builtin_amdgcn_s_barrier(); SCHEDB(); }while(0)

// ---------------------------------------------------------------------------
// Persistent scan kernel. 85 WGs x 256 threads. WG84 = barrier master.
// WGs 0..63: hidden-unit tiles (16 jj each). WGs 64..83: out-cell / ccA tiles.
// ---------------------------------------------------------------------------
__global__ __launch_bounds__(256, 1) void k_scan(
    const float* __restrict__ m_true,
    const u16* __restrict__ Wcell, const u16* __restrict__ Win_h,
    const u16* __restrict__ Win_x, const u16* __restrict__ Wout,
    const u16* __restrict__ WccA,
    const float* __restrict__ b_in, const float* __restrict__ b_cell,
    const float* __restrict__ cAb, const float* __restrict__ b_out,
    const float* __restrict__ b_cc,
    u16* hS, u16* cS, float* cF, float* ccB, float* outp, u32* bar)
{
  const int wg = blockIdx.x;
  const int tid = threadIdx.x;
  const int wave = tid >> 6, lane = tid & 63;

  // ---- master WG: flat-combining barrier server, all RELAXED ----
  if (wg == NCOMP){
    if (wave == 0){
      u32* arr = bar;
      u32* go  = bar + NCOMP*32;
      for (u32 ep = 1; ep <= NEPOCH; ++ep){
        for(;;){
          int ok = 1;
          if (lane < 42){
            u32 a0 = __hip_atomic_load(arr + lane*32,      __ATOMIC_RELAXED, __HIP_MEMORY_SCOPE_AGENT);
            u32 a1 = __hip_atomic_load(arr + (lane+42)*32, __ATOMIC_RELAXED, __HIP_MEMORY_SCOPE_AGENT);
            ok = (a0 >= ep) && (a1 >= ep);
          }
          if (__all(ok)) break;
          __builtin_amdgcn_s_sleep(1);
        }
        if (lane < NREP)
          __hip_atomic_store(go + lane*32, ep, __ATOMIC_RELAXED, __HIP_MEMORY_SCOPE_AGENT);
      }
    }
    return;
  }

  const int bl = lane & 15, kg = lane >> 4;
  const int b = (wave << 4) + bl;
  const int swz = (bl & 7) << 4;
  __shared__ __align__(16) u16 ldsW[40960 + 1024];   // 2x40KB weights + 2KB bias
  float* fb = (float*)(ldsW + 40960);

  auto stage_async = [&](const u16* src, u16* lb, int spw){
    const u16* g = src + ((size_t)(wave*spw) << 9) + (lane << 3);
    u16* l = lb + ((wave*spw) << 9);
    for (int s = 0; s < spw; ++s){
      __builtin_amdgcn_global_load_lds(
          (const __attribute__((address_space(1))) void*)g,
          (__attribute__((address_space(3))) void*)l, 16, 0, 0);
      g += 512; l += 512;
    }
    SCHEDB();
  };
  auto afL = [&](const u16* lb, int row, int kb) -> bf16x8 {
    return *(const bf16x8*)((const char*)lb + row*512 + (kb ^ swz));
  };

  // distributed barrier + next-phase chunk0 prefetch under the wait
  auto gsync = [&](u32 ep, const u16* pfsrc, int pfspw){
    SCHEDB();
    __syncthreads();                  // drains vmcnt(0): all state stores visible
    if (tid == 0)
      __hip_atomic_store(bar + wg*32, ep, __ATOMIC_RELAXED, __HIP_MEMORY_SCOPE_AGENT);
    if (pfsrc){
      const u16* g = pfsrc + ((size_t)(wave*pfspw) << 9) + (lane << 3);
      u16* l = ldsW + ((wave*pfspw) << 9);
      for (int s = 0; s < pfspw; ++s){
        __builtin_amdgcn_global_load_lds(
            (const __attribute__((address_space(1))) void*)g,
            (__attribute__((address_space(3))) void*)l, 16, 0, 0);
        g += 512; l += 512;
      }
    }
    SCHEDB();
    if (tid == 0){
      const u32* gp = bar + NCOMP*32 + (wg % NREP)*32;
      while (__hip_atomic_load(gp, __ATOMIC_RELAXED, __HIP_MEMORY_SCOPE_AGENT) < ep)
        __builtin_amdgcn_s_sleep(1);
      asm volatile("" ::: "memory");
    }
    __syncthreads();                  // drains prefetch -> buf0 ready
    SCHEDB();
  };

  // ---- in-cell phase (wg<64). entry: buf0 = Win_h chunk0 (prefetched)
  auto phase_incell = [&](int t, const u16* hIn, u16* hOut, u16* cOut){
    f32x4 A0={0,0,0,0}, A1={0,0,0,0}, A2={0,0,0,0}, A3={0,0,0,0};
    const float* xr = m_true + (size_t)b*81920 + (size_t)(255 - t)*320;
    FRAG xf[10];
    #pragma unroll
    for (int ks = 0; ks < 10; ++ks){
      int k = (ks << 5) + (kg << 3);
      f32x4 x0 = *(const f32x4*)(xr + k);
      f32x4 x1 = *(const f32x4*)(xr + k + 4);
      xf[ks].s[0]=f2bf(x0[0]); xf[ks].s[1]=f2bf(x0[1]); xf[ks].s[2]=f2bf(x0[2]); xf[ks].s[3]=f2bf(x0[3]);
      xf[ks].s[4]=f2bf(x1[0]); xf[ks].s[5]=f2bf(x1[1]); xf[ks].s[6]=f2bf(x1[2]); xf[ks].s[7]=f2bf(x1[3]);
    }
    SCHEDB();
    const u16* Wb = Win_h + ((size_t)wg << 16);
    const char* hp0 = (const char*)(hIn + ((size_t)b << 10) + (kg << 3));
    int jl = (kg << 2), jj = (wg << 4) + jl;
    const char* cfp = (const char*)(cF + ((size_t)b << 10) + jj);
    u64 sh[2][16]; F4 cp4;
    #pragma unroll
    for (int ks = 0; ks < 8; ++ks){
      sh[0][2*ks]   = ald(hp0 + ks*64);
      sh[0][2*ks+1] = ald(hp0 + ks*64 + 8);
    }
    cp4.q[0] = ald(cfp); cp4.q[1] = ald(cfp + 8);
    SCHEDB();
    stage_async(Wb + 16384, ldsW + 20480, 8);      // S1 -> buf1
    #pragma unroll
    for (int c = 0; c < 4; ++c){
      if (c > 0){
        BARW();                                     // done reading buf[(c+1)&1]
        if (c < 3) stage_async(Wb + (size_t)(c+1)*16384, ldsW + ((c+1)&1)*20480, 8);
        else       stage_async(Win_x + (size_t)wg*20480, ldsW, 10);   // x -> buf0
      }
      if (c == 3) { WAITV(10); } else { WAITV(8); } // own stage S_c + loads L_c done
      if (c > 0) BARW();                            // cross-wave S_c drained
      if (c < 3){
        #pragma unroll
        for (int ks = 0; ks < 8; ++ks){
          sh[(c+1)&1][2*ks]   = ald(hp0 + (c+1)*512 + ks*64);
          sh[(c+1)&1][2*ks+1] = ald(hp0 + (c+1)*512 + ks*64 + 8);
        }
        SCHEDB();
      }
      const u16* lb = ldsW + (c & 1)*20480;
      #pragma unroll
      for (int ks = 0; ks < 8; ++ks){
        FRAG bh; bh.q[0] = sh[c&1][2*ks]; bh.q[1] = sh[c&1][2*ks+1];
        int kb = (ks << 6) + (kg << 4);
        FRAG a;
        a.v = afL(lb, bl, kb);      A0 = MFMA16(a.v, bh.v, A0);
        a.v = afL(lb, 16 + bl, kb); A1 = MFMA16(a.v, bh.v, A1);
        a.v = afL(lb, 32 + bl, kb); A2 = MFMA16(a.v, bh.v, A2);
        a.v = afL(lb, 48 + bl, kb); A3 = MFMA16(a.v, bh.v, A3);
      }
    }
    WAITV(0); BARW();                               // x chunk ready in buf0
    #pragma unroll
    for (int ks = 0; ks < 8; ++ks){
      int kb = (ks << 6) + (kg << 4);
      FRAG a;
      a.v = afL(ldsW, bl, kb);      A0 = MFMA16(a.v, xf[ks].v, A0);
      a.v = afL(ldsW, 16 + bl, kb); A1 = MFMA16(a.v, xf[ks].v, A1);
      a.v = afL(ldsW, 32 + bl, kb); A2 = MFMA16(a.v, xf[ks].v, A2);
      a.v = afL(ldsW, 48 + bl, kb); A3 = MFMA16(a.v, xf[ks].v, A3);
    }
    #pragma unroll
    for (int ks = 0; ks < 2; ++ks){
      int kb = (ks << 6) + (kg << 4);
      FRAG a;
      a.v = *(const bf16x8*)((const char*)ldsW + 32768 + bl*128      + (kb ^ swz)); A0 = MFMA16(a.v, xf[8+ks].v, A0);
      a.v = *(const bf16x8*)((const char*)ldsW + 32768 + (16+bl)*128 + (kb ^ swz)); A1 = MFMA16(a.v, xf[8+ks].v, A1);
      a.v = *(const bf16x8*)((const char*)ldsW + 32768 + (32+bl)*128 + (kb ^ swz)); A2 = MFMA16(a.v, xf[8+ks].v, A2);
      a.v = *(const bf16x8*)((const char*)ldsW + 32768 + (48+bl)*128 + (kb ^ swz)); A3 = MFMA16(a.v, xf[8+ks].v, A3);
    }
    P4 hw, cw;
    #pragma unroll
    for (int r = 0; r < 4; ++r){
      float gi = A0[r] + fb[jl + r];
      float gf = A1[r] + fb[16 + jl + r];
      float gg = A2[r] + fb[32 + jl + r];
      float go = A3[r] + fb[48 + jl + r];
      float cn = sigm(gf)*cp4.f[r] + sigm(gi)*tanh_(gg);
      hw.s[r] = f2bf(sigm(go)*tanh_(cn));
      cw.s[r] = f2bf(cn);
    }
    ast(hOut + ((size_t)b << 10) + jj, hw.q);
    ast(cOut + ((size_t)b << 10) + jj, cw.q);
  };

  // ---- inner cell phase i (wg<64). entry: buf0 = Wcell_i chunk0
  auto phase_cell = [&](int i, const u16* hIn, const u16* cIn, u16* hOut, u16* cOut, bool last){
    f32x4 A0={0,0,0,0}, A1={0,0,0,0}, A2={0,0,0,0}, A3={0,0,0,0}, A4={0,0,0,0};
    const u16* Wb = Wcell + (size_t)(i*64 + wg) * 81920;
    const char* hp0 = (const char*)(hIn + ((size_t)b << 10) + (kg << 3));
    const char* cp0 = (const char*)(cIn + ((size_t)b << 10) + (kg << 3));
    u64 sh[2][16], sc[2][16];
    #pragma unroll
    for (int ks = 0; ks < 8; ++ks){
      sh[0][2*ks]   = ald(hp0 + ks*64);
      sh[0][2*ks+1] = ald(hp0 + ks*64 + 8);
      sc[0][2*ks]   = ald(cp0 + ks*64);
      sc[0][2*ks+1] = ald(cp0 + ks*64 + 8);
    }
    SCHEDB();
    stage_async(Wb + 20480, ldsW + 20480, 10);      // S1 -> buf1
    #pragma unroll
    for (int c = 0; c < 4; ++c){
      if (c > 0){
        BARW();
        if (c < 3) stage_async(Wb + (size_t)(c+1)*20480, ldsW + ((c+1)&1)*20480, 10);
      }
      if (c == 3) { WAITV(0); } else { WAITV(10); }
      if (c > 0) BARW();
      if (c < 3){
        #pragma unroll
        for (int ks = 0; ks < 8; ++ks){
          sh[(c+1)&1][2*ks]   = ald(hp0 + (c+1)*512 + ks*64);
          sh[(c+1)&1][2*ks+1] = ald(hp0 + (c+1)*512 + ks*64 + 8);
          sc[(c+1)&1][2*ks]   = ald(cp0 + (c+1)*512 + ks*64);
          sc[(c+1)&1][2*ks+1] = ald(cp0 + (c+1)*512 + ks*64 + 8);
        }
        SCHEDB();
      }
      const u16* lb = ldsW + (c & 1)*20480;
      #pragma unroll
      for (int ks = 0; ks < 8; ++ks){
        FRAG bh; bh.q[0] = sh[c&1][2*ks]; bh.q[1] = sh[c&1][2*ks+1];
        FRAG bc; bc.q[0] = sc[c&1][2*ks]; bc.q[1] = sc[c&1][2*ks+1];
        int kb = (ks << 6) + (kg << 4);
        FRAG a;
        a.v = afL(lb, bl, kb);      A0 = MFMA16(a.v, bh.v, A0);
        a.v = afL(lb, 16 + bl, kb); A1 = MFMA16(a.v, bh.v, A1);
        a.v = afL(lb, 32 + bl, kb); A2 = MFMA16(a.v, bh.v, A2);
        a.v = afL(lb, 48 + bl, kb); A3 = MFMA16(a.v, bh.v, A3);
        a.v = afL(lb, 64 + bl, kb); A4 = MFMA16(a.v, bc.v, A4);
      }
    }
    int jl = (kg << 2), jj = (wg << 4) + jl;
    P4 hw, cw; F4 cf4;
    #pragma unroll
    for (int r = 0; r < 4; ++r){
      float gi = A0[r] + fb[64 + i*80 + jl + r];
      float gf = A1[r] + fb[64 + i*80 + 16 + jl + r];
      float gg = A2[r] + fb[64 + i*80 + 32 + jl + r];
      float go = A3[r] + fb[64 + i*80 + 48 + jl + r];
      float c1 = A4[r] + fb[64 + i*80 + 64 + jl + r];
      float cn = sigm(gf)*c1 + sigm(gi)*tanh_(gg);
      hw.s[r] = f2bf(sigm(go)*tanh_(cn));
      cw.s[r] = f2bf(cn);
      cf4.f[r] = cn;
    }
    ast(hOut + ((size_t)b << 10) + jj, hw.q);
    ast(cOut + ((size_t)b << 10) + jj, cw.q);
    if (last){
      char* cfp = (char*)(cF + ((size_t)b << 10) + jj);
      ast(cfp, cf4.q[0]); ast(cfp + 8, cf4.q[1]);
    }
  };

  // ---- ccA phase (wg 64..83, with cell i==3). entry: buf0 = WccA chunk0
  auto phase_ccA = [&](const u16* cIn){
    f32x4 A = {0,0,0,0};
    int w2 = wg - 64;
    const u16* Wb = WccA + ((size_t)w2 << 14);
    const char* cp0 = (const char*)(cIn + ((size_t)b << 10) + (kg << 3));
    u64 sc[2][16];
    #pragma unroll
    for (int ks = 0; ks < 8; ++ks){
      sc[0][2*ks]   = ald(cp0 + ks*64);
      sc[0][2*ks+1] = ald(cp0 + ks*64 + 8);
    }
    SCHEDB();
    stage_async(Wb + 4096, ldsW + 20480, 2);
    #pragma unroll
    for (int c = 0; c < 4; ++c){
      if (c > 0){
        BARW();
        if (c < 3) stage_async(Wb + (size_t)(c+1)*4096, ldsW + ((c+1)&1)*20480, 2);
      }
      if (c == 3) { WAITV(0); } else { WAITV(2); }
      if (c > 0) BARW();
      if (c < 3){
        #pragma unroll
        for (int ks = 0; ks < 8; ++ks){
          sc[(c+1)&1][2*ks]   = ald(cp0 + (c+1)*512 + ks*64);
          sc[(c+1)&1][2*ks+1] = ald(cp0 + (c+1)*512 + ks*64 + 8);
        }
        SCHEDB();
      }
      const u16* lb = ldsW + (c & 1)*20480;
      #pragma unroll
      for (int ks = 0; ks < 8; ++ks){
        FRAG bc; bc.q[0] = sc[c&1][2*ks]; bc.q[1] = sc[c&1][2*ks+1];
        int kb = (ks << 6) + (kg << 4);
        FRAG a; a.v = afL(lb, bl, kb);
        A = MFMA16(a.v, bc.v, A);
      }
    }
    int jl = (kg << 2), jjo = (w2 << 4) + jl;
    F4 v;
    #pragma unroll
    for (int r = 0; r < 4; ++r) v.f[r] = A[r] + fb[64 + jl + r];
    char* cp2 = (char*)(ccB + (size_t)b*320 + jjo);
    ast(cp2, v.q[0]); ast(cp2 + 8, v.q[1]);
  };

  // ---- out-cell phase (wg 64..83). entry: buf0 = Wout chunk0
  auto phase_out = [&](int t, const u16* hIn){
    f32x4 A0={0,0,0,0}, A1={0,0,0,0}, A2={0,0,0,0}, A3={0,0,0,0};
    int w2 = wg - 64;
    const u16* Wb = Wout + ((size_t)w2 << 16);
    const char* hp0 = (const char*)(hIn + ((size_t)b << 10) + (kg << 3));
    int jl = (kg << 2), jjo = (w2 << 4) + jl;
    const char* ccp = (const char*)(ccB + (size_t)b*320 + jjo);
    u64 sh[2][16]; F4 cc4;
    #pragma unroll
    for (int ks = 0; ks < 8; ++ks){
      sh[0][2*ks]   = ald(hp0 + ks*64);
      sh[0][2*ks+1] = ald(hp0 + ks*64 + 8);
    }
    cc4.q[0] = ald(ccp); cc4.q[1] = ald(ccp + 8);
    SCHEDB();
    stage_async(Wb + 16384, ldsW + 20480, 8);
    #pragma unroll
    for (int c = 0; c < 4; ++c){
      if (c > 0){
        BARW();
        if (c < 3) stage_async(Wb + (size_t)(c+1)*16384, ldsW + ((c+1)&1)*20480, 8);
      }
      if (c == 3) { WAITV(0); } else { WAITV(8); }
      if (c > 0) BARW();
      if (c < 3){
        #pragma unroll
        for (int ks = 0; ks < 8; ++ks){
          sh[(c+1)&1][2*ks]   = ald(hp0 + (c+1)*512 + ks*64);
          sh[(c+1)&1][2*ks+1] = ald(hp0 + (c+1)*512 + ks*64 + 8);
        }
        SCHEDB();
      }
      const u16* lb = ldsW + (c & 1)*20480;
      #pragma unroll
      for (int ks = 0; ks < 8; ++ks){
        FRAG bh; bh.q[0] = sh[c&1][2*ks]; bh.q[1] = sh[c&1][2*ks+1];
        int kb = (ks << 6) + (kg << 4);
        FRAG a;
        a.v = afL(lb, bl, kb);      A0 = MFMA16(a.v, bh.v, A0);
        a.v = afL(lb, 16 + bl, kb); A1 = MFMA16(a.v, bh.v, A1);
        a.v = afL(lb, 32 + bl, kb); A2 = MFMA16(a.v, bh.v, A2);
        a.v = afL(lb, 48 + bl, kb); A3 = MFMA16(a.v, bh.v, A3);
      }
    }
    f32x4 ho;
    #pragma unroll
    for (int r = 0; r < 4; ++r){
      float gi = A0[r] + fb[jl + r];
      float gf = A1[r] + fb[16 + jl + r];
      float gg = A2[r] + fb[32 + jl + r];
      float go = A3[r] + fb[48 + jl + r];
      float cn = sigm(gf)*cc4.f[r] + sigm(gi)*tanh_(gg);
      ho[r] = sigm(go)*tanh_(cn);
    }
    *(f32x4*)(outp + (size_t)b*81920 + (size_t)(t+1)*320 + jjo) = ho;
  };

  // ---- init: biases -> LDS, first chunk0 prefetch ----
  if (wg < 64){
    if (tid < 16){
      int q = tid, j0 = wg*16;
      for (int g = 0; g < 4; ++g) fb[g*16 + q] = b_in[g*1024 + j0 + q];
      for (int i2 = 0; i2 < 4; ++i2){
        for (int g = 0; g < 4; ++g)
          fb[64 + i2*80 + g*16 + q] = b_cell[i2*4096 + g*1024 + j0 + q];
        fb[64 + i2*80 + 64 + q] = cAb[i2*1024 + j0 + q];
      }
    }
    stage_async(Win_h + ((size_t)wg << 16), ldsW, 8);
  } else {
    if (tid < 16){
      int q = tid, j0 = (wg - 64)*16;
      for (int g = 0; g < 4; ++g) fb[g*16 + q] = b_out[g*320 + j0 + q];
      fb[64 + q] = b_cc[j0 + q];
    }
  }
  __syncthreads();
  SCHEDB();

  u16* hB0 = hS;        u16* hB1 = hS + 65536;
  u16* cB0 = cS;        u16* cB1 = cS + 65536;

  u32 ep = 1;
  if (wg < 64) phase_incell(0, hB1, hB0, cB0);
  gsync(ep++, (wg < 64) ? Wcell + (size_t)wg*81920 : nullptr, 10);
  int p = 1;
  #pragma unroll 1
  for (int t = 0; t < 255; ++t){
    #pragma unroll 1
    for (int i = 0; i < 4; ++i){
      u16* hIn = (p & 1) ? hB0 : hB1;  u16* cIn = (p & 1) ? cB0 : cB1;
      u16* hOut = (p & 1) ? hB1 : hB0; u16* cOut = (p & 1) ? cB1 : cB0;
      if (wg < 64)      phase_cell(i, hIn, cIn, hOut, cOut, i == 3);
      else if (i == 3)  phase_ccA(cIn);
      const u16* pf = nullptr; int spw = 0;
      if (wg < 64){
        if (i < 3){ pf = Wcell + (size_t)((i+1)*64 + wg)*81920; spw = 10; }
        else      { pf = Win_h + ((size_t)wg << 16);            spw = 8;  }
      } else {
        if (i == 2){ pf = WccA + ((size_t)(wg-64) << 14); spw = 2; }
        else if (i == 3){ pf = Wout + ((size_t)(wg-64) << 16); spw = 8; }
      }
      gsync(ep++, pf, spw);
      ++p;
    }
    u16* hIn = (p & 1) ? hB0 : hB1;
    u16* hOut = (p & 1) ? hB1 : hB0; u16* cOut = (p & 1) ? cB1 : cB0;
    if (wg >= 64)       phase_out(t, hIn);
    else if (t < 254)   phase_incell(t + 1, hIn, hOut, cOut);
    gsync(ep++, (wg < 64 && t < 254) ? Wcell + (size_t)wg*81920 : nullptr, 10);
    ++p;
  }
}

// ---------------------------------------------------------------------------
// Precompute kernels (unchanged)
// ---------------------------------------------------------------------------

__global__ __launch_bounds__(256) void k_dense(const float* __restrict__ X, int xmode,
    const float* __restrict__ W, const float* __restrict__ bias,
    int OD, int ID, int act, int omode, float* outF, u16* outB)
{
  int o = blockIdx.x*4 + (threadIdx.x >> 6);
  if (o >= OD) return;
  int lane = threadIdx.x & 63;
  const float* wr = W + (size_t)o*ID;
  float acc = 0.f;
  if (xmode == 0){ for (int k = 0; k < ID; ++k) acc = fmaf(wr[k], X[(size_t)lane*ID + k], acc); }
  else           { for (int k = 0; k < ID; ++k) acc = fmaf(wr[k], X[(size_t)k*64 + lane], acc); }
  acc += bias[o];
  if (act) acc = acc * sigm(acc);
  if (omode == 0)      outF[(size_t)o*64 + lane] = acc;
  else if (omode == 1) outB[(size_t)lane*1024 + o] = f2bf(acc);
  else if (omode == 2) outF[(size_t)lane*1024 + o] = acc;
  else                 outF[(size_t)lane*81920 + 256 + o] = acc;
}

__global__ void k_zero0(float* out){ out[(size_t)blockIdx.x*81920 + threadIdx.x] = 0.f; }

__global__ __launch_bounds__(256) void k_tr(const float* __restrict__ in, u16* __restrict__ out, int M, int N){
  __shared__ u16 t[64][65];
  int m0 = blockIdx.x << 6, n0 = blockIdx.y << 6;
  int c = threadIdx.x & 63, rq = threadIdx.x >> 6;
  for (int rr = 0; rr < 16; ++rr){
    int r = (rq << 4) + rr;
    t[r][c] = f2bf(in[(size_t)(m0 + r)*N + n0 + c]);
  }
  __syncthreads();
  for (int rr = 0; rr < 16; ++rr){
    int r = (rq << 4) + rr;
    out[(size_t)(n0 + r)*M + m0 + c] = t[c][r];
  }
}

__global__ __launch_bounds__(256) void k_fuse(const float* __restrict__ Whh, const float* __restrict__ Wih,
    const u16* __restrict__ BT, int KM, int mode, u16* __restrict__ dst)
{
  int bx = blockIdx.x, by = blockIdx.y, bz = blockIdx.z;
  int lane = threadIdx.x & 63, wv = threadIdx.x >> 6;
  int bl = lane & 15, kg = lane >> 4;
  int jbase = (mode == 0) ? bz*1024 : ((mode == 1) ? bz*320 : 0);
  int jrow = jbase + bx*16 + bl;
  int k2c = by*64 + wv*16 + bl;
  f32x4 acc = {0,0,0,0};
  for (int m0 = 0; m0 < KM; m0 += 32){
    f32x4 wa0 = *(const f32x4*)(Whh + (size_t)jrow*KM + m0 + (kg << 3));
    f32x4 wa1 = *(const f32x4*)(Whh + (size_t)jrow*KM + m0 + (kg << 3) + 4);
    FRAG a;
    a.s[0]=f2bf(wa0[0]); a.s[1]=f2bf(wa0[1]); a.s[2]=f2bf(wa0[2]); a.s[3]=f2bf(wa0[3]);
    a.s[4]=f2bf(wa1[0]); a.s[5]=f2bf(wa1[1]); a.s[6]=f2bf(wa1[2]); a.s[7]=f2bf(wa1[3]);
    FRAG bb; bb.v = *(const bf16x8*)(BT + (size_t)k2c*KM + m0 + (kg << 3));
    acc = MFMA16(a.v, bb.v, acc);
  }
  #pragma unroll
  for (int r = 0; r < 4; ++r){
    int jl = (kg << 2) + r;
    int jg = jbase + bx*16 + jl;
    float v = acc[r];
    if (mode < 2) v += Wih[(size_t)jg*1024 + k2c];
    int re = (mode == 2) ? jl : (bz*16 + jl);
    int c = k2c >> 8, kl = k2c & 255;
    size_t pos;
    if (mode == 0)      pos = (size_t)bx*81920 + c*20480 + re*256 + (kl ^ ((re&7)<<3));
    else if (mode == 1) pos = (size_t)bx*65536 + c*16384 + re*256 + (kl ^ ((re&7)<<3));
    else                pos = (size_t)bx*16384 + c*4096  + re*256 + (kl ^ ((re&7)<<3));
    dst[pos] = f2bf(v);
  }
}

__global__ void k_pack_winh(const float* __restrict__ src, u16* __restrict__ dst){
  int id = blockIdx.x*256 + threadIdx.x;
  int j = id >> 10, k = id & 1023;
  int g = j >> 10, jj = j & 1023;
  int w = jj >> 4, r = (g << 4) + (jj & 15);
  int c = k >> 8, kl = k & 255;
  dst[(size_t)w*65536 + c*16384 + r*256 + (kl ^ ((r&7)<<3))] = f2bf(src[id]);
}

__global__ void k_pack_winx(const float* __restrict__ src, u16* __restrict__ dst){
  int j = blockIdx.x, k = threadIdx.x;
  int g = j >> 10, jj = j & 1023;
  int w = jj >> 4, r = (g << 4) + (jj & 15);
  float v = src[(size_t)j*320 + k];
  size_t pos;
  if (k < 256) pos = (size_t)w*20480 + r*256 + (k ^ ((r&7)<<3));
  else         pos = (size_t)w*20480 + 16384 + r*64 + ((k - 256) ^ ((r&7)<<3));
  dst[pos] = f2bf(v);
}

__global__ void k_pack_ca(const float* __restrict__ src, u16* __restrict__ dst){
  int id = blockIdx.x*256 + threadIdx.x;
  int jj = id >> 10, k = id & 1023;
  int w = jj >> 4, r = 64 + (jj & 15);
  int c = k >> 8, kl = k & 255;
  dst[(size_t)w*81920 + c*20480 + r*256 + (kl ^ ((r&7)<<3))] = f2bf(src[id]);
}

__global__ __launch_bounds__(256) void k_bias(const float* __restrict__ A, const float* __restrict__ x,
    const float* __restrict__ a1, const float* __restrict__ a2, float* __restrict__ o, int NJ, int K)
{
  int j = blockIdx.x*4 + (threadIdx.x >> 6);
  if (j >= NJ) return;
  int lane = threadIdx.x & 63;
  float acc = 0.f;
  if (A) for (int k = lane; k < K; k += 64) acc += A[(size_t)j*K + k]*x[k];
  for (int off = 32; off; off >>= 1) acc += __shfl_down(acc, off);
  if (lane == 0) o[j] = acc + (a1 ? a1[j] : 0.f) + (a2 ? a2[j] : 0.f);
}

// ---------------------------------------------------------------------------
extern "C" void kernel_launch(void* const* d_in, const int* in_sizes, int n_in,
                              void* d_out, int out_size, void* d_ws, size_t ws_size,
                              hipStream_t stream)
{
  (void)in_sizes; (void)n_in; (void)out_size;
  const float* z      = (const float*)d_in[0];
  const float* m_true = (const float*)d_in[1];
  const float* eh_W1=(const float*)d_in[2],  *eh_b1=(const float*)d_in[3];
  const float* eh_W2=(const float*)d_in[4],  *eh_b2=(const float*)d_in[5];
  const float* eh_W3=(const float*)d_in[6],  *eh_b3=(const float*)d_in[7];
  const float* ec_W1=(const float*)d_in[8],  *ec_b1=(const float*)d_in[9];
  const float* ec_W2=(const float*)d_in[10], *ec_b2=(const float*)d_in[11];
  const float* ec_W3=(const float*)d_in[12], *ec_b3=(const float*)d_in[13];
  const float* ex_W1=(const float*)d_in[14], *ex_b1=(const float*)d_in[15];
  const float* ex_W2=(const float*)d_in[16], *ex_b2=(const float*)d_in[17];
  const float* ex_W3=(const float*)d_in[18], *ex_b3=(const float*)d_in[19];
  const float* in_Wih=(const float*)d_in[20], *in_Whh=(const float*)d_in[21];
  const float* in_bih=(const float*)d_in[22], *in_bhh=(const float*)d_in[23];
  const float* r_Wih=(const float*)d_in[24],  *r_Whh=(const float*)d_in[25];
  const float* r_bih=(const float*)d_in[26],  *r_bhh=(const float*)d_in[27];
  const float* hA_W=(const float*)d_in[28],   *hA_b=(const float*)d_in[29];
  const float* cA_W=(const float*)d_in[30],   *cA_b=(const float*)d_in[31];
  const float* lastH_W=(const float*)d_in[32], *lastH_b=(const float*)d_in[33];
  const float* lastC_W=(const float*)d_in[34], *lastC_b=(const float*)d_in[35];
  const float* out_Wih=(const float*)d_in[36], *out_Whh=(const float*)d_in[37];
  const float* out_bih=(const float*)d_in[38], *out_bhh=(const float*)d_in[39];
  float* out = (float*)d_out;

  char* wsb = (char*)d_ws;
  size_t off = 0;
  auto alloc = [&](size_t bytes)->char*{
    char* p = wsb + off; off = (off + bytes + 255) & ~(size_t)255; return p;
  };
  u32* bar    = (u32*)alloc(128*32*4);
  u16* hS     = (u16*)alloc(2*64*1024*2);
  u16* cS     = (u16*)alloc(2*64*1024*2);
  float* cF   = (float*)alloc(64*1024*4);
  float* ccB  = (float*)alloc(64*320*4);
  float* b_in = (float*)alloc(4096*4);
  float* b_cell=(float*)alloc(4*4096*4);
  float* b_out= (float*)alloc(1280*4);
  float* b_cc = (float*)alloc(320*4);
  float* t1   = (float*)alloc(1024*64*4);
  float* t2   = (float*)alloc(1024*64*4);
  u16* Tbuf   = (u16*)alloc((size_t)1024*1024*2);
  u16* Win_h  = (u16*)alloc((size_t)64*65536*2);
  u16* Win_x  = (u16*)alloc((size_t)64*20480*2);
  u16* Wcell  = (u16*)alloc((size_t)4*64*81920*2);
  u16* Wout   = (u16*)alloc((size_t)20*65536*2);
  u16* WccA   = (u16*)alloc((size_t)20*16384*2);
  if (off > ws_size) return;

  hipMemsetAsync(bar, 0, 128*32*4, stream);

  k_dense<<<256,256,0,stream>>>(z, 0, eh_W1, eh_b1, 1024, 256, 1, 0, t1, nullptr);
  k_dense<<<256,256,0,stream>>>(t1,1, eh_W2, eh_b2, 1024,1024, 1, 0, t2, nullptr);
  k_dense<<<256,256,0,stream>>>(t2,1, eh_W3, eh_b3, 1024,1024, 0, 1, nullptr, hS + 65536);
  k_dense<<<256,256,0,stream>>>(z, 0, ec_W1, ec_b1, 1024, 256, 1, 0, t1, nullptr);
  k_dense<<<256,256,0,stream>>>(t1,1, ec_W2, ec_b2, 1024,1024, 1, 0, t2, nullptr);
  k_dense<<<256,256,0,stream>>>(t2,1, ec_W3, ec_b3, 1024,1024, 0, 2, cF, nullptr);
  k_dense<<<256,256,0,stream>>>(z, 0, ex_W1, ex_b1, 1024, 256, 1, 0, t1, nullptr);
  k_dense<<<256,256,0,stream>>>(t1,1, ex_W2, ex_b2, 1024,1024, 1, 0, t2, nullptr);
  k_dense<<<16 ,256,0,stream>>>(t2,1, ex_W3, ex_b3,   64,1024, 0, 3, out, nullptr);
  k_zero0<<<64,256,0,stream>>>(out);

  k_pack_winh<<<16384,256,0,stream>>>(in_Whh, Win_h);
  k_pack_winx<<<4096,320,0,stream>>>(in_Wih, Win_x);
  for (int i = 0; i < 4; ++i)
    k_pack_ca<<<4096,256,0,stream>>>(cA_W + (size_t)i*1024*1024, Wcell + (size_t)i*64*81920);

  for (int i = 0; i < 4; ++i){
    k_tr<<<dim3(16,16),256,0,stream>>>(hA_W + (size_t)i*1024*1024, Tbuf, 1024, 1024);
    k_fuse<<<dim3(64,16,4),256,0,stream>>>(r_Whh + (size_t)i*4096*1024,
                                           r_Wih + (size_t)i*4096*1024,
                                           Tbuf, 1024, 0, Wcell + (size_t)i*64*81920);
  }
  k_tr<<<dim3(5,16),256,0,stream>>>(lastH_W, Tbuf, 320, 1024);
  k_fuse<<<dim3(20,16,4),256,0,stream>>>(out_Whh, out_Wih, Tbuf, 320, 1, Wout);
  k_tr<<<dim3(16,16),256,0,stream>>>(cA_W + (size_t)3*1024*1024, Tbuf, 1024, 1024);
  k_fuse<<<dim3(20,16,1),256,0,stream>>>(lastC_W, nullptr, Tbuf, 1024, 2, WccA);

  k_bias<<<1024,256,0,stream>>>(nullptr, nullptr, in_bih, in_bhh, b_in, 4096, 0);
  for (int i = 0; i < 4; ++i)
    k_bias<<<1024,256,0,stream>>>(r_Whh + (size_t)i*4096*1024, hA_b + i*1024,
                                  r_bih + i*4096, r_bhh + i*4096, b_cell + i*4096, 4096, 1024);
  k_bias<<<320,256,0,stream>>>(out_Whh, lastH_b, out_bih, out_bhh, b_out, 1280, 320);
  k_bias<<<80 ,256,0,stream>>>(lastC_W, cA_b + 3*1024, lastC_b, nullptr, b_cc, 320, 1024);

  k_scan<<<NWG,256,0,stream>>>(m_true, Wcell, Win_h, Win_x, Wout, WccA,
                               b_in, b_cell, cA_b, b_out, b_cc,
                               hS, cS, cF, ccB, out, bar);
}

// Round 4
// 17490.858 us; speedup vs baseline: 2.2575x; 1.6363x over previous
//
#include <hip/hip_runtime.h>

// BigARDecoder: persistent-kernel LSTM scan on MI355X.
// B=64, T=256, IN=256, H=1024, G=256, O=64, D=4, GO=320.
//
// R4: kill the uncached-state-load amplification. h/c state stored in
// MFMA-fragment-ready layout [btile][ks][bl][kg][8] -> coalesced dwordx4
// state loads (plain, cached) + one acquire-agent fence (buffer_inv) per
// phase under the barrier wait; state writes remain 8-B relaxed agent
// atomics (write-through to MALL). R3's distributed barrier kept.

typedef unsigned int u32;
typedef unsigned long long u64;
typedef unsigned short u16;
typedef __attribute__((ext_vector_type(8))) __bf16 bf16x8;
typedef __attribute__((ext_vector_type(4))) float f32x4;

#define DEVI __device__ __forceinline__

union FRAG { bf16x8 v; u16 s[8]; u64 q[2]; };
union P4 { u64 q; u16 s[4]; };
union F4 { u64 q[2]; float f[4]; };

DEVI u16 f2bf(float x){ u32 u = __float_as_uint(x); return (u16)((u + 0x7fffu + ((u>>16)&1u)) >> 16); }
DEVI float sigm(float x){ return 1.0f/(1.0f + __expf(-x)); }
DEVI float tanh_(float x){ return 2.0f/(1.0f + __expf(-2.0f*x)) - 1.0f; }
DEVI void ast(void* p, u64 v){ __hip_atomic_store((u64*)p, v, __ATOMIC_RELAXED, __HIP_MEMORY_SCOPE_AGENT); }

#define MFMA16(a,b,c) __builtin_amdgcn_mfma_f32_16x16x32_bf16(a, b, c, 0, 0, 0)

#define NCOMP 84
#define NWG 85
#define NREP 21
#define NEPOCH 1276

#define SCHEDB() __builtin_amdgcn_sched_barrier(0)
#define WAITV(n) do{ SCHEDB(); \
  asm volatile("s_waitcnt vmcnt(" #n ")" ::: "memory"); \
  SCHEDB(); }while(0)
#define BARW() do{ __builtin_amdgcn_s_barrier(); SCHEDB(); }while(0)

#if __has_builtin(__builtin_amdgcn_fence)
#define FENCE_ACQ() __builtin_amdgcn_fence(__ATOMIC_ACQUIRE, "agent")
#else
#define FENCE_ACQ() __hip_atomic_fence(__ATOMIC_ACQUIRE, __HIP_MEMORY_SCOPE_AGENT)
#endif

// ---------------------------------------------------------------------------
// Persistent scan kernel. 85 WGs x 256 threads. WG84 = barrier master.
// WGs 0..63: hidden-unit tiles (16 jj each). WGs 64..83: out-cell / ccA tiles.
// State frag layout (per buffer, 128KB): [btile(4)][ks(32)][bl(16)][kg(4)][8 bf16]
// ---------------------------------------------------------------------------
__global__ __launch_bounds__(256, 1) void k_scan(
    const float* __restrict__ m_true,
    const u16* __restrict__ Wcell, const u16* __restrict__ Win_h,
    const u16* __restrict__ Win_x, const u16* __restrict__ Wout,
    const u16* __restrict__ WccA,
    const float* __restrict__ b_in, const float* __restrict__ b_cell,
    const float* __restrict__ cAb, const float* __restrict__ b_out,
    const float* __restrict__ b_cc,
    u16* hS, u16* cS, float* cF, float* ccB, float* outp, u32* bar)
{
  const int wg = blockIdx.x;
  const int tid = threadIdx.x;
  const int wave = tid >> 6, lane = tid & 63;

  // ---- master WG: flat-combining barrier server, all RELAXED ----
  if (wg == NCOMP){
    if (wave == 0){
      u32* arr = bar;
      u32* go  = bar + NCOMP*32;
      for (u32 ep = 1; ep <= NEPOCH; ++ep){
        for(;;){
          int ok = 1;
          if (lane < 42){
            u32 a0 = __hip_atomic_load(arr + lane*32,      __ATOMIC_RELAXED, __HIP_MEMORY_SCOPE_AGENT);
            u32 a1 = __hip_atomic_load(arr + (lane+42)*32, __ATOMIC_RELAXED, __HIP_MEMORY_SCOPE_AGENT);
            ok = (a0 >= ep) && (a1 >= ep);
          }
          if (__all(ok)) break;
          __builtin_amdgcn_s_sleep(1);
        }
        if (lane < NREP)
          __hip_atomic_store(go + lane*32, ep, __ATOMIC_RELAXED, __HIP_MEMORY_SCOPE_AGENT);
      }
    }
    return;
  }

  const int bl = lane & 15, kg = lane >> 4;
  const int b = (wave << 4) + bl;
  const int swz = (bl & 7) << 4;
  const int foff = ((bl << 2) + kg) << 4;   // byte offset of this lane's frag piece
  // writer byte offset into frag-layout state (j = wg*16 + kg*4 .. +3, all b)
  const int woff = (wave << 15) + ((wg >> 1) << 10) + (bl << 6) + ((wg & 1) << 5) + (kg << 3);
  __shared__ __align__(16) u16 ldsW[40960 + 1024];   // 2x40KB weights + 2KB bias
  float* fb = (float*)(ldsW + 40960);

  auto stage_async = [&](const u16* src, u16* lb, int spw){
    const u16* g = src + ((size_t)(wave*spw) << 9) + (lane << 3);
    u16* l = lb + ((wave*spw) << 9);
    for (int s = 0; s < spw; ++s){
      __builtin_amdgcn_global_load_lds(
          (const __attribute__((address_space(1))) void*)g,
          (__attribute__((address_space(3))) void*)l, 16, 0, 0);
      g += 512; l += 512;
    }
    SCHEDB();
  };
  auto afL = [&](const u16* lb, int row, int kb) -> bf16x8 {
    return *(const bf16x8*)((const char*)lb + row*512 + (kb ^ swz));
  };

  // distributed barrier; acquire-agent fence + next-phase chunk0 prefetch
  // hidden under the wait
  auto gsync = [&](u32 ep, const u16* pfsrc, int pfspw){
    SCHEDB();
    __syncthreads();                  // drains vmcnt(0): all state stores at MALL
    if (tid == 0)
      __hip_atomic_store(bar + wg*32, ep, __ATOMIC_RELAXED, __HIP_MEMORY_SCOPE_AGENT);
    if (wave == 0) FENCE_ACQ();       // inv L1+L2 (one wave suffices: shared caches)
    SCHEDB();
    if (pfsrc){
      const u16* g = pfsrc + ((size_t)(wave*pfspw) << 9) + (lane << 3);
      u16* l = ldsW + ((wave*pfspw) << 9);
      for (int s = 0; s < pfspw; ++s){
        __builtin_amdgcn_global_load_lds(
            (const __attribute__((address_space(1))) void*)g,
            (__attribute__((address_space(3))) void*)l, 16, 0, 0);
        g += 512; l += 512;
      }
    }
    SCHEDB();
    if (tid == 0){
      const u32* gp = bar + NCOMP*32 + (wg % NREP)*32;
      while (__hip_atomic_load(gp, __ATOMIC_RELAXED, __HIP_MEMORY_SCOPE_AGENT) < ep)
        __builtin_amdgcn_s_sleep(1);
      asm volatile("" ::: "memory");
    }
    __syncthreads();                  // orders fence before state loads; drains prefetch
    SCHEDB();
  };

  // ---- in-cell phase (wg<64). entry: buf0 = Win_h chunk0 (prefetched)
  auto phase_incell = [&](int t, const u16* hIn, u16* hOut, u16* cOut){
    f32x4 A0={0,0,0,0}, A1={0,0,0,0}, A2={0,0,0,0}, A3={0,0,0,0};
    const float* xr = m_true + (size_t)b*81920 + (size_t)(255 - t)*320;
    FRAG xf[10];
    #pragma unroll
    for (int ks = 0; ks < 10; ++ks){
      int k = (ks << 5) + (kg << 3);
      f32x4 x0 = *(const f32x4*)(xr + k);
      f32x4 x1 = *(const f32x4*)(xr + k + 4);
      xf[ks].s[0]=f2bf(x0[0]); xf[ks].s[1]=f2bf(x0[1]); xf[ks].s[2]=f2bf(x0[2]); xf[ks].s[3]=f2bf(x0[3]);
      xf[ks].s[4]=f2bf(x1[0]); xf[ks].s[5]=f2bf(x1[1]); xf[ks].s[6]=f2bf(x1[2]); xf[ks].s[7]=f2bf(x1[3]);
    }
    int jl = (kg << 2), jj = (wg << 4) + jl;
    f32x4 cpv = *(const f32x4*)((const char*)cF + ((size_t)b << 12) + (jj << 2));
    const char* hf = (const char*)hIn + (wave << 15) + foff;
    FRAG sh[2][8];
    #pragma unroll
    for (int ks = 0; ks < 8; ++ks) sh[0][ks].v = *(const bf16x8*)(hf + ks*1024);
    SCHEDB();
    const u16* Wb = Win_h + ((size_t)wg << 16);
    stage_async(Wb + 16384, ldsW + 20480, 8);      // S1 -> buf1
    #pragma unroll
    for (int c = 0; c < 4; ++c){
      if (c > 0){
        BARW();                                     // done reading buf[(c+1)&1]
        if (c < 3) stage_async(Wb + (size_t)(c+1)*16384, ldsW + ((c+1)&1)*20480, 8);
        else       stage_async(Win_x + (size_t)wg*20480, ldsW, 10);   // x -> buf0
      }
      if (c == 3) { WAITV(10); } else { WAITV(8); }
      if (c > 0) BARW();                            // cross-wave S_c drained
      if (c < 3){
        #pragma unroll
        for (int ks = 0; ks < 8; ++ks)
          sh[(c+1)&1][ks].v = *(const bf16x8*)(hf + ((c+1)*8 + ks)*1024);
        SCHEDB();
      }
      const u16* lb = ldsW + (c & 1)*20480;
      #pragma unroll
      for (int ks = 0; ks < 8; ++ks){
        int kb = (ks << 6) + (kg << 4);
        FRAG a;
        a.v = afL(lb, bl, kb);      A0 = MFMA16(a.v, sh[c&1][ks].v, A0);
        a.v = afL(lb, 16 + bl, kb); A1 = MFMA16(a.v, sh[c&1][ks].v, A1);
        a.v = afL(lb, 32 + bl, kb); A2 = MFMA16(a.v, sh[c&1][ks].v, A2);
        a.v = afL(lb, 48 + bl, kb); A3 = MFMA16(a.v, sh[c&1][ks].v, A3);
      }
    }
    WAITV(0); BARW();                               // x chunk ready in buf0
    #pragma unroll
    for (int ks = 0; ks < 8; ++ks){
      int kb = (ks << 6) + (kg << 4);
      FRAG a;
      a.v = afL(ldsW, bl, kb);      A0 = MFMA16(a.v, xf[ks].v, A0);
      a.v = afL(ldsW, 16 + bl, kb); A1 = MFMA16(a.v, xf[ks].v, A1);
      a.v = afL(ldsW, 32 + bl, kb); A2 = MFMA16(a.v, xf[ks].v, A2);
      a.v = afL(ldsW, 48 + bl, kb); A3 = MFMA16(a.v, xf[ks].v, A3);
    }
    #pragma unroll
    for (int ks = 0; ks < 2; ++ks){
      int kb = (ks << 6) + (kg << 4);
      FRAG a;
      a.v = *(const bf16x8*)((const char*)ldsW + 32768 + bl*128      + (kb ^ swz)); A0 = MFMA16(a.v, xf[8+ks].v, A0);
      a.v = *(const bf16x8*)((const char*)ldsW + 32768 + (16+bl)*128 + (kb ^ swz)); A1 = MFMA16(a.v, xf[8+ks].v, A1);
      a.v = *(const bf16x8*)((const char*)ldsW + 32768 + (32+bl)*128 + (kb ^ swz)); A2 = MFMA16(a.v, xf[8+ks].v, A2);
      a.v = *(const bf16x8*)((const char*)ldsW + 32768 + (48+bl)*128 + (kb ^ swz)); A3 = MFMA16(a.v, xf[8+ks].v, A3);
    }
    P4 hw, cw;
    #pragma unroll
    for (int r = 0; r < 4; ++r){
      float gi = A0[r] + fb[jl + r];
      float gf = A1[r] + fb[16 + jl + r];
      float gg = A2[r] + fb[32 + jl + r];
      float go = A3[r] + fb[48 + jl + r];
      float cn = sigm(gf)*cpv[r] + sigm(gi)*tanh_(gg);
      hw.s[r] = f2bf(sigm(go)*tanh_(cn));
      cw.s[r] = f2bf(cn);
    }
    ast((char*)hOut + woff, hw.q);
    ast((char*)cOut + woff, cw.q);
  };

  // ---- inner cell phase i (wg<64). entry: buf0 = Wcell_i chunk0
  auto phase_cell = [&](int i, const u16* hIn, const u16* cIn, u16* hOut, u16* cOut, bool last){
    f32x4 A0={0,0,0,0}, A1={0,0,0,0}, A2={0,0,0,0}, A3={0,0,0,0}, A4={0,0,0,0};
    const u16* Wb = Wcell + (size_t)(i*64 + wg) * 81920;
    const char* hf = (const char*)hIn + (wave << 15) + foff;
    const char* cfr = (const char*)cIn + (wave << 15) + foff;
    FRAG sh[2][8], sc[2][8];
    #pragma unroll
    for (int ks = 0; ks < 8; ++ks){
      sh[0][ks].v = *(const bf16x8*)(hf + ks*1024);
      sc[0][ks].v = *(const bf16x8*)(cfr + ks*1024);
    }
    SCHEDB();
    stage_async(Wb + 20480, ldsW + 20480, 10);      // S1 -> buf1
    #pragma unroll
    for (int c = 0; c < 4; ++c){
      if (c > 0){
        BARW();
        if (c < 3) stage_async(Wb + (size_t)(c+1)*20480, ldsW + ((c+1)&1)*20480, 10);
      }
      if (c == 3) { WAITV(0); } else { WAITV(10); }
      if (c > 0) BARW();
      if (c < 3){
        #pragma unroll
        for (int ks = 0; ks < 8; ++ks){
          sh[(c+1)&1][ks].v = *(const bf16x8*)(hf + ((c+1)*8 + ks)*1024);
          sc[(c+1)&1][ks].v = *(const bf16x8*)(cfr + ((c+1)*8 + ks)*1024);
        }
        SCHEDB();
      }
      const u16* lb = ldsW + (c & 1)*20480;
      #pragma unroll
      for (int ks = 0; ks < 8; ++ks){
        int kb = (ks << 6) + (kg << 4);
        FRAG a;
        a.v = afL(lb, bl, kb);      A0 = MFMA16(a.v, sh[c&1][ks].v, A0);
        a.v = afL(lb, 16 + bl, kb); A1 = MFMA16(a.v, sh[c&1][ks].v, A1);
        a.v = afL(lb, 32 + bl, kb); A2 = MFMA16(a.v, sh[c&1][ks].v, A2);
        a.v = afL(lb, 48 + bl, kb); A3 = MFMA16(a.v, sh[c&1][ks].v, A3);
        a.v = afL(lb, 64 + bl, kb); A4 = MFMA16(a.v, sc[c&1][ks].v, A4);
      }
    }
    int jl = (kg << 2), jj = (wg << 4) + jl;
    P4 hw, cw; F4 cf4;
    #pragma unroll
    for (int r = 0; r < 4; ++r){
      float gi = A0[r] + fb[64 + i*80 + jl + r];
      float gf = A1[r] + fb[64 + i*80 + 16 + jl + r];
      float gg = A2[r] + fb[64 + i*80 + 32 + jl + r];
      float go = A3[r] + fb[64 + i*80 + 48 + jl + r];
      float c1 = A4[r] + fb[64 + i*80 + 64 + jl + r];
      float cn = sigm(gf)*c1 + sigm(gi)*tanh_(gg);
      hw.s[r] = f2bf(sigm(go)*tanh_(cn));
      cw.s[r] = f2bf(cn);
      cf4.f[r] = cn;
    }
    ast((char*)hOut + woff, hw.q);
    ast((char*)cOut + woff, cw.q);
    if (last){
      char* cfp = (char*)cF + ((size_t)b << 12) + (jj << 2);
      ast(cfp, cf4.q[0]); ast(cfp + 8, cf4.q[1]);
    }
  };

  // ---- ccA phase (wg 64..83, with cell i==3). entry: buf0 = WccA chunk0
  auto phase_ccA = [&](const u16* cIn){
    f32x4 A = {0,0,0,0};
    int w2 = wg - 64;
    const u16* Wb = WccA + ((size_t)w2 << 14);
    const char* cfr = (const char*)cIn + (wave << 15) + foff;
    FRAG sc[2][8];
    #pragma unroll
    for (int ks = 0; ks < 8; ++ks) sc[0][ks].v = *(const bf16x8*)(cfr + ks*1024);
    SCHEDB();
    stage_async(Wb + 4096, ldsW + 20480, 2);
    #pragma unroll
    for (int c = 0; c < 4; ++c){
      if (c > 0){
        BARW();
        if (c < 3) stage_async(Wb + (size_t)(c+1)*4096, ldsW + ((c+1)&1)*20480, 2);
      }
      if (c == 3) { WAITV(0); } else { WAITV(2); }
      if (c > 0) BARW();
      if (c < 3){
        #pragma unroll
        for (int ks = 0; ks < 8; ++ks)
          sc[(c+1)&1][ks].v = *(const bf16x8*)(cfr + ((c+1)*8 + ks)*1024);
        SCHEDB();
      }
      const u16* lb = ldsW + (c & 1)*20480;
      #pragma unroll
      for (int ks = 0; ks < 8; ++ks){
        int kb = (ks << 6) + (kg << 4);
        FRAG a; a.v = afL(lb, bl, kb);
        A = MFMA16(a.v, sc[c&1][ks].v, A);
      }
    }
    int jl = (kg << 2), jjo = (w2 << 4) + jl;
    F4 v;
    #pragma unroll
    for (int r = 0; r < 4; ++r) v.f[r] = A[r] + fb[64 + jl + r];
    char* cp2 = (char*)ccB + ((size_t)b*320 + jjo)*4;
    ast(cp2, v.q[0]); ast(cp2 + 8, v.q[1]);
  };

  // ---- out-cell phase (wg 64..83). entry: buf0 = Wout chunk0
  auto phase_out = [&](int t, const u16* hIn){
    f32x4 A0={0,0,0,0}, A1={0,0,0,0}, A2={0,0,0,0}, A3={0,0,0,0};
    int w2 = wg - 64;
    const u16* Wb = Wout + ((size_t)w2 << 16);
    const char* hf = (const char*)hIn + (wave << 15) + foff;
    int jl = (kg << 2), jjo = (w2 << 4) + jl;
    f32x4 ccv = *(const f32x4*)((const char*)ccB + ((size_t)b*320 + jjo)*4);
    FRAG sh[2][8];
    #pragma unroll
    for (int ks = 0; ks < 8; ++ks) sh[0][ks].v = *(const bf16x8*)(hf + ks*1024);
    SCHEDB();
    stage_async(Wb + 16384, ldsW + 20480, 8);
    #pragma unroll
    for (int c = 0; c < 4; ++c){
      if (c > 0){
        BARW();
        if (c < 3) stage_async(Wb + (size_t)(c+1)*16384, ldsW + ((c+1)&1)*20480, 8);
      }
      if (c == 3) { WAITV(0); } else { WAITV(8); }
      if (c > 0) BARW();
      if (c < 3){
        #pragma unroll
        for (int ks = 0; ks < 8; ++ks)
          sh[(c+1)&1][ks].v = *(const bf16x8*)(hf + ((c+1)*8 + ks)*1024);
        SCHEDB();
      }
      const u16* lb = ldsW + (c & 1)*20480;
      #pragma unroll
      for (int ks = 0; ks < 8; ++ks){
        int kb = (ks << 6) + (kg << 4);
        FRAG a;
        a.v = afL(lb, bl, kb);      A0 = MFMA16(a.v, sh[c&1][ks].v, A0);
        a.v = afL(lb, 16 + bl, kb); A1 = MFMA16(a.v, sh[c&1][ks].v, A1);
        a.v = afL(lb, 32 + bl, kb); A2 = MFMA16(a.v, sh[c&1][ks].v, A2);
        a.v = afL(lb, 48 + bl, kb); A3 = MFMA16(a.v, sh[c&1][ks].v, A3);
      }
    }
    f32x4 ho;
    #pragma unroll
    for (int r = 0; r < 4; ++r){
      float gi = A0[r] + fb[jl + r];
      float gf = A1[r] + fb[16 + jl + r];
      float gg = A2[r] + fb[32 + jl + r];
      float go = A3[r] + fb[48 + jl + r];
      float cn = sigm(gf)*ccv[r] + sigm(gi)*tanh_(gg);
      ho[r] = sigm(go)*tanh_(cn);
    }
    *(f32x4*)(outp + (size_t)b*81920 + (size_t)(t+1)*320 + jjo) = ho;
  };

  // ---- init: biases -> LDS, first chunk0 prefetch ----
  if (wg < 64){
    if (tid < 16){
      int q = tid, j0 = wg*16;
      for (int g = 0; g < 4; ++g) fb[g*16 + q] = b_in[g*1024 + j0 + q];
      for (int i2 = 0; i2 < 4; ++i2){
        for (int g = 0; g < 4; ++g)
          fb[64 + i2*80 + g*16 + q] = b_cell[i2*4096 + g*1024 + j0 + q];
        fb[64 + i2*80 + 64 + q] = cAb[i2*1024 + j0 + q];
      }
    }
    stage_async(Win_h + ((size_t)wg << 16), ldsW, 8);
  } else {
    if (tid < 16){
      int q = tid, j0 = (wg - 64)*16;
      for (int g = 0; g < 4; ++g) fb[g*16 + q] = b_out[g*320 + j0 + q];
      fb[64 + q] = b_cc[j0 + q];
    }
  }
  __syncthreads();
  SCHEDB();

  u16* hB0 = hS;        u16* hB1 = hS + 65536;
  u16* cB0 = cS;        u16* cB1 = cS + 65536;

  u32 ep = 1;
  if (wg < 64) phase_incell(0, hB1, hB0, cB0);
  gsync(ep++, (wg < 64) ? Wcell + (size_t)wg*81920 : nullptr, 10);
  int p = 1;
  #pragma unroll 1
  for (int t = 0; t < 255; ++t){
    #pragma unroll 1
    for (int i = 0; i < 4; ++i){
      u16* hIn = (p & 1) ? hB0 : hB1;  u16* cIn = (p & 1) ? cB0 : cB1;
      u16* hOut = (p & 1) ? hB1 : hB0; u16* cOut = (p & 1) ? cB1 : cB0;
      if (wg < 64)      phase_cell(i, hIn, cIn, hOut, cOut, i == 3);
      else if (i == 3)  phase_ccA(cIn);
      const u16* pf = nullptr; int spw = 0;
      if (wg < 64){
        if (i < 3){ pf = Wcell + (size_t)((i+1)*64 + wg)*81920; spw = 10; }
        else      { pf = Win_h + ((size_t)wg << 16);            spw = 8;  }
      } else {
        if (i == 2){ pf = WccA + ((size_t)(wg-64) << 14); spw = 2; }
        else if (i == 3){ pf = Wout + ((size_t)(wg-64) << 16); spw = 8; }
      }
      gsync(ep++, pf, spw);
      ++p;
    }
    u16* hIn = (p & 1) ? hB0 : hB1;
    u16* hOut = (p & 1) ? hB1 : hB0; u16* cOut = (p & 1) ? cB1 : cB0;
    if (wg >= 64)       phase_out(t, hIn);
    else if (t < 254)   phase_incell(t + 1, hIn, hOut, cOut);
    gsync(ep++, (wg < 64 && t < 254) ? Wcell + (size_t)wg*81920 : nullptr, 10);
    ++p;
  }
}

// ---------------------------------------------------------------------------
// Precompute kernels
// ---------------------------------------------------------------------------

__global__ __launch_bounds__(256) void k_dense(const float* __restrict__ X, int xmode,
    const float* __restrict__ W, const float* __restrict__ bias,
    int OD, int ID, int act, int omode, float* outF, u16* outB)
{
  int o = blockIdx.x*4 + (threadIdx.x >> 6);
  if (o >= OD) return;
  int lane = threadIdx.x & 63;
  const float* wr = W + (size_t)o*ID;
  float acc = 0.f;
  if (xmode == 0){ for (int k = 0; k < ID; ++k) acc = fmaf(wr[k], X[(size_t)lane*ID + k], acc); }
  else           { for (int k = 0; k < ID; ++k) acc = fmaf(wr[k], X[(size_t)k*64 + lane], acc); }
  acc += bias[o];
  if (act) acc = acc * sigm(acc);
  if (omode == 0)      outF[(size_t)o*64 + lane] = acc;
  else if (omode == 1){
    // frag layout: [btile][ks][bl][kg][8] (u16 units)
    int bt = lane >> 4, blx = lane & 15;
    outB[(size_t)bt*16384 + (size_t)(o>>5)*512 + blx*32 + ((o&31)>>3)*8 + (o&7)] = f2bf(acc);
  }
  else if (omode == 2) outF[(size_t)lane*1024 + o] = acc;
  else                 outF[(size_t)lane*81920 + 256 + o] = acc;
}

__global__ void k_zero0(float* out){ out[(size_t)blockIdx.x*81920 + threadIdx.x] = 0.f; }

__global__ __launch_bounds__(256) void k_tr(const float* __restrict__ in, u16* __restrict__ out, int M, int N){
  __shared__ u16 t[64][65];
  int m0 = blockIdx.x << 6, n0 = blockIdx.y << 6;
  int c = threadIdx.x & 63, rq = threadIdx.x >> 6;
  for (int rr = 0; rr < 16; ++rr){
    int r = (rq << 4) + rr;
    t[r][c] = f2bf(in[(size_t)(m0 + r)*N + n0 + c]);
  }
  __syncthreads();
  for (int rr = 0; rr < 16; ++rr){
    int r = (rq << 4) + rr;
    out[(size_t)(n0 + r)*M + m0 + c] = t[c][r];
  }
}

__global__ __launch_bounds__(256) void k_fuse(const float* __restrict__ Whh, const float* __restrict__ Wih,
    const u16* __restrict__ BT, int KM, int mode, u16* __restrict__ dst)
{
  int bx = blockIdx.x, by = blockIdx.y, bz = blockIdx.z;
  int lane = threadIdx.x & 63, wv = threadIdx.x >> 6;
  int bl = lane & 15, kg = lane >> 4;
  int jbase = (mode == 0) ? bz*1024 : ((mode == 1) ? bz*320 : 0);
  int jrow = jbase + bx*16 + bl;
  int k2c = by*64 + wv*16 + bl;
  f32x4 acc = {0,0,0,0};
  for (int m0 = 0; m0 < KM; m0 += 32){
    f32x4 wa0 = *(const f32x4*)(Whh + (size_t)jrow*KM + m0 + (kg << 3));
    f32x4 wa1 = *(const f32x4*)(Whh + (size_t)jrow*KM + m0 + (kg << 3) + 4);
    FRAG a;
    a.s[0]=f2bf(wa0[0]); a.s[1]=f2bf(wa0[1]); a.s[2]=f2bf(wa0[2]); a.s[3]=f2bf(wa0[3]);
    a.s[4]=f2bf(wa1[0]); a.s[5]=f2bf(wa1[1]); a.s[6]=f2bf(wa1[2]); a.s[7]=f2bf(wa1[3]);
    FRAG bb; bb.v = *(const bf16x8*)(BT + (size_t)k2c*KM + m0 + (kg << 3));
    acc = MFMA16(a.v, bb.v, acc);
  }
  #pragma unroll
  for (int r = 0; r < 4; ++r){
    int jl = (kg << 2) + r;
    int jg = jbase + bx*16 + jl;
    float v = acc[r];
    if (mode < 2) v += Wih[(size_t)jg*1024 + k2c];
    int re = (mode == 2) ? jl : (bz*16 + jl);
    int c = k2c >> 8, kl = k2c & 255;
    size_t pos;
    if (mode == 0)      pos = (size_t)bx*81920 + c*20480 + re*256 + (kl ^ ((re&7)<<3));
    else if (mode == 1) pos = (size_t)bx*65536 + c*16384 + re*256 + (kl ^ ((re&7)<<3));
    else                pos = (size_t)bx*16384 + c*4096  + re*256 + (kl ^ ((re&7)<<3));
    dst[pos] = f2bf(v);
  }
}

__global__ void k_pack_winh(const float* __restrict__ src, u16* __restrict__ dst){
  int id = blockIdx.x*256 + threadIdx.x;
  int j = id >> 10, k = id & 1023;
  int g = j >> 10, jj = j & 1023;
  int w = jj >> 4, r = (g << 4) + (jj & 15);
  int c = k >> 8, kl = k & 255;
  dst[(size_t)w*65536 + c*16384 + r*256 + (kl ^ ((r&7)<<3))] = f2bf(src[id]);
}

__global__ void k_pack_winx(const float* __restrict__ src, u16* __restrict__ dst){
  int j = blockIdx.x, k = threadIdx.x;
  int g = j >> 10, jj = j & 1023;
  int w = jj >> 4, r = (g << 4) + (jj & 15);
  float v = src[(size_t)j*320 + k];
  size_t pos;
  if (k < 256) pos = (size_t)w*20480 + r*256 + (k ^ ((r&7)<<3));
  else         pos = (size_t)w*20480 + 16384 + r*64 + ((k - 256) ^ ((r&7)<<3));
  dst[pos] = f2bf(v);
}

__global__ void k_pack_ca(const float* __restrict__ src, u16* __restrict__ dst){
  int id = blockIdx.x*256 + threadIdx.x;
  int jj = id >> 10, k = id & 1023;
  int w = jj >> 4, r = 64 + (jj & 15);
  int c = k >> 8, kl = k & 255;
  dst[(size_t)w*81920 + c*20480 + r*256 + (kl ^ ((r&7)<<3))] = f2bf(src[id]);
}

__global__ __launch_bounds__(256) void k_bias(const float* __restrict__ A, const float* __restrict__ x,
    const float* __restrict__ a1, const float* __restrict__ a2, float* __restrict__ o, int NJ, int K)
{
  int j = blockIdx.x*4 + (threadIdx.x >> 6);
  if (j >= NJ) return;
  int lane = threadIdx.x & 63;
  float acc = 0.f;
  if (A) for (int k = lane; k < K; k += 64) acc += A[(size_t)j*K + k]*x[k];
  for (int off = 32; off; off >>= 1) acc += __shfl_down(acc, off);
  if (lane == 0) o[j] = acc + (a1 ? a1[j] : 0.f) + (a2 ? a2[j] : 0.f);
}

// ---------------------------------------------------------------------------
extern "C" void kernel_launch(void* const* d_in, const int* in_sizes, int n_in,
                              void* d_out, int out_size, void* d_ws, size_t ws_size,
                              hipStream_t stream)
{
  (void)in_sizes; (void)n_in; (void)out_size;
  const float* z      = (const float*)d_in[0];
  const float* m_true = (const float*)d_in[1];
  const float* eh_W1=(const float*)d_in[2],  *eh_b1=(const float*)d_in[3];
  const float* eh_W2=(const float*)d_in[4],  *eh_b2=(const float*)d_in[5];
  const float* eh_W3=(const float*)d_in[6],  *eh_b3=(const float*)d_in[7];
  const float* ec_W1=(const float*)d_in[8],  *ec_b1=(const float*)d_in[9];
  const float* ec_W2=(const float*)d_in[10], *ec_b2=(const float*)d_in[11];
  const float* ec_W3=(const float*)d_in[12], *ec_b3=(const float*)d_in[13];
  const float* ex_W1=(const float*)d_in[14], *ex_b1=(const float*)d_in[15];
  const float* ex_W2=(const float*)d_in[16], *ex_b2=(const float*)d_in[17];
  const float* ex_W3=(const float*)d_in[18], *ex_b3=(const float*)d_in[19];
  const float* in_Wih=(const float*)d_in[20], *in_Whh=(const float*)d_in[21];
  const float* in_bih=(const float*)d_in[22], *in_bhh=(const float*)d_in[23];
  const float* r_Wih=(const float*)d_in[24],  *r_Whh=(const float*)d_in[25];
  const float* r_bih=(const float*)d_in[26],  *r_bhh=(const float*)d_in[27];
  const float* hA_W=(const float*)d_in[28],   *hA_b=(const float*)d_in[29];
  const float* cA_W=(const float*)d_in[30],   *cA_b=(const float*)d_in[31];
  const float* lastH_W=(const float*)d_in[32], *lastH_b=(const float*)d_in[33];
  const float* lastC_W=(const float*)d_in[34], *lastC_b=(const float*)d_in[35];
  const float* out_Wih=(const float*)d_in[36], *out_Whh=(const float*)d_in[37];
  const float* out_bih=(const float*)d_in[38], *out_bhh=(const float*)d_in[39];
  float* out = (float*)d_out;

  char* wsb = (char*)d_ws;
  size_t off = 0;
  auto alloc = [&](size_t bytes)->char*{
    char* p = wsb + off; off = (off + bytes + 255) & ~(size_t)255; return p;
  };
  u32* bar    = (u32*)alloc(128*32*4);
  u16* hS     = (u16*)alloc(2*64*1024*2);
  u16* cS     = (u16*)alloc(2*64*1024*2);
  float* cF   = (float*)alloc(64*1024*4);
  float* ccB  = (float*)alloc(64*320*4);
  float* b_in = (float*)alloc(4096*4);
  float* b_cell=(float*)alloc(4*4096*4);
  float* b_out= (float*)alloc(1280*4);
  float* b_cc = (float*)alloc(320*4);
  float* t1   = (float*)alloc(1024*64*4);
  float* t2   = (float*)alloc(1024*64*4);
  u16* Tbuf   = (u16*)alloc((size_t)1024*1024*2);
  u16* Win_h  = (u16*)alloc((size_t)64*65536*2);
  u16* Win_x  = (u16*)alloc((size_t)64*20480*2);
  u16* Wcell  = (u16*)alloc((size_t)4*64*81920*2);
  u16* Wout   = (u16*)alloc((size_t)20*65536*2);
  u16* WccA   = (u16*)alloc((size_t)20*16384*2);
  if (off > ws_size) return;

  hipMemsetAsync(bar, 0, 128*32*4, stream);

  k_dense<<<256,256,0,stream>>>(z, 0, eh_W1, eh_b1, 1024, 256, 1, 0, t1, nullptr);
  k_dense<<<256,256,0,stream>>>(t1,1, eh_W2, eh_b2, 1024,1024, 1, 0, t2, nullptr);
  k_dense<<<256,256,0,stream>>>(t2,1, eh_W3, eh_b3, 1024,1024, 0, 1, nullptr, hS + 65536);
  k_dense<<<256,256,0,stream>>>(z, 0, ec_W1, ec_b1, 1024, 256, 1, 0, t1, nullptr);
  k_dense<<<256,256,0,stream>>>(t1,1, ec_W2, ec_b2, 1024,1024, 1, 0, t2, nullptr);
  k_dense<<<256,256,0,stream>>>(t2,1, ec_W3, ec_b3, 1024,1024, 0, 2, cF, nullptr);
  k_dense<<<256,256,0,stream>>>(z, 0, ex_W1, ex_b1, 1024, 256, 1, 0, t1, nullptr);
  k_dense<<<256,256,0,stream>>>(t1,1, ex_W2, ex_b2, 1024,1024, 1, 0, t2, nullptr);
  k_dense<<<16 ,256,0,stream>>>(t2,1, ex_W3, ex_b3,   64,1024, 0, 3, out, nullptr);
  k_zero0<<<64,256,0,stream>>>(out);

  k_pack_winh<<<16384,256,0,stream>>>(in_Whh, Win_h);
  k_pack_winx<<<4096,320,0,stream>>>(in_Wih, Win_x);
  for (int i = 0; i < 4; ++i)
    k_pack_ca<<<4096,256,0,stream>>>(cA_W + (size_t)i*1024*1024, Wcell + (size_t)i*64*81920);

  for (int i = 0; i < 4; ++i){
    k_tr<<<dim3(16,16),256,0,stream>>>(hA_W + (size_t)i*1024*1024, Tbuf, 1024, 1024);
    k_fuse<<<dim3(64,16,4),256,0,stream>>>(r_Whh + (size_t)i*4096*1024,
                                           r_Wih + (size_t)i*4096*1024,
                                           Tbuf, 1024, 0, Wcell + (size_t)i*64*81920);
  }
  k_tr<<<dim3(5,16),256,0,stream>>>(lastH_W, Tbuf, 320, 1024);
  k_fuse<<<dim3(20,16,4),256,0,stream>>>(out_Whh, out_Wih, Tbuf, 320, 1, Wout);
  k_tr<<<dim3(16,16),256,0,stream>>>(cA_W + (size_t)3*1024*1024, Tbuf, 1024, 1024);
  k_fuse<<<dim3(20,16,1),256,0,stream>>>(lastC_W, nullptr, Tbuf, 1024, 2, WccA);

  k_bias<<<1024,256,0,stream>>>(nullptr, nullptr, in_bih, in_bhh, b_in, 4096, 0);
  for (int i = 0; i < 4; ++i)
    k_bias<<<1024,256,0,stream>>>(r_Whh + (size_t)i*4096*1024, hA_b + i*1024,
                                  r_bih + i*4096, r_bhh + i*4096, b_cell + i*4096, 4096, 1024);
  k_bias<<<320,256,0,stream>>>(out_Whh, lastH_b, out_bih, out_bhh, b_out, 1280, 320);
  k_bias<<<80 ,256,0,stream>>>(lastC_W, cA_b + 3*1024, lastC_b, nullptr, b_cc, 320, 1024);

  k_scan<<<NWG,256,0,stream>>>(m_true, Wcell, Win_h, Win_x, Wout, WccA,
                               b_in, b_cell, cA_b, b_out, b_cc,
                               hS, cS, cF, ccB, out, bar);
}

// Round 5
// 16096.432 us; speedup vs baseline: 2.4530x; 1.0866x over previous
//
#include <hip/hip_runtime.h>

// BigARDecoder: persistent-kernel LSTM scan on MI355X.
// B=64, T=256, IN=256, H=1024, G=256, O=64, D=4, GO=320.
//
// R5: two independent half-batch pipelines (b 0-31 / 32-63), 168 compute WGs
// x 128 threads (2 waves = 2 btiles) + 1 master. Per-WG cell-phase memory
// drops 416->288 KB; pipeline twins are mapped 8 blocks apart so their
// simultaneous fetches of the same weight lines L2-merge per XCD. Same
// phase/barrier structure, fence and frag-layout state as R4; vmcnt literals
// doubled (20/16/4 segs per wave).

typedef unsigned int u32;
typedef unsigned long long u64;
typedef unsigned short u16;
typedef __attribute__((ext_vector_type(8))) __bf16 bf16x8;
typedef __attribute__((ext_vector_type(4))) float f32x4;

#define DEVI __device__ __forceinline__

union FRAG { bf16x8 v; u16 s[8]; u64 q[2]; };
union P4 { u64 q; u16 s[4]; };
union F4 { u64 q[2]; float f[4]; };

DEVI u16 f2bf(float x){ u32 u = __float_as_uint(x); return (u16)((u + 0x7fffu + ((u>>16)&1u)) >> 16); }
DEVI float sigm(float x){ return 1.0f/(1.0f + __expf(-x)); }
DEVI float tanh_(float x){ return 2.0f/(1.0f + __expf(-2.0f*x)) - 1.0f; }
DEVI void ast(void* p, u64 v){ __hip_atomic_store((u64*)p, v, __ATOMIC_RELAXED, __HIP_MEMORY_SCOPE_AGENT); }

#define MFMA16(a,b,c) __builtin_amdgcn_mfma_f32_16x16x32_bf16(a, b, c, 0, 0, 0)

#define NARR 168          // compute WGs (arrive lines)
#define NWG 169           // + master
#define NREP 21
#define NEPOCH 1276

#define SCHEDB() __builtin_amdgcn_sched_barrier(0)
#define WAITV(n) do{ SCHEDB(); \
  asm volatile("s_waitcnt vmcnt(" #n ")" ::: "memory"); \
  SCHEDB(); }while(0)
#define BARW() do{ __builtin_amdgcn_s_barrier(); SCHEDB(); }while(0)

#if __has_builtin(__builtin_amdgcn_fence)
#define FENCE_ACQ() __builtin_amdgcn_fence(__ATOMIC_ACQUIRE, "agent")
#else
#define FENCE_ACQ() __hip_atomic_fence(__ATOMIC_ACQUIRE, __HIP_MEMORY_SCOPE_AGENT)
#endif

// ---------------------------------------------------------------------------
// Persistent scan kernel. 169 WGs x 128 threads. WG168 = barrier master.
// wg -> (pipe, lw): pipes handle b-halves; twins (same lw) are 8 blocks apart
// (same XCD under round-robin dispatch) for L2 merge of weight fetches.
// lw 0..63: hidden-tile WGs (jt = lw); lw 64..83: out-cell / ccA tiles.
// State frag layout (per buffer, 128KB): [btile(4)][ks(32)][bl(16)][kg(4)][8 bf16]
// ---------------------------------------------------------------------------
__global__ __launch_bounds__(128, 1) void k_scan(
    const float* __restrict__ m_true,
    const u16* __restrict__ Wcell, const u16* __restrict__ Win_h,
    const u16* __restrict__ Win_x, const u16* __restrict__ Wout,
    const u16* __restrict__ WccA,
    const float* __restrict__ b_in, const float* __restrict__ b_cell,
    const float* __restrict__ cAb, const float* __restrict__ b_out,
    const float* __restrict__ b_cc,
    u16* hS, u16* cS, float* cF, float* ccB, float* outp, u32* bar)
{
  const int wg = blockIdx.x;
  const int tid = threadIdx.x;
  const int wave = tid >> 6, lane = tid & 63;

  // ---- master WG: flat-combining barrier server, all RELAXED ----
  if (wg == NARR){
    if (wave == 0){
      u32* arr = bar;
      u32* go  = bar + NARR*32;
      for (u32 ep = 1; ep <= NEPOCH; ++ep){
        for(;;){
          int ok = 1;
          if (lane < 56){
            u32 a0 = __hip_atomic_load(arr + lane*32,       __ATOMIC_RELAXED, __HIP_MEMORY_SCOPE_AGENT);
            u32 a1 = __hip_atomic_load(arr + (lane+56)*32,  __ATOMIC_RELAXED, __HIP_MEMORY_SCOPE_AGENT);
            u32 a2 = __hip_atomic_load(arr + (lane+112)*32, __ATOMIC_RELAXED, __HIP_MEMORY_SCOPE_AGENT);
            ok = (a0 >= ep) && (a1 >= ep) && (a2 >= ep);
          }
          if (__all(ok)) break;
          __builtin_amdgcn_s_sleep(1);
        }
        if (lane < NREP)
          __hip_atomic_store(go + lane*32, ep, __ATOMIC_RELAXED, __HIP_MEMORY_SCOPE_AGENT);
      }
    }
    return;
  }

  // pipe / local-index mapping (twins 8 apart -> same XCD mod 8)
  int pipe, lw;
  if (wg < 160){ pipe = (wg >> 3) & 1; lw = ((wg >> 4) << 3) | (wg & 7); }
  else         { pipe = (wg - 160) >> 2; lw = 80 + ((wg - 160) & 3); }

  const int bl = lane & 15, kg = lane >> 4;
  const int bt = (pipe << 1) + wave;        // btile this wave owns
  const int b  = (bt << 4) + bl;
  const int swz = (bl & 7) << 4;
  const int foff = ((bl << 2) + kg) << 4;   // byte offset of lane's frag piece
  const int woff = (bt << 15) + ((lw >> 1) << 10) + (bl << 6) + ((lw & 1) << 5) + (kg << 3);
  __shared__ __align__(16) u16 ldsW[40960 + 1024];   // 2x40KB weights + 2KB bias
  float* fb = (float*)(ldsW + 40960);

  auto stage_async = [&](const u16* src, u16* lb, int spw){
    const u16* g = src + ((size_t)(wave*spw) << 9) + (lane << 3);
    u16* l = lb + ((wave*spw) << 9);
    for (int s = 0; s < spw; ++s){
      __builtin_amdgcn_global_load_lds(
          (const __attribute__((address_space(1))) void*)g,
          (__attribute__((address_space(3))) void*)l, 16, 0, 0);
      g += 512; l += 512;
    }
    SCHEDB();
  };
  auto afL = [&](const u16* lb, int row, int kb) -> bf16x8 {
    return *(const bf16x8*)((const char*)lb + row*512 + (kb ^ swz));
  };

  // distributed barrier; acquire-agent fence + next-phase chunk0 prefetch
  auto gsync = [&](u32 ep, const u16* pfsrc, int pfspw){
    SCHEDB();
    __syncthreads();                  // drains vmcnt(0): all state stores at MALL
    if (tid == 0)
      __hip_atomic_store(bar + wg*32, ep, __ATOMIC_RELAXED, __HIP_MEMORY_SCOPE_AGENT);
    if (wave == 0) FENCE_ACQ();
    SCHEDB();
    if (pfsrc){
      const u16* g = pfsrc + ((size_t)(wave*pfspw) << 9) + (lane << 3);
      u16* l = ldsW + ((wave*pfspw) << 9);
      for (int s = 0; s < pfspw; ++s){
        __builtin_amdgcn_global_load_lds(
            (const __attribute__((address_space(1))) void*)g,
            (__attribute__((address_space(3))) void*)l, 16, 0, 0);
        g += 512; l += 512;
      }
    }
    SCHEDB();
    if (tid == 0){
      const u32* gp = bar + NARR*32 + (wg % NREP)*32;
      while (__hip_atomic_load(gp, __ATOMIC_RELAXED, __HIP_MEMORY_SCOPE_AGENT) < ep)
        __builtin_amdgcn_s_sleep(1);
      asm volatile("" ::: "memory");
    }
    __syncthreads();                  // orders fence before state loads; drains prefetch
    SCHEDB();
  };

  // ---- in-cell phase (lw<64). entry: buf0 = Win_h chunk0 (prefetched)
  auto phase_incell = [&](int t, const u16* hIn, u16* hOut, u16* cOut){
    f32x4 A0={0,0,0,0}, A1={0,0,0,0}, A2={0,0,0,0}, A3={0,0,0,0};
    const float* xr = m_true + (size_t)b*81920 + (size_t)(255 - t)*320;
    FRAG xf[10];
    #pragma unroll
    for (int ks = 0; ks < 10; ++ks){
      int k = (ks << 5) + (kg << 3);
      f32x4 x0 = *(const f32x4*)(xr + k);
      f32x4 x1 = *(const f32x4*)(xr + k + 4);
      xf[ks].s[0]=f2bf(x0[0]); xf[ks].s[1]=f2bf(x0[1]); xf[ks].s[2]=f2bf(x0[2]); xf[ks].s[3]=f2bf(x0[3]);
      xf[ks].s[4]=f2bf(x1[0]); xf[ks].s[5]=f2bf(x1[1]); xf[ks].s[6]=f2bf(x1[2]); xf[ks].s[7]=f2bf(x1[3]);
    }
    int jl = (kg << 2), jj = (lw << 4) + jl;
    f32x4 cpv = *(const f32x4*)((const char*)cF + ((size_t)b << 12) + (jj << 2));
    const char* hf = (const char*)hIn + (bt << 15) + foff;
    FRAG sh[2][8];
    #pragma unroll
    for (int ks = 0; ks < 8; ++ks) sh[0][ks].v = *(const bf16x8*)(hf + ks*1024);
    SCHEDB();
    const u16* Wb = Win_h + ((size_t)lw << 16);
    stage_async(Wb + 16384, ldsW + 20480, 16);      // S1 -> buf1
    #pragma unroll
    for (int c = 0; c < 4; ++c){
      if (c > 0){
        BARW();                                     // done reading buf[(c+1)&1]
        if (c < 3) stage_async(Wb + (size_t)(c+1)*16384, ldsW + ((c+1)&1)*20480, 16);
        else       stage_async(Win_x + (size_t)lw*20480, ldsW, 20);   // x -> buf0
      }
      if (c == 3) { WAITV(20); } else { WAITV(16); }
      if (c > 0) BARW();                            // cross-wave S_c drained
      if (c < 3){
        #pragma unroll
        for (int ks = 0; ks < 8; ++ks)
          sh[(c+1)&1][ks].v = *(const bf16x8*)(hf + ((c+1)*8 + ks)*1024);
        SCHEDB();
      }
      const u16* lb = ldsW + (c & 1)*20480;
      #pragma unroll
      for (int ks = 0; ks < 8; ++ks){
        int kb = (ks << 6) + (kg << 4);
        FRAG a;
        a.v = afL(lb, bl, kb);      A0 = MFMA16(a.v, sh[c&1][ks].v, A0);
        a.v = afL(lb, 16 + bl, kb); A1 = MFMA16(a.v, sh[c&1][ks].v, A1);
        a.v = afL(lb, 32 + bl, kb); A2 = MFMA16(a.v, sh[c&1][ks].v, A2);
        a.v = afL(lb, 48 + bl, kb); A3 = MFMA16(a.v, sh[c&1][ks].v, A3);
      }
    }
    WAITV(0); BARW();                               // x chunk ready in buf0
    #pragma unroll
    for (int ks = 0; ks < 8; ++ks){
      int kb = (ks << 6) + (kg << 4);
      FRAG a;
      a.v = afL(ldsW, bl, kb);      A0 = MFMA16(a.v, xf[ks].v, A0);
      a.v = afL(ldsW, 16 + bl, kb); A1 = MFMA16(a.v, xf[ks].v, A1);
      a.v = afL(ldsW, 32 + bl, kb); A2 = MFMA16(a.v, xf[ks].v, A2);
      a.v = afL(ldsW, 48 + bl, kb); A3 = MFMA16(a.v, xf[ks].v, A3);
    }
    #pragma unroll
    for (int ks = 0; ks < 2; ++ks){
      int kb = (ks << 6) + (kg << 4);
      FRAG a;
      a.v = *(const bf16x8*)((const char*)ldsW + 32768 + bl*128      + (kb ^ swz)); A0 = MFMA16(a.v, xf[8+ks].v, A0);
      a.v = *(const bf16x8*)((const char*)ldsW + 32768 + (16+bl)*128 + (kb ^ swz)); A1 = MFMA16(a.v, xf[8+ks].v, A1);
      a.v = *(const bf16x8*)((const char*)ldsW + 32768 + (32+bl)*128 + (kb ^ swz)); A2 = MFMA16(a.v, xf[8+ks].v, A2);
      a.v = *(const bf16x8*)((const char*)ldsW + 32768 + (48+bl)*128 + (kb ^ swz)); A3 = MFMA16(a.v, xf[8+ks].v, A3);
    }
    P4 hw, cw;
    #pragma unroll
    for (int r = 0; r < 4; ++r){
      float gi = A0[r] + fb[jl + r];
      float gf = A1[r] + fb[16 + jl + r];
      float gg = A2[r] + fb[32 + jl + r];
      float go = A3[r] + fb[48 + jl + r];
      float cn = sigm(gf)*cpv[r] + sigm(gi)*tanh_(gg);
      hw.s[r] = f2bf(sigm(go)*tanh_(cn));
      cw.s[r] = f2bf(cn);
    }
    ast((char*)hOut + woff, hw.q);
    ast((char*)cOut + woff, cw.q);
  };

  // ---- inner cell phase i (lw<64). entry: buf0 = Wcell_i chunk0
  auto phase_cell = [&](int i, const u16* hIn, const u16* cIn, u16* hOut, u16* cOut, bool last){
    f32x4 A0={0,0,0,0}, A1={0,0,0,0}, A2={0,0,0,0}, A3={0,0,0,0}, A4={0,0,0,0};
    const u16* Wb = Wcell + (size_t)(i*64 + lw) * 81920;
    const char* hf  = (const char*)hIn + (bt << 15) + foff;
    const char* cfr = (const char*)cIn + (bt << 15) + foff;
    FRAG sh[2][8], sc[2][8];
    #pragma unroll
    for (int ks = 0; ks < 8; ++ks){
      sh[0][ks].v = *(const bf16x8*)(hf + ks*1024);
      sc[0][ks].v = *(const bf16x8*)(cfr + ks*1024);
    }
    SCHEDB();
    stage_async(Wb + 20480, ldsW + 20480, 20);      // S1 -> buf1
    #pragma unroll
    for (int c = 0; c < 4; ++c){
      if (c > 0){
        BARW();
        if (c < 3) stage_async(Wb + (size_t)(c+1)*20480, ldsW + ((c+1)&1)*20480, 20);
      }
      if (c == 3) { WAITV(0); } else { WAITV(20); }
      if (c > 0) BARW();
      if (c < 3){
        #pragma unroll
        for (int ks = 0; ks < 8; ++ks){
          sh[(c+1)&1][ks].v = *(const bf16x8*)(hf + ((c+1)*8 + ks)*1024);
          sc[(c+1)&1][ks].v = *(const bf16x8*)(cfr + ((c+1)*8 + ks)*1024);
        }
        SCHEDB();
      }
      const u16* lb = ldsW + (c & 1)*20480;
      #pragma unroll
      for (int ks = 0; ks < 8; ++ks){
        int kb = (ks << 6) + (kg << 4);
        FRAG a;
        a.v = afL(lb, bl, kb);      A0 = MFMA16(a.v, sh[c&1][ks].v, A0);
        a.v = afL(lb, 16 + bl, kb); A1 = MFMA16(a.v, sh[c&1][ks].v, A1);
        a.v = afL(lb, 32 + bl, kb); A2 = MFMA16(a.v, sh[c&1][ks].v, A2);
        a.v = afL(lb, 48 + bl, kb); A3 = MFMA16(a.v, sh[c&1][ks].v, A3);
        a.v = afL(lb, 64 + bl, kb); A4 = MFMA16(a.v, sc[c&1][ks].v, A4);
      }
    }
    int jl = (kg << 2), jj = (lw << 4) + jl;
    P4 hw, cw; F4 cf4;
    #pragma unroll
    for (int r = 0; r < 4; ++r){
      float gi = A0[r] + fb[64 + i*80 + jl + r];
      float gf = A1[r] + fb[64 + i*80 + 16 + jl + r];
      float gg = A2[r] + fb[64 + i*80 + 32 + jl + r];
      float go = A3[r] + fb[64 + i*80 + 48 + jl + r];
      float c1 = A4[r] + fb[64 + i*80 + 64 + jl + r];
      float cn = sigm(gf)*c1 + sigm(gi)*tanh_(gg);
      hw.s[r] = f2bf(sigm(go)*tanh_(cn));
      cw.s[r] = f2bf(cn);
      cf4.f[r] = cn;
    }
    ast((char*)hOut + woff, hw.q);
    ast((char*)cOut + woff, cw.q);
    if (last){
      char* cfp = (char*)cF + ((size_t)b << 12) + (jj << 2);
      ast(cfp, cf4.q[0]); ast(cfp + 8, cf4.q[1]);
    }
  };

  // ---- ccA phase (lw 64..83, with cell i==3). entry: buf0 = WccA chunk0
  auto phase_ccA = [&](const u16* cIn){
    f32x4 A = {0,0,0,0};
    int w2 = lw - 64;
    const u16* Wb = WccA + ((size_t)w2 << 14);
    const char* cfr = (const char*)cIn + (bt << 15) + foff;
    FRAG sc[2][8];
    #pragma unroll
    for (int ks = 0; ks < 8; ++ks) sc[0][ks].v = *(const bf16x8*)(cfr + ks*1024);
    SCHEDB();
    stage_async(Wb + 4096, ldsW + 20480, 4);
    #pragma unroll
    for (int c = 0; c < 4; ++c){
      if (c > 0){
        BARW();
        if (c < 3) stage_async(Wb + (size_t)(c+1)*4096, ldsW + ((c+1)&1)*20480, 4);
      }
      if (c == 3) { WAITV(0); } else { WAITV(4); }
      if (c > 0) BARW();
      if (c < 3){
        #pragma unroll
        for (int ks = 0; ks < 8; ++ks)
          sc[(c+1)&1][ks].v = *(const bf16x8*)(cfr + ((c+1)*8 + ks)*1024);
        SCHEDB();
      }
      const u16* lb = ldsW + (c & 1)*20480;
      #pragma unroll
      for (int ks = 0; ks < 8; ++ks){
        int kb = (ks << 6) + (kg << 4);
        FRAG a; a.v = afL(lb, bl, kb);
        A = MFMA16(a.v, sc[c&1][ks].v, A);
      }
    }
    int jl = (kg << 2), jjo = (w2 << 4) + jl;
    F4 v;
    #pragma unroll
    for (int r = 0; r < 4; ++r) v.f[r] = A[r] + fb[64 + jl + r];
    char* cp2 = (char*)ccB + ((size_t)b*320 + jjo)*4;
    ast(cp2, v.q[0]); ast(cp2 + 8, v.q[1]);
  };

  // ---- out-cell phase (lw 64..83). entry: buf0 = Wout chunk0
  auto phase_out = [&](int t, const u16* hIn){
    f32x4 A0={0,0,0,0}, A1={0,0,0,0}, A2={0,0,0,0}, A3={0,0,0,0};
    int w2 = lw - 64;
    const u16* Wb = Wout + ((size_t)w2 << 16);
    const char* hf = (const char*)hIn + (bt << 15) + foff;
    int jl = (kg << 2), jjo = (w2 << 4) + jl;
    f32x4 ccv = *(const f32x4*)((const char*)ccB + ((size_t)b*320 + jjo)*4);
    FRAG sh[2][8];
    #pragma unroll
    for (int ks = 0; ks < 8; ++ks) sh[0][ks].v = *(const bf16x8*)(hf + ks*1024);
    SCHEDB();
    stage_async(Wb + 16384, ldsW + 20480, 16);
    #pragma unroll
    for (int c = 0; c < 4; ++c){
      if (c > 0){
        BARW();
        if (c < 3) stage_async(Wb + (size_t)(c+1)*16384, ldsW + ((c+1)&1)*20480, 16);
      }
      if (c == 3) { WAITV(0); } else { WAITV(16); }
      if (c > 0) BARW();
      if (c < 3){
        #pragma unroll
        for (int ks = 0; ks < 8; ++ks)
          sh[(c+1)&1][ks].v = *(const bf16x8*)(hf + ((c+1)*8 + ks)*1024);
        SCHEDB();
      }
      const u16* lb = ldsW + (c & 1)*20480;
      #pragma unroll
      for (int ks = 0; ks < 8; ++ks){
        int kb = (ks << 6) + (kg << 4);
        FRAG a;
        a.v = afL(lb, bl, kb);      A0 = MFMA16(a.v, sh[c&1][ks].v, A0);
        a.v = afL(lb, 16 + bl, kb); A1 = MFMA16(a.v, sh[c&1][ks].v, A1);
        a.v = afL(lb, 32 + bl, kb); A2 = MFMA16(a.v, sh[c&1][ks].v, A2);
        a.v = afL(lb, 48 + bl, kb); A3 = MFMA16(a.v, sh[c&1][ks].v, A3);
      }
    }
    f32x4 ho;
    #pragma unroll
    for (int r = 0; r < 4; ++r){
      float gi = A0[r] + fb[jl + r];
      float gf = A1[r] + fb[16 + jl + r];
      float gg = A2[r] + fb[32 + jl + r];
      float go = A3[r] + fb[48 + jl + r];
      float cn = sigm(gf)*ccv[r] + sigm(gi)*tanh_(gg);
      ho[r] = sigm(go)*tanh_(cn);
    }
    *(f32x4*)(outp + (size_t)b*81920 + (size_t)(t+1)*320 + jjo) = ho;
  };

  // ---- init: biases -> LDS, first chunk0 prefetch ----
  if (lw < 64){
    if (tid < 16){
      int q = tid, j0 = lw*16;
      for (int g = 0; g < 4; ++g) fb[g*16 + q] = b_in[g*1024 + j0 + q];
      for (int i2 = 0; i2 < 4; ++i2){
        for (int g = 0; g < 4; ++g)
          fb[64 + i2*80 + g*16 + q] = b_cell[i2*4096 + g*1024 + j0 + q];
        fb[64 + i2*80 + 64 + q] = cAb[i2*1024 + j0 + q];
      }
    }
    stage_async(Win_h + ((size_t)lw << 16), ldsW, 16);
  } else {
    if (tid < 16){
      int q = tid, j0 = (lw - 64)*16;
      for (int g = 0; g < 4; ++g) fb[g*16 + q] = b_out[g*320 + j0 + q];
      fb[64 + q] = b_cc[j0 + q];
    }
  }
  __syncthreads();
  SCHEDB();

  u16* hB0 = hS;        u16* hB1 = hS + 65536;
  u16* cB0 = cS;        u16* cB1 = cS + 65536;

  u32 ep = 1;
  if (lw < 64) phase_incell(0, hB1, hB0, cB0);
  gsync(ep++, (lw < 64) ? Wcell + (size_t)lw*81920 : nullptr, 20);
  int p = 1;
  #pragma unroll 1
  for (int t = 0; t < 255; ++t){
    #pragma unroll 1
    for (int i = 0; i < 4; ++i){
      u16* hIn = (p & 1) ? hB0 : hB1;  u16* cIn = (p & 1) ? cB0 : cB1;
      u16* hOut = (p & 1) ? hB1 : hB0; u16* cOut = (p & 1) ? cB1 : cB0;
      if (lw < 64)      phase_cell(i, hIn, cIn, hOut, cOut, i == 3);
      else if (i == 3)  phase_ccA(cIn);
      const u16* pf = nullptr; int spw = 0;
      if (lw < 64){
        if (i < 3){ pf = Wcell + (size_t)((i+1)*64 + lw)*81920; spw = 20; }
        else      { pf = Win_h + ((size_t)lw << 16);            spw = 16; }
      } else {
        if (i == 2){ pf = WccA + ((size_t)(lw-64) << 14); spw = 4; }
        else if (i == 3){ pf = Wout + ((size_t)(lw-64) << 16); spw = 16; }
      }
      gsync(ep++, pf, spw);
      ++p;
    }
    u16* hIn = (p & 1) ? hB0 : hB1;
    u16* hOut = (p & 1) ? hB1 : hB0; u16* cOut = (p & 1) ? cB1 : cB0;
    if (lw >= 64)       phase_out(t, hIn);
    else if (t < 254)   phase_incell(t + 1, hIn, hOut, cOut);
    gsync(ep++, (lw < 64 && t < 254) ? Wcell + (size_t)lw*81920 : nullptr, 20);
    ++p;
  }
}

// ---------------------------------------------------------------------------
// Precompute kernels (unchanged from R4)
// ---------------------------------------------------------------------------

__global__ __launch_bounds__(256) void k_dense(const float* __restrict__ X, int xmode,
    const float* __restrict__ W, const float* __restrict__ bias,
    int OD, int ID, int act, int omode, float* outF, u16* outB)
{
  int o = blockIdx.x*4 + (threadIdx.x >> 6);
  if (o >= OD) return;
  int lane = threadIdx.x & 63;
  const float* wr = W + (size_t)o*ID;
  float acc = 0.f;
  if (xmode == 0){ for (int k = 0; k < ID; ++k) acc = fmaf(wr[k], X[(size_t)lane*ID + k], acc); }
  else           { for (int k = 0; k < ID; ++k) acc = fmaf(wr[k], X[(size_t)k*64 + lane], acc); }
  acc += bias[o];
  if (act) acc = acc * sigm(acc);
  if (omode == 0)      outF[(size_t)o*64 + lane] = acc;
  else if (omode == 1){
    int bt = lane >> 4, blx = lane & 15;
    outB[(size_t)bt*16384 + (size_t)(o>>5)*512 + blx*32 + ((o&31)>>3)*8 + (o&7)] = f2bf(acc);
  }
  else if (omode == 2) outF[(size_t)lane*1024 + o] = acc;
  else                 outF[(size_t)lane*81920 + 256 + o] = acc;
}

__global__ void k_zero0(float* out){ out[(size_t)blockIdx.x*81920 + threadIdx.x] = 0.f; }

__global__ __launch_bounds__(256) void k_tr(const float* __restrict__ in, u16* __restrict__ out, int M, int N){
  __shared__ u16 t[64][65];
  int m0 = blockIdx.x << 6, n0 = blockIdx.y << 6;
  int c = threadIdx.x & 63, rq = threadIdx.x >> 6;
  for (int rr = 0; rr < 16; ++rr){
    int r = (rq << 4) + rr;
    t[r][c] = f2bf(in[(size_t)(m0 + r)*N + n0 + c]);
  }
  __syncthreads();
  for (int rr = 0; rr < 16; ++rr){
    int r = (rq << 4) + rr;
    out[(size_t)(n0 + r)*M + m0 + c] = t[c][r];
  }
}

__global__ __launch_bounds__(256) void k_fuse(const float* __restrict__ Whh, const float* __restrict__ Wih,
    const u16* __restrict__ BT, int KM, int mode, u16* __restrict__ dst)
{
  int bx = blockIdx.x, by = blockIdx.y, bz = blockIdx.z;
  int lane = threadIdx.x & 63, wv = threadIdx.x >> 6;
  int bl = lane & 15, kg = lane >> 4;
  int jbase = (mode == 0) ? bz*1024 : ((mode == 1) ? bz*320 : 0);
  int jrow = jbase + bx*16 + bl;
  int k2c = by*64 + wv*16 + bl;
  f32x4 acc = {0,0,0,0};
  for (int m0 = 0; m0 < KM; m0 += 32){
    f32x4 wa0 = *(const f32x4*)(Whh + (size_t)jrow*KM + m0 + (kg << 3));
    f32x4 wa1 = *(const f32x4*)(Whh + (size_t)jrow*KM + m0 + (kg << 3) + 4);
    FRAG a;
    a.s[0]=f2bf(wa0[0]); a.s[1]=f2bf(wa0[1]); a.s[2]=f2bf(wa0[2]); a.s[3]=f2bf(wa0[3]);
    a.s[4]=f2bf(wa1[0]); a.s[5]=f2bf(wa1[1]); a.s[6]=f2bf(wa1[2]); a.s[7]=f2bf(wa1[3]);
    FRAG bb; bb.v = *(const bf16x8*)(BT + (size_t)k2c*KM + m0 + (kg << 3));
    acc = MFMA16(a.v, bb.v, acc);
  }
  #pragma unroll
  for (int r = 0; r < 4; ++r){
    int jl = (kg << 2) + r;
    int jg = jbase + bx*16 + jl;
    float v = acc[r];
    if (mode < 2) v += Wih[(size_t)jg*1024 + k2c];
    int re = (mode == 2) ? jl : (bz*16 + jl);
    int c = k2c >> 8, kl = k2c & 255;
    size_t pos;
    if (mode == 0)      pos = (size_t)bx*81920 + c*20480 + re*256 + (kl ^ ((re&7)<<3));
    else if (mode == 1) pos = (size_t)bx*65536 + c*16384 + re*256 + (kl ^ ((re&7)<<3));
    else                pos = (size_t)bx*16384 + c*4096  + re*256 + (kl ^ ((re&7)<<3));
    dst[pos] = f2bf(v);
  }
}

__global__ void k_pack_winh(const float* __restrict__ src, u16* __restrict__ dst){
  int id = blockIdx.x*256 + threadIdx.x;
  int j = id >> 10, k = id & 1023;
  int g = j >> 10, jj = j & 1023;
  int w = jj >> 4, r = (g << 4) + (jj & 15);
  int c = k >> 8, kl = k & 255;
  dst[(size_t)w*65536 + c*16384 + r*256 + (kl ^ ((r&7)<<3))] = f2bf(src[id]);
}

__global__ void k_pack_winx(const float* __restrict__ src, u16* __restrict__ dst){
  int j = blockIdx.x, k = threadIdx.x;
  int g = j >> 10, jj = j & 1023;
  int w = jj >> 4, r = (g << 4) + (jj & 15);
  float v = src[(size_t)j*320 + k];
  size_t pos;
  if (k < 256) pos = (size_t)w*20480 + r*256 + (k ^ ((r&7)<<3));
  else         pos = (size_t)w*20480 + 16384 + r*64 + ((k - 256) ^ ((r&7)<<3));
  dst[pos] = f2bf(v);
}

__global__ void k_pack_ca(const float* __restrict__ src, u16* __restrict__ dst){
  int id = blockIdx.x*256 + threadIdx.x;
  int jj = id >> 10, k = id & 1023;
  int w = jj >> 4, r = 64 + (jj & 15);
  int c = k >> 8, kl = k & 255;
  dst[(size_t)w*81920 + c*20480 + r*256 + (kl ^ ((r&7)<<3))] = f2bf(src[id]);
}

__global__ __launch_bounds__(256) void k_bias(const float* __restrict__ A, const float* __restrict__ x,
    const float* __restrict__ a1, const float* __restrict__ a2, float* __restrict__ o, int NJ, int K)
{
  int j = blockIdx.x*4 + (threadIdx.x >> 6);
  if (j >= NJ) return;
  int lane = threadIdx.x & 63;
  float acc = 0.f;
  if (A) for (int k = lane; k < K; k += 64) acc += A[(size_t)j*K + k]*x[k];
  for (int off = 32; off; off >>= 1) acc += __shfl_down(acc, off);
  if (lane == 0) o[j] = acc + (a1 ? a1[j] : 0.f) + (a2 ? a2[j] : 0.f);
}

// ---------------------------------------------------------------------------
extern "C" void kernel_launch(void* const* d_in, const int* in_sizes, int n_in,
                              void* d_out, int out_size, void* d_ws, size_t ws_size,
                              hipStream_t stream)
{
  (void)in_sizes; (void)n_in; (void)out_size;
  const float* z      = (const float*)d_in[0];
  const float* m_true = (const float*)d_in[1];
  const float* eh_W1=(const float*)d_in[2],  *eh_b1=(const float*)d_in[3];
  const float* eh_W2=(const float*)d_in[4],  *eh_b2=(const float*)d_in[5];
  const float* eh_W3=(const float*)d_in[6],  *eh_b3=(const float*)d_in[7];
  const float* ec_W1=(const float*)d_in[8],  *ec_b1=(const float*)d_in[9];
  const float* ec_W2=(const float*)d_in[10], *ec_b2=(const float*)d_in[11];
  const float* ec_W3=(const float*)d_in[12], *ec_b3=(const float*)d_in[13];
  const float* ex_W1=(const float*)d_in[14], *ex_b1=(const float*)d_in[15];
  const float* ex_W2=(const float*)d_in[16], *ex_b2=(const float*)d_in[17];
  const float* ex_W3=(const float*)d_in[18], *ex_b3=(const float*)d_in[19];
  const float* in_Wih=(const float*)d_in[20], *in_Whh=(const float*)d_in[21];
  const float* in_bih=(const float*)d_in[22], *in_bhh=(const float*)d_in[23];
  const float* r_Wih=(const float*)d_in[24],  *r_Whh=(const float*)d_in[25];
  const float* r_bih=(const float*)d_in[26],  *r_bhh=(const float*)d_in[27];
  const float* hA_W=(const float*)d_in[28],   *hA_b=(const float*)d_in[29];
  const float* cA_W=(const float*)d_in[30],   *cA_b=(const float*)d_in[31];
  const float* lastH_W=(const float*)d_in[32], *lastH_b=(const float*)d_in[33];
  const float* lastC_W=(const float*)d_in[34], *lastC_b=(const float*)d_in[35];
  const float* out_Wih=(const float*)d_in[36], *out_Whh=(const float*)d_in[37];
  const float* out_bih=(const float*)d_in[38], *out_bhh=(const float*)d_in[39];
  float* out = (float*)d_out;

  char* wsb = (char*)d_ws;
  size_t off = 0;
  auto alloc = [&](size_t bytes)->char*{
    char* p = wsb + off; off = (off + bytes + 255) & ~(size_t)255; return p;
  };
  u32* bar    = (u32*)alloc(256*32*4);
  u16* hS     = (u16*)alloc(2*64*1024*2);
  u16* cS     = (u16*)alloc(2*64*1024*2);
  float* cF   = (float*)alloc(64*1024*4);
  float* ccB  = (float*)alloc(64*320*4);
  float* b_in = (float*)alloc(4096*4);
  float* b_cell=(float*)alloc(4*4096*4);
  float* b_out= (float*)alloc(1280*4);
  float* b_cc = (float*)alloc(320*4);
  float* t1   = (float*)alloc(1024*64*4);
  float* t2   = (float*)alloc(1024*64*4);
  u16* Tbuf   = (u16*)alloc((size_t)1024*1024*2);
  u16* Win_h  = (u16*)alloc((size_t)64*65536*2);
  u16* Win_x  = (u16*)alloc((size_t)64*20480*2);
  u16* Wcell  = (u16*)alloc((size_t)4*64*81920*2);
  u16* Wout   = (u16*)alloc((size_t)20*65536*2);
  u16* WccA   = (u16*)alloc((size_t)20*16384*2);
  if (off > ws_size) return;

  hipMemsetAsync(bar, 0, 256*32*4, stream);

  k_dense<<<256,256,0,stream>>>(z, 0, eh_W1, eh_b1, 1024, 256, 1, 0, t1, nullptr);
  k_dense<<<256,256,0,stream>>>(t1,1, eh_W2, eh_b2, 1024,1024, 1, 0, t2, nullptr);
  k_dense<<<256,256,0,stream>>>(t2,1, eh_W3, eh_b3, 1024,1024, 0, 1, nullptr, hS + 65536);
  k_dense<<<256,256,0,stream>>>(z, 0, ec_W1, ec_b1, 1024, 256, 1, 0, t1, nullptr);
  k_dense<<<256,256,0,stream>>>(t1,1, ec_W2, ec_b2, 1024,1024, 1, 0, t2, nullptr);
  k_dense<<<256,256,0,stream>>>(t2,1, ec_W3, ec_b3, 1024,1024, 0, 2, cF, nullptr);
  k_dense<<<256,256,0,stream>>>(z, 0, ex_W1, ex_b1, 1024, 256, 1, 0, t1, nullptr);
  k_dense<<<256,256,0,stream>>>(t1,1, ex_W2, ex_b2, 1024,1024, 1, 0, t2, nullptr);
  k_dense<<<16 ,256,0,stream>>>(t2,1, ex_W3, ex_b3,   64,1024, 0, 3, out, nullptr);
  k_zero0<<<64,256,0,stream>>>(out);

  k_pack_winh<<<16384,256,0,stream>>>(in_Whh, Win_h);
  k_pack_winx<<<4096,320,0,stream>>>(in_Wih, Win_x);
  for (int i = 0; i < 4; ++i)
    k_pack_ca<<<4096,256,0,stream>>>(cA_W + (size_t)i*1024*1024, Wcell + (size_t)i*64*81920);

  for (int i = 0; i < 4; ++i){
    k_tr<<<dim3(16,16),256,0,stream>>>(hA_W + (size_t)i*1024*1024, Tbuf, 1024, 1024);
    k_fuse<<<dim3(64,16,4),256,0,stream>>>(r_Whh + (size_t)i*4096*1024,
                                           r_Wih + (size_t)i*4096*1024,
                                           Tbuf, 1024, 0, Wcell + (size_t)i*64*81920);
  }
  k_tr<<<dim3(5,16),256,0,stream>>>(lastH_W, Tbuf, 320, 1024);
  k_fuse<<<dim3(20,16,4),256,0,stream>>>(out_Whh, out_Wih, Tbuf, 320, 1, Wout);
  k_tr<<<dim3(16,16),256,0,stream>>>(cA_W + (size_t)3*1024*1024, Tbuf, 1024, 1024);
  k_fuse<<<dim3(20,16,1),256,0,stream>>>(lastC_W, nullptr, Tbuf, 1024, 2, WccA);

  k_bias<<<1024,256,0,stream>>>(nullptr, nullptr, in_bih, in_bhh, b_in, 4096, 0);
  for (int i = 0; i < 4; ++i)
    k_bias<<<1024,256,0,stream>>>(r_Whh + (size_t)i*4096*1024, hA_b + i*1024,
                                  r_bih + i*4096, r_bhh + i*4096, b_cell + i*4096, 4096, 1024);
  k_bias<<<320,256,0,stream>>>(out_Whh, lastH_b, out_bih, out_bhh, b_out, 1280, 320);
  k_bias<<<80 ,256,0,stream>>>(lastC_W, cA_b + 3*1024, lastC_b, nullptr, b_cc, 320, 1024);

  k_scan<<<NWG,128,0,stream>>>(m_true, Wcell, Win_h, Win_x, Wout, WccA,
                               b_in, b_cell, cA_b, b_out, b_cc,
                               hS, cS, cF, ccB, out, bar);
}

// Round 6
// 14975.536 us; speedup vs baseline: 2.6366x; 1.0748x over previous
//
#include <hip/hip_runtime.h>

// BigARDecoder: persistent-kernel LSTM scan on MI355X.
// B=64, T=256, IN=256, H=1024, G=256, O=64, D=4, GO=320.
//
// R6: whole-phase-deep weight pipeline. 3 x 40KB LDS buffers; gsync prefetches
// chunk0+chunk1 (drained under the barrier wait), phase body issues ch2/ch3 +
// all state loads in one ordered stream with literal counted vmcnt waits.
// Collapses the chunk-boundary latency chain (4 x ~2us) to ~1 state-load
// latency + compute. Two half-batch pipelines (R5) and distributed RELAXED
// barrier + agent fence (R3/R4) kept.

typedef unsigned int u32;
typedef unsigned long long u64;
typedef unsigned short u16;
typedef __attribute__((ext_vector_type(8))) __bf16 bf16x8;
typedef __attribute__((ext_vector_type(4))) float f32x4;

#define DEVI __device__ __forceinline__

union FRAG { bf16x8 v; u16 s[8]; u64 q[2]; };
union P4 { u64 q; u16 s[4]; };
union F4 { u64 q[2]; float f[4]; };

DEVI u16 f2bf(float x){ u32 u = __float_as_uint(x); return (u16)((u + 0x7fffu + ((u>>16)&1u)) >> 16); }
DEVI float sigm(float x){ return 1.0f/(1.0f + __expf(-x)); }
DEVI float tanh_(float x){ return 2.0f/(1.0f + __expf(-2.0f*x)) - 1.0f; }
DEVI void ast(void* p, u64 v){ __hip_atomic_store((u64*)p, v, __ATOMIC_RELAXED, __HIP_MEMORY_SCOPE_AGENT); }

#define MFMA16(a,b,c) __builtin_amdgcn_mfma_f32_16x16x32_bf16(a, b, c, 0, 0, 0)

#define NARR 168          // compute WGs (arrive lines)
#define NWG 169           // + master
#define NREP 21
#define NEPOCH 1276

#define SCHEDB() __builtin_amdgcn_sched_barrier(0)
#define WAITV(n) do{ SCHEDB(); \
  asm volatile("s_waitcnt vmcnt(" #n ")" ::: "memory"); \
  SCHEDB(); }while(0)
#define BARW() do{ __builtin_amdgcn_s_barrier(); SCHEDB(); }while(0)

#if __has_builtin(__builtin_amdgcn_fence)
#define FENCE_ACQ() __builtin_amdgcn_fence(__ATOMIC_ACQUIRE, "agent")
#else
#define FENCE_ACQ() __hip_atomic_fence(__ATOMIC_ACQUIRE, __HIP_MEMORY_SCOPE_AGENT)
#endif

// ---------------------------------------------------------------------------
// Persistent scan kernel. 169 WGs x 128 threads. WG168 = barrier master.
// wg -> (pipe, lw): twins 8 apart (same XCD) for L2 merge of weight fetches.
// lw 0..63: hidden-tile WGs; lw 64..83: out-cell / ccA tiles.
// State frag layout (per buffer, 128KB): [btile(4)][ks(32)][bl(16)][kg(4)][8 bf16]
// LDS: B0/B1/B2 weight buffers (3 x 40KB) + 2KB bias.
// ---------------------------------------------------------------------------
__global__ __launch_bounds__(128, 1) void k_scan(
    const float* __restrict__ m_true,
    const u16* __restrict__ Wcell, const u16* __restrict__ Win_h,
    const u16* __restrict__ Win_x, const u16* __restrict__ Wout,
    const u16* __restrict__ WccA,
    const float* __restrict__ b_in, const float* __restrict__ b_cell,
    const float* __restrict__ cAb, const float* __restrict__ b_out,
    const float* __restrict__ b_cc,
    u16* hS, u16* cS, float* cF, float* ccB, float* outp, u32* bar)
{
  const int wg = blockIdx.x;
  const int tid = threadIdx.x;
  const int wave = tid >> 6, lane = tid & 63;

  // ---- master WG: flat-combining barrier server, all RELAXED ----
  if (wg == NARR){
    if (wave == 0){
      u32* arr = bar;
      u32* go  = bar + NARR*32;
      for (u32 ep = 1; ep <= NEPOCH; ++ep){
        for(;;){
          int ok = 1;
          if (lane < 56){
            u32 a0 = __hip_atomic_load(arr + lane*32,       __ATOMIC_RELAXED, __HIP_MEMORY_SCOPE_AGENT);
            u32 a1 = __hip_atomic_load(arr + (lane+56)*32,  __ATOMIC_RELAXED, __HIP_MEMORY_SCOPE_AGENT);
            u32 a2 = __hip_atomic_load(arr + (lane+112)*32, __ATOMIC_RELAXED, __HIP_MEMORY_SCOPE_AGENT);
            ok = (a0 >= ep) && (a1 >= ep) && (a2 >= ep);
          }
          if (__all(ok)) break;
          __builtin_amdgcn_s_sleep(1);
        }
        if (lane < NREP)
          __hip_atomic_store(go + lane*32, ep, __ATOMIC_RELAXED, __HIP_MEMORY_SCOPE_AGENT);
      }
    }
    return;
  }

  int pipe, lw;
  if (wg < 160){ pipe = (wg >> 3) & 1; lw = ((wg >> 4) << 3) | (wg & 7); }
  else         { pipe = (wg - 160) >> 2; lw = 80 + ((wg - 160) & 3); }

  const int bl = lane & 15, kg = lane >> 4;
  const int bt = (pipe << 1) + wave;        // btile this wave owns
  const int b  = (bt << 4) + bl;
  const int swz = (bl & 7) << 4;
  const int foff = ((bl << 2) + kg) << 4;
  const int woff = (bt << 15) + ((lw >> 1) << 10) + (bl << 6) + ((lw & 1) << 5) + (kg << 3);
  __shared__ __align__(16) u16 ldsW[61440 + 1024];   // B0,B1,B2 + bias
  u16* B0p = ldsW;
  u16* B1p = ldsW + 20480;
  u16* B2p = ldsW + 40960;
  float* fb = (float*)(ldsW + 61440);

  auto stage_async = [&](const u16* src, u16* lb, int spw){
    const u16* g = src + ((size_t)(wave*spw) << 9) + (lane << 3);
    u16* l = lb + ((wave*spw) << 9);
    for (int s = 0; s < spw; ++s){
      __builtin_amdgcn_global_load_lds(
          (const __attribute__((address_space(1))) void*)g,
          (__attribute__((address_space(3))) void*)l, 16, 0, 0);
      g += 512; l += 512;
    }
    SCHEDB();
  };
  auto afL = [&](const u16* lb, int row, int kb) -> bf16x8 {
    return *(const bf16x8*)((const char*)lb + row*512 + (kb ^ swz));
  };

  // distributed barrier; fence + two-chunk prefetch (B0,B1) under the wait
  auto gsync = [&](u32 ep, const u16* pfsrc, int cszu16, int pfspw){
    SCHEDB();
    __syncthreads();                  // drains vmcnt(0): state stores at MALL
    if (tid == 0)
      __hip_atomic_store(bar + wg*32, ep, __ATOMIC_RELAXED, __HIP_MEMORY_SCOPE_AGENT);
    if (wave == 0) FENCE_ACQ();
    SCHEDB();
    if (pfsrc){
      stage_async(pfsrc, B0p, pfspw);
      stage_async(pfsrc + cszu16, B1p, pfspw);
    }
    SCHEDB();
    if (tid == 0){
      const u32* gp = bar + NARR*32 + (wg % NREP)*32;
      while (__hip_atomic_load(gp, __ATOMIC_RELAXED, __HIP_MEMORY_SCOPE_AGENT) < ep)
        __builtin_amdgcn_s_sleep(1);
      asm volatile("" ::: "memory");
    }
    __syncthreads();                  // drains prefetch; orders fence
    SCHEDB();
  };

  // ---- in-cell phase (lw<64). entry: B0=in_h ch0, B1=ch1 ----
  auto phase_incell = [&](int t, const u16* hIn, u16* hOut, u16* cOut){
    f32x4 A0={0,0,0,0}, A1={0,0,0,0}, A2={0,0,0,0}, A3={0,0,0,0};
    const u16* Wb = Win_h + ((size_t)lw << 16);
    const char* hf = (const char*)hIn + (bt << 15) + foff;
    int jl = (kg << 2), jj = (lw << 4) + jl;
    FRAG sh[2][8], xf[10];
    // A-group: xf(20) + cpv(1) + h0(8) = 29
    const float* xr = m_true + (size_t)b*81920 + (size_t)(255 - t)*320;
    #pragma unroll
    for (int ks = 0; ks < 10; ++ks){
      int k = (ks << 5) + (kg << 3);
      f32x4 x0 = *(const f32x4*)(xr + k);
      f32x4 x1 = *(const f32x4*)(xr + k + 4);
      xf[ks].s[0]=f2bf(x0[0]); xf[ks].s[1]=f2bf(x0[1]); xf[ks].s[2]=f2bf(x0[2]); xf[ks].s[3]=f2bf(x0[3]);
      xf[ks].s[4]=f2bf(x1[0]); xf[ks].s[5]=f2bf(x1[1]); xf[ks].s[6]=f2bf(x1[2]); xf[ks].s[7]=f2bf(x1[3]);
    }
    f32x4 cpv = *(const f32x4*)((const char*)cF + ((size_t)b << 12) + (jj << 2));
    #pragma unroll
    for (int ks = 0; ks < 8; ++ks) sh[0][ks].v = *(const bf16x8*)(hf + ks*1024);
    SCHEDB();
    stage_async(Wb + 2*16384, B2p, 16);            // B: ch2
    WAITV(16);                                     // A done
    #pragma unroll
    for (int ks = 0; ks < 8; ++ks){                // c0 (B0)
      int kb = (ks << 6) + (kg << 4);
      FRAG a;
      a.v = afL(B0p, bl, kb);      A0 = MFMA16(a.v, sh[0][ks].v, A0);
      a.v = afL(B0p, 16 + bl, kb); A1 = MFMA16(a.v, sh[0][ks].v, A1);
      a.v = afL(B0p, 32 + bl, kb); A2 = MFMA16(a.v, sh[0][ks].v, A2);
      a.v = afL(B0p, 48 + bl, kb); A3 = MFMA16(a.v, sh[0][ks].v, A3);
    }
    #pragma unroll
    for (int ks = 0; ks < 8; ++ks) sh[1][ks].v = *(const bf16x8*)(hf + (8 + ks)*1024);  // C
    SCHEDB();
    BARW();                                        // B0 free
    stage_async(Wb + 3*16384, B0p, 16);            // D: ch3
    WAITV(16);                                     // B,C done
    BARW();                                        // ch2 visible
    #pragma unroll
    for (int ks = 0; ks < 8; ++ks) sh[0][ks].v = *(const bf16x8*)(hf + (16 + ks)*1024); // E
    SCHEDB();
    #pragma unroll
    for (int ks = 0; ks < 8; ++ks){                // c1 (B1)
      int kb = (ks << 6) + (kg << 4);
      FRAG a;
      a.v = afL(B1p, bl, kb);      A0 = MFMA16(a.v, sh[1][ks].v, A0);
      a.v = afL(B1p, 16 + bl, kb); A1 = MFMA16(a.v, sh[1][ks].v, A1);
      a.v = afL(B1p, 32 + bl, kb); A2 = MFMA16(a.v, sh[1][ks].v, A2);
      a.v = afL(B1p, 48 + bl, kb); A3 = MFMA16(a.v, sh[1][ks].v, A3);
    }
    #pragma unroll
    for (int ks = 0; ks < 8; ++ks) sh[1][ks].v = *(const bf16x8*)(hf + (24 + ks)*1024); // F
    SCHEDB();
    BARW();                                        // B1 free
    stage_async(Win_x + (size_t)lw*20480, B1p, 20);// G: x -> B1
    WAITV(28);                                     // D,E done (F8+G20 out)
    BARW();                                        // ch3 visible
    #pragma unroll
    for (int ks = 0; ks < 8; ++ks){                // c2 (B2)
      int kb = (ks << 6) + (kg << 4);
      FRAG a;
      a.v = afL(B2p, bl, kb);      A0 = MFMA16(a.v, sh[0][ks].v, A0);
      a.v = afL(B2p, 16 + bl, kb); A1 = MFMA16(a.v, sh[0][ks].v, A1);
      a.v = afL(B2p, 32 + bl, kb); A2 = MFMA16(a.v, sh[0][ks].v, A2);
      a.v = afL(B2p, 48 + bl, kb); A3 = MFMA16(a.v, sh[0][ks].v, A3);
    }
    WAITV(20);                                     // F done
    #pragma unroll
    for (int ks = 0; ks < 8; ++ks){                // c3 (B0)
      int kb = (ks << 6) + (kg << 4);
      FRAG a;
      a.v = afL(B0p, bl, kb);      A0 = MFMA16(a.v, sh[1][ks].v, A0);
      a.v = afL(B0p, 16 + bl, kb); A1 = MFMA16(a.v, sh[1][ks].v, A1);
      a.v = afL(B0p, 32 + bl, kb); A2 = MFMA16(a.v, sh[1][ks].v, A2);
      a.v = afL(B0p, 48 + bl, kb); A3 = MFMA16(a.v, sh[1][ks].v, A3);
    }
    WAITV(0);                                      // G done
    BARW();                                        // x visible
    #pragma unroll
    for (int ks = 0; ks < 8; ++ks){                // x part 1 (B1, 512B rows)
      int kb = (ks << 6) + (kg << 4);
      FRAG a;
      a.v = afL(B1p, bl, kb);      A0 = MFMA16(a.v, xf[ks].v, A0);
      a.v = afL(B1p, 16 + bl, kb); A1 = MFMA16(a.v, xf[ks].v, A1);
      a.v = afL(B1p, 32 + bl, kb); A2 = MFMA16(a.v, xf[ks].v, A2);
      a.v = afL(B1p, 48 + bl, kb); A3 = MFMA16(a.v, xf[ks].v, A3);
    }
    #pragma unroll
    for (int ks = 0; ks < 2; ++ks){                // x part 2 (128B rows)
      int kb = (ks << 6) + (kg << 4);
      const char* xb = (const char*)ldsW + 73728;
      FRAG a;
      a.v = *(const bf16x8*)(xb + bl*128      + (kb ^ swz)); A0 = MFMA16(a.v, xf[8+ks].v, A0);
      a.v = *(const bf16x8*)(xb + (16+bl)*128 + (kb ^ swz)); A1 = MFMA16(a.v, xf[8+ks].v, A1);
      a.v = *(const bf16x8*)(xb + (32+bl)*128 + (kb ^ swz)); A2 = MFMA16(a.v, xf[8+ks].v, A2);
      a.v = *(const bf16x8*)(xb + (48+bl)*128 + (kb ^ swz)); A3 = MFMA16(a.v, xf[8+ks].v, A3);
    }
    P4 hw, cw;
    #pragma unroll
    for (int r = 0; r < 4; ++r){
      float gi = A0[r] + fb[jl + r];
      float gf = A1[r] + fb[16 + jl + r];
      float gg = A2[r] + fb[32 + jl + r];
      float go = A3[r] + fb[48 + jl + r];
      float cn = sigm(gf)*cpv[r] + sigm(gi)*tanh_(gg);
      hw.s[r] = f2bf(sigm(go)*tanh_(cn));
      cw.s[r] = f2bf(cn);
    }
    ast((char*)hOut + woff, hw.q);
    ast((char*)cOut + woff, cw.q);
  };

  // ---- inner cell phase i (lw<64). entry: B0=ch0, B1=ch1 ----
  auto phase_cell = [&](int i, const u16* hIn, const u16* cIn, u16* hOut, u16* cOut, bool last){
    f32x4 A0={0,0,0,0}, A1={0,0,0,0}, A2={0,0,0,0}, A3={0,0,0,0}, A4={0,0,0,0};
    const u16* Wb = Wcell + (size_t)(i*64 + lw) * 81920;
    const char* hf  = (const char*)hIn + (bt << 15) + foff;
    const char* cfr = (const char*)cIn + (bt << 15) + foff;
    FRAG sh[2][8], sc[2][8];
    #pragma unroll
    for (int ks = 0; ks < 8; ++ks){                // A: state0 (16)
      sh[0][ks].v = *(const bf16x8*)(hf + ks*1024);
      sc[0][ks].v = *(const bf16x8*)(cfr + ks*1024);
    }
    SCHEDB();
    stage_async(Wb + 2*20480, B2p, 20);            // B: ch2
    WAITV(20);                                     // A done
    #pragma unroll
    for (int ks = 0; ks < 8; ++ks){                // c0 (B0)
      int kb = (ks << 6) + (kg << 4);
      FRAG a;
      a.v = afL(B0p, bl, kb);      A0 = MFMA16(a.v, sh[0][ks].v, A0);
      a.v = afL(B0p, 16 + bl, kb); A1 = MFMA16(a.v, sh[0][ks].v, A1);
      a.v = afL(B0p, 32 + bl, kb); A2 = MFMA16(a.v, sh[0][ks].v, A2);
      a.v = afL(B0p, 48 + bl, kb); A3 = MFMA16(a.v, sh[0][ks].v, A3);
      a.v = afL(B0p, 64 + bl, kb); A4 = MFMA16(a.v, sc[0][ks].v, A4);
    }
    #pragma unroll
    for (int ks = 0; ks < 8; ++ks){                // C: state1 (16)
      sh[1][ks].v = *(const bf16x8*)(hf + (8 + ks)*1024);
      sc[1][ks].v = *(const bf16x8*)(cfr + (8 + ks)*1024);
    }
    SCHEDB();
    BARW();                                        // B0 free
    stage_async(Wb + 3*20480, B0p, 20);            // D: ch3
    WAITV(20);                                     // B,C done
    BARW();                                        // ch2 visible
    #pragma unroll
    for (int ks = 0; ks < 8; ++ks){                // E: state2 (16)
      sh[0][ks].v = *(const bf16x8*)(hf + (16 + ks)*1024);
      sc[0][ks].v = *(const bf16x8*)(cfr + (16 + ks)*1024);
    }
    SCHEDB();
    #pragma unroll
    for (int ks = 0; ks < 8; ++ks){                // c1 (B1)
      int kb = (ks << 6) + (kg << 4);
      FRAG a;
      a.v = afL(B1p, bl, kb);      A0 = MFMA16(a.v, sh[1][ks].v, A0);
      a.v = afL(B1p, 16 + bl, kb); A1 = MFMA16(a.v, sh[1][ks].v, A1);
      a.v = afL(B1p, 32 + bl, kb); A2 = MFMA16(a.v, sh[1][ks].v, A2);
      a.v = afL(B1p, 48 + bl, kb); A3 = MFMA16(a.v, sh[1][ks].v, A3);
      a.v = afL(B1p, 64 + bl, kb); A4 = MFMA16(a.v, sc[1][ks].v, A4);
    }
    #pragma unroll
    for (int ks = 0; ks < 8; ++ks){                // F: state3 (16)
      sh[1][ks].v = *(const bf16x8*)(hf + (24 + ks)*1024);
      sc[1][ks].v = *(const bf16x8*)(cfr + (24 + ks)*1024);
    }
    SCHEDB();
    WAITV(16);                                     // D,E done (F out)
    BARW();                                        // ch3 visible
    #pragma unroll
    for (int ks = 0; ks < 8; ++ks){                // c2 (B2)
      int kb = (ks << 6) + (kg << 4);
      FRAG a;
      a.v = afL(B2p, bl, kb);      A0 = MFMA16(a.v, sh[0][ks].v, A0);
      a.v = afL(B2p, 16 + bl, kb); A1 = MFMA16(a.v, sh[0][ks].v, A1);
      a.v = afL(B2p, 32 + bl, kb); A2 = MFMA16(a.v, sh[0][ks].v, A2);
      a.v = afL(B2p, 48 + bl, kb); A3 = MFMA16(a.v, sh[0][ks].v, A3);
      a.v = afL(B2p, 64 + bl, kb); A4 = MFMA16(a.v, sc[0][ks].v, A4);
    }
    WAITV(0);                                      // F done
    #pragma unroll
    for (int ks = 0; ks < 8; ++ks){                // c3 (B0)
      int kb = (ks << 6) + (kg << 4);
      FRAG a;
      a.v = afL(B0p, bl, kb);      A0 = MFMA16(a.v, sh[1][ks].v, A0);
      a.v = afL(B0p, 16 + bl, kb); A1 = MFMA16(a.v, sh[1][ks].v, A1);
      a.v = afL(B0p, 32 + bl, kb); A2 = MFMA16(a.v, sh[1][ks].v, A2);
      a.v = afL(B0p, 48 + bl, kb); A3 = MFMA16(a.v, sh[1][ks].v, A3);
      a.v = afL(B0p, 64 + bl, kb); A4 = MFMA16(a.v, sc[1][ks].v, A4);
    }
    int jl = (kg << 2), jj = (lw << 4) + jl;
    P4 hw, cw; F4 cf4;
    #pragma unroll
    for (int r = 0; r < 4; ++r){
      float gi = A0[r] + fb[64 + i*80 + jl + r];
      float gf = A1[r] + fb[64 + i*80 + 16 + jl + r];
      float gg = A2[r] + fb[64 + i*80 + 32 + jl + r];
      float go = A3[r] + fb[64 + i*80 + 48 + jl + r];
      float c1 = A4[r] + fb[64 + i*80 + 64 + jl + r];
      float cn = sigm(gf)*c1 + sigm(gi)*tanh_(gg);
      hw.s[r] = f2bf(sigm(go)*tanh_(cn));
      cw.s[r] = f2bf(cn);
      cf4.f[r] = cn;
    }
    ast((char*)hOut + woff, hw.q);
    ast((char*)cOut + woff, cw.q);
    if (last){
      char* cfp = (char*)cF + ((size_t)b << 12) + (jj << 2);
      ast(cfp, cf4.q[0]); ast(cfp + 8, cf4.q[1]);
    }
  };

  // ---- ccA phase (lw 64..83, with cell i==3). entry: B0=ch0, B1=ch1 ----
  auto phase_ccA = [&](const u16* cIn){
    f32x4 A = {0,0,0,0};
    int w2 = lw - 64;
    const u16* Wb = WccA + ((size_t)w2 << 14);
    const char* cfr = (const char*)cIn + (bt << 15) + foff;
    FRAG sc[2][8];
    #pragma unroll
    for (int ks = 0; ks < 8; ++ks) sc[0][ks].v = *(const bf16x8*)(cfr + ks*1024);   // A(8)
    SCHEDB();
    stage_async(Wb + 2*4096, B2p, 4);              // B: ch2
    WAITV(4);                                      // A done
    #pragma unroll
    for (int ks = 0; ks < 8; ++ks){                // c0 (B0)
      int kb = (ks << 6) + (kg << 4);
      FRAG a; a.v = afL(B0p, bl, kb);
      A = MFMA16(a.v, sc[0][ks].v, A);
    }
    #pragma unroll
    for (int ks = 0; ks < 8; ++ks) sc[1][ks].v = *(const bf16x8*)(cfr + (8+ks)*1024); // C(8)
    SCHEDB();
    BARW();                                        // B0 free
    stage_async(Wb + 3*4096, B0p, 4);              // D: ch3
    WAITV(4);                                      // B,C done
    BARW();                                        // ch2 visible
    #pragma unroll
    for (int ks = 0; ks < 8; ++ks) sc[0][ks].v = *(const bf16x8*)(cfr + (16+ks)*1024); // E(8)
    SCHEDB();
    #pragma unroll
    for (int ks = 0; ks < 8; ++ks){                // c1 (B1)
      int kb = (ks << 6) + (kg << 4);
      FRAG a; a.v = afL(B1p, bl, kb);
      A = MFMA16(a.v, sc[1][ks].v, A);
    }
    #pragma unroll
    for (int ks = 0; ks < 8; ++ks) sc[1][ks].v = *(const bf16x8*)(cfr + (24+ks)*1024); // F(8)
    SCHEDB();
    WAITV(8);                                      // D,E done (F out)
    BARW();                                        // ch3 visible
    #pragma unroll
    for (int ks = 0; ks < 8; ++ks){                // c2 (B2)
      int kb = (ks << 6) + (kg << 4);
      FRAG a; a.v = afL(B2p, bl, kb);
      A = MFMA16(a.v, sc[0][ks].v, A);
    }
    WAITV(0);                                      // F done
    #pragma unroll
    for (int ks = 0; ks < 8; ++ks){                // c3 (B0)
      int kb = (ks << 6) + (kg << 4);
      FRAG a; a.v = afL(B0p, bl, kb);
      A = MFMA16(a.v, sc[1][ks].v, A);
    }
    int jl = (kg << 2), jjo = (w2 << 4) + jl;
    F4 v;
    #pragma unroll
    for (int r = 0; r < 4; ++r) v.f[r] = A[r] + fb[64 + jl + r];
    char* cp2 = (char*)ccB + ((size_t)b*320 + jjo)*4;
    ast(cp2, v.q[0]); ast(cp2 + 8, v.q[1]);
  };

  // ---- out-cell phase (lw 64..83). entry: B0=ch0, B1=ch1 ----
  auto phase_out = [&](int t, const u16* hIn){
    f32x4 A0={0,0,0,0}, A1={0,0,0,0}, A2={0,0,0,0}, A3={0,0,0,0};
    int w2 = lw - 64;
    const u16* Wb = Wout + ((size_t)w2 << 16);
    const char* hf = (const char*)hIn + (bt << 15) + foff;
    int jl = (kg << 2), jjo = (w2 << 4) + jl;
    FRAG sh[2][8];
    f32x4 ccv = *(const f32x4*)((const char*)ccB + ((size_t)b*320 + jjo)*4);  // A(1)
    #pragma unroll
    for (int ks = 0; ks < 8; ++ks) sh[0][ks].v = *(const bf16x8*)(hf + ks*1024); // A(8)
    SCHEDB();
    stage_async(Wb + 2*16384, B2p, 16);            // B: ch2
    WAITV(16);                                     // A done
    #pragma unroll
    for (int ks = 0; ks < 8; ++ks){                // c0 (B0)
      int kb = (ks << 6) + (kg << 4);
      FRAG a;
      a.v = afL(B0p, bl, kb);      A0 = MFMA16(a.v, sh[0][ks].v, A0);
      a.v = afL(B0p, 16 + bl, kb); A1 = MFMA16(a.v, sh[0][ks].v, A1);
      a.v = afL(B0p, 32 + bl, kb); A2 = MFMA16(a.v, sh[0][ks].v, A2);
      a.v = afL(B0p, 48 + bl, kb); A3 = MFMA16(a.v, sh[0][ks].v, A3);
    }
    #pragma unroll
    for (int ks = 0; ks < 8; ++ks) sh[1][ks].v = *(const bf16x8*)(hf + (8+ks)*1024); // C
    SCHEDB();
    BARW();                                        // B0 free
    stage_async(Wb + 3*16384, B0p, 16);            // D: ch3
    WAITV(16);                                     // B,C done
    BARW();                                        // ch2 visible
    #pragma unroll
    for (int ks = 0; ks < 8; ++ks) sh[0][ks].v = *(const bf16x8*)(hf + (16+ks)*1024); // E
    SCHEDB();
    #pragma unroll
    for (int ks = 0; ks < 8; ++ks){                // c1 (B1)
      int kb = (ks << 6) + (kg << 4);
      FRAG a;
      a.v = afL(B1p, bl, kb);      A0 = MFMA16(a.v, sh[1][ks].v, A0);
      a.v = afL(B1p, 16 + bl, kb); A1 = MFMA16(a.v, sh[1][ks].v, A1);
      a.v = afL(B1p, 32 + bl, kb); A2 = MFMA16(a.v, sh[1][ks].v, A2);
      a.v = afL(B1p, 48 + bl, kb); A3 = MFMA16(a.v, sh[1][ks].v, A3);
    }
    #pragma unroll
    for (int ks = 0; ks < 8; ++ks) sh[1][ks].v = *(const bf16x8*)(hf + (24+ks)*1024); // F
    SCHEDB();
    WAITV(8);                                      // D,E done (F out)
    BARW();                                        // ch3 visible
    #pragma unroll
    for (int ks = 0; ks < 8; ++ks){                // c2 (B2)
      int kb = (ks << 6) + (kg << 4);
      FRAG a;
      a.v = afL(B2p, bl, kb);      A0 = MFMA16(a.v, sh[0][ks].v, A0);
      a.v = afL(B2p, 16 + bl, kb); A1 = MFMA16(a.v, sh[0][ks].v, A1);
      a.v = afL(B2p, 32 + bl, kb); A2 = MFMA16(a.v, sh[0][ks].v, A2);
      a.v = afL(B2p, 48 + bl, kb); A3 = MFMA16(a.v, sh[0][ks].v, A3);
    }
    WAITV(0);                                      // F done
    #pragma unroll
    for (int ks = 0; ks < 8; ++ks){                // c3 (B0)
      int kb = (ks << 6) + (kg << 4);
      FRAG a;
      a.v = afL(B0p, bl, kb);      A0 = MFMA16(a.v, sh[1][ks].v, A0);
      a.v = afL(B0p, 16 + bl, kb); A1 = MFMA16(a.v, sh[1][ks].v, A1);
      a.v = afL(B0p, 32 + bl, kb); A2 = MFMA16(a.v, sh[1][ks].v, A2);
      a.v = afL(B0p, 48 + bl, kb); A3 = MFMA16(a.v, sh[1][ks].v, A3);
    }
    f32x4 ho;
    #pragma unroll
    for (int r = 0; r < 4; ++r){
      float gi = A0[r] + fb[jl + r];
      float gf = A1[r] + fb[16 + jl + r];
      float gg = A2[r] + fb[32 + jl + r];
      float go = A3[r] + fb[48 + jl + r];
      float cn = sigm(gf)*ccv[r] + sigm(gi)*tanh_(gg);
      ho[r] = sigm(go)*tanh_(cn);
    }
    *(f32x4*)(outp + (size_t)b*81920 + (size_t)(t+1)*320 + jjo) = ho;
  };

  // ---- init: biases -> LDS, first two-chunk prefetch ----
  if (lw < 64){
    if (tid < 16){
      int q = tid, j0 = lw*16;
      for (int g = 0; g < 4; ++g) fb[g*16 + q] = b_in[g*1024 + j0 + q];
      for (int i2 = 0; i2 < 4; ++i2){
        for (int g = 0; g < 4; ++g)
          fb[64 + i2*80 + g*16 + q] = b_cell[i2*4096 + g*1024 + j0 + q];
        fb[64 + i2*80 + 64 + q] = cAb[i2*1024 + j0 + q];
      }
    }
    stage_async(Win_h + ((size_t)lw << 16), B0p, 16);
    stage_async(Win_h + ((size_t)lw << 16) + 16384, B1p, 16);
  } else {
    if (tid < 16){
      int q = tid, j0 = (lw - 64)*16;
      for (int g = 0; g < 4; ++g) fb[g*16 + q] = b_out[g*320 + j0 + q];
      fb[64 + q] = b_cc[j0 + q];
    }
  }
  __syncthreads();
  SCHEDB();

  u16* hB0 = hS;        u16* hB1 = hS + 65536;
  u16* cB0 = cS;        u16* cB1 = cS + 65536;

  u32 ep = 1;
  if (lw < 64) phase_incell(0, hB1, hB0, cB0);
  gsync(ep++, (lw < 64) ? Wcell + (size_t)lw*81920 : nullptr, 20480, 20);
  int p = 1;
  #pragma unroll 1
  for (int t = 0; t < 255; ++t){
    #pragma unroll 1
    for (int i = 0; i < 4; ++i){
      u16* hIn = (p & 1) ? hB0 : hB1;  u16* cIn = (p & 1) ? cB0 : cB1;
      u16* hOut = (p & 1) ? hB1 : hB0; u16* cOut = (p & 1) ? cB1 : cB0;
      if (lw < 64)      phase_cell(i, hIn, cIn, hOut, cOut, i == 3);
      else if (i == 3)  phase_ccA(cIn);
      const u16* pf = nullptr; int csz = 0, spw = 0;
      if (lw < 64){
        if (i < 3){ pf = Wcell + (size_t)((i+1)*64 + lw)*81920; csz = 20480; spw = 20; }
        else      { pf = Win_h + ((size_t)lw << 16);            csz = 16384; spw = 16; }
      } else {
        if (i == 2){ pf = WccA + ((size_t)(lw-64) << 14); csz = 4096; spw = 4; }
        else if (i == 3){ pf = Wout + ((size_t)(lw-64) << 16); csz = 16384; spw = 16; }
      }
      gsync(ep++, pf, csz, spw);
      ++p;
    }
    u16* hIn = (p & 1) ? hB0 : hB1;
    u16* hOut = (p & 1) ? hB1 : hB0; u16* cOut = (p & 1) ? cB1 : cB0;
    if (lw >= 64)       phase_out(t, hIn);
    else if (t < 254)   phase_incell(t + 1, hIn, hOut, cOut);
    gsync(ep++, (lw < 64 && t < 254) ? Wcell + (size_t)lw*81920 : nullptr, 20480, 20);
    ++p;
  }
}

// ---------------------------------------------------------------------------
// Precompute kernels (unchanged)
// ---------------------------------------------------------------------------

__global__ __launch_bounds__(256) void k_dense(const float* __restrict__ X, int xmode,
    const float* __restrict__ W, const float* __restrict__ bias,
    int OD, int ID, int act, int omode, float* outF, u16* outB)
{
  int o = blockIdx.x*4 + (threadIdx.x >> 6);
  if (o >= OD) return;
  int lane = threadIdx.x & 63;
  const float* wr = W + (size_t)o*ID;
  float acc = 0.f;
  if (xmode == 0){ for (int k = 0; k < ID; ++k) acc = fmaf(wr[k], X[(size_t)lane*ID + k], acc); }
  else           { for (int k = 0; k < ID; ++k) acc = fmaf(wr[k], X[(size_t)k*64 + lane], acc); }
  acc += bias[o];
  if (act) acc = acc * sigm(acc);
  if (omode == 0)      outF[(size_t)o*64 + lane] = acc;
  else if (omode == 1){
    int bt = lane >> 4, blx = lane & 15;
    outB[(size_t)bt*16384 + (size_t)(o>>5)*512 + blx*32 + ((o&31)>>3)*8 + (o&7)] = f2bf(acc);
  }
  else if (omode == 2) outF[(size_t)lane*1024 + o] = acc;
  else                 outF[(size_t)lane*81920 + 256 + o] = acc;
}

__global__ void k_zero0(float* out){ out[(size_t)blockIdx.x*81920 + threadIdx.x] = 0.f; }

__global__ __launch_bounds__(256) void k_tr(const float* __restrict__ in, u16* __restrict__ out, int M, int N){
  __shared__ u16 t[64][65];
  int m0 = blockIdx.x << 6, n0 = blockIdx.y << 6;
  int c = threadIdx.x & 63, rq = threadIdx.x >> 6;
  for (int rr = 0; rr < 16; ++rr){
    int r = (rq << 4) + rr;
    t[r][c] = f2bf(in[(size_t)(m0 + r)*N + n0 + c]);
  }
  __syncthreads();
  for (int rr = 0; rr < 16; ++rr){
    int r = (rq << 4) + rr;
    out[(size_t)(n0 + r)*M + m0 + c] = t[c][r];
  }
}

__global__ __launch_bounds__(256) void k_fuse(const float* __restrict__ Whh, const float* __restrict__ Wih,
    const u16* __restrict__ BT, int KM, int mode, u16* __restrict__ dst)
{
  int bx = blockIdx.x, by = blockIdx.y, bz = blockIdx.z;
  int lane = threadIdx.x & 63, wv = threadIdx.x >> 6;
  int bl = lane & 15, kg = lane >> 4;
  int jbase = (mode == 0) ? bz*1024 : ((mode == 1) ? bz*320 : 0);
  int jrow = jbase + bx*16 + bl;
  int k2c = by*64 + wv*16 + bl;
  f32x4 acc = {0,0,0,0};
  for (int m0 = 0; m0 < KM; m0 += 32){
    f32x4 wa0 = *(const f32x4*)(Whh + (size_t)jrow*KM + m0 + (kg << 3));
    f32x4 wa1 = *(const f32x4*)(Whh + (size_t)jrow*KM + m0 + (kg << 3) + 4);
    FRAG a;
    a.s[0]=f2bf(wa0[0]); a.s[1]=f2bf(wa0[1]); a.s[2]=f2bf(wa0[2]); a.s[3]=f2bf(wa0[3]);
    a.s[4]=f2bf(wa1[0]); a.s[5]=f2bf(wa1[1]); a.s[6]=f2bf(wa1[2]); a.s[7]=f2bf(wa1[3]);
    FRAG bb; bb.v = *(const bf16x8*)(BT + (size_t)k2c*KM + m0 + (kg << 3));
    acc = MFMA16(a.v, bb.v, acc);
  }
  #pragma unroll
  for (int r = 0; r < 4; ++r){
    int jl = (kg << 2) + r;
    int jg = jbase + bx*16 + jl;
    float v = acc[r];
    if (mode < 2) v += Wih[(size_t)jg*1024 + k2c];
    int re = (mode == 2) ? jl : (bz*16 + jl);
    int c = k2c >> 8, kl = k2c & 255;
    size_t pos;
    if (mode == 0)      pos = (size_t)bx*81920 + c*20480 + re*256 + (kl ^ ((re&7)<<3));
    else if (mode == 1) pos = (size_t)bx*65536 + c*16384 + re*256 + (kl ^ ((re&7)<<3));
    else                pos = (size_t)bx*16384 + c*4096  + re*256 + (kl ^ ((re&7)<<3));
    dst[pos] = f2bf(v);
  }
}

__global__ void k_pack_winh(const float* __restrict__ src, u16* __restrict__ dst){
  int id = blockIdx.x*256 + threadIdx.x;
  int j = id >> 10, k = id & 1023;
  int g = j >> 10, jj = j & 1023;
  int w = jj >> 4, r = (g << 4) + (jj & 15);
  int c = k >> 8, kl = k & 255;
  dst[(size_t)w*65536 + c*16384 + r*256 + (kl ^ ((r&7)<<3))] = f2bf(src[id]);
}

__global__ void k_pack_winx(const float* __restrict__ src, u16* __restrict__ dst){
  int j = blockIdx.x, k = threadIdx.x;
  int g = j >> 10, jj = j & 1023;
  int w = jj >> 4, r = (g << 4) + (jj & 15);
  float v = src[(size_t)j*320 + k];
  size_t pos;
  if (k < 256) pos = (size_t)w*20480 + r*256 + (k ^ ((r&7)<<3));
  else         pos = (size_t)w*20480 + 16384 + r*64 + ((k - 256) ^ ((r&7)<<3));
  dst[pos] = f2bf(v);
}

__global__ void k_pack_ca(const float* __restrict__ src, u16* __restrict__ dst){
  int id = blockIdx.x*256 + threadIdx.x;
  int jj = id >> 10, k = id & 1023;
  int w = jj >> 4, r = 64 + (jj & 15);
  int c = k >> 8, kl = k & 255;
  dst[(size_t)w*81920 + c*20480 + r*256 + (kl ^ ((r&7)<<3))] = f2bf(src[id]);
}

__global__ __launch_bounds__(256) void k_bias(const float* __restrict__ A, const float* __restrict__ x,
    const float* __restrict__ a1, const float* __restrict__ a2, float* __restrict__ o, int NJ, int K)
{
  int j = blockIdx.x*4 + (threadIdx.x >> 6);
  if (j >= NJ) return;
  int lane = threadIdx.x & 63;
  float acc = 0.f;
  if (A) for (int k = lane; k < K; k += 64) acc += A[(size_t)j*K + k]*x[k];
  for (int off = 32; off; off >>= 1) acc += __shfl_down(acc, off);
  if (lane == 0) o[j] = acc + (a1 ? a1[j] : 0.f) + (a2 ? a2[j] : 0.f);
}

// ---------------------------------------------------------------------------
extern "C" void kernel_launch(void* const* d_in, const int* in_sizes, int n_in,
                              void* d_out, int out_size, void* d_ws, size_t ws_size,
                              hipStream_t stream)
{
  (void)in_sizes; (void)n_in; (void)out_size;
  const float* z      = (const float*)d_in[0];
  const float* m_true = (const float*)d_in[1];
  const float* eh_W1=(const float*)d_in[2],  *eh_b1=(const float*)d_in[3];
  const float* eh_W2=(const float*)d_in[4],  *eh_b2=(const float*)d_in[5];
  const float* eh_W3=(const float*)d_in[6],  *eh_b3=(const float*)d_in[7];
  const float* ec_W1=(const float*)d_in[8],  *ec_b1=(const float*)d_in[9];
  const float* ec_W2=(const float*)d_in[10], *ec_b2=(const float*)d_in[11];
  const float* ec_W3=(const float*)d_in[12], *ec_b3=(const float*)d_in[13];
  const float* ex_W1=(const float*)d_in[14], *ex_b1=(const float*)d_in[15];
  const float* ex_W2=(const float*)d_in[16], *ex_b2=(const float*)d_in[17];
  const float* ex_W3=(const float*)d_in[18], *ex_b3=(const float*)d_in[19];
  const float* in_Wih=(const float*)d_in[20], *in_Whh=(const float*)d_in[21];
  const float* in_bih=(const float*)d_in[22], *in_bhh=(const float*)d_in[23];
  const float* r_Wih=(const float*)d_in[24],  *r_Whh=(const float*)d_in[25];
  const float* r_bih=(const float*)d_in[26],  *r_bhh=(const float*)d_in[27];
  const float* hA_W=(const float*)d_in[28],   *hA_b=(const float*)d_in[29];
  const float* cA_W=(const float*)d_in[30],   *cA_b=(const float*)d_in[31];
  const float* lastH_W=(const float*)d_in[32], *lastH_b=(const float*)d_in[33];
  const float* lastC_W=(const float*)d_in[34], *lastC_b=(const float*)d_in[35];
  const float* out_Wih=(const float*)d_in[36], *out_Whh=(const float*)d_in[37];
  const float* out_bih=(const float*)d_in[38], *out_bhh=(const float*)d_in[39];
  float* out = (float*)d_out;

  char* wsb = (char*)d_ws;
  size_t off = 0;
  auto alloc = [&](size_t bytes)->char*{
    char* p = wsb + off; off = (off + bytes + 255) & ~(size_t)255; return p;
  };
  u32* bar    = (u32*)alloc(256*32*4);
  u16* hS     = (u16*)alloc(2*64*1024*2);
  u16* cS     = (u16*)alloc(2*64*1024*2);
  float* cF   = (float*)alloc(64*1024*4);
  float* ccB  = (float*)alloc(64*320*4);
  float* b_in = (float*)alloc(4096*4);
  float* b_cell=(float*)alloc(4*4096*4);
  float* b_out= (float*)alloc(1280*4);
  float* b_cc = (float*)alloc(320*4);
  float* t1   = (float*)alloc(1024*64*4);
  float* t2   = (float*)alloc(1024*64*4);
  u16* Tbuf   = (u16*)alloc((size_t)1024*1024*2);
  u16* Win_h  = (u16*)alloc((size_t)64*65536*2);
  u16* Win_x  = (u16*)alloc((size_t)64*20480*2);
  u16* Wcell  = (u16*)alloc((size_t)4*64*81920*2);
  u16* Wout   = (u16*)alloc((size_t)20*65536*2);
  u16* WccA   = (u16*)alloc((size_t)20*16384*2);
  if (off > ws_size) return;

  hipMemsetAsync(bar, 0, 256*32*4, stream);

  k_dense<<<256,256,0,stream>>>(z, 0, eh_W1, eh_b1, 1024, 256, 1, 0, t1, nullptr);
  k_dense<<<256,256,0,stream>>>(t1,1, eh_W2, eh_b2, 1024,1024, 1, 0, t2, nullptr);
  k_dense<<<256,256,0,stream>>>(t2,1, eh_W3, eh_b3, 1024,1024, 0, 1, nullptr, hS + 65536);
  k_dense<<<256,256,0,stream>>>(z, 0, ec_W1, ec_b1, 1024, 256, 1, 0, t1, nullptr);
  k_dense<<<256,256,0,stream>>>(t1,1, ec_W2, ec_b2, 1024,1024, 1, 0, t2, nullptr);
  k_dense<<<256,256,0,stream>>>(t2,1, ec_W3, ec_b3, 1024,1024, 0, 2, cF, nullptr);
  k_dense<<<256,256,0,stream>>>(z, 0, ex_W1, ex_b1, 1024, 256, 1, 0, t1, nullptr);
  k_dense<<<256,256,0,stream>>>(t1,1, ex_W2, ex_b2, 1024,1024, 1, 0, t2, nullptr);
  k_dense<<<16 ,256,0,stream>>>(t2,1, ex_W3, ex_b3,   64,1024, 0, 3, out, nullptr);
  k_zero0<<<64,256,0,stream>>>(out);

  k_pack_winh<<<16384,256,0,stream>>>(in_Whh, Win_h);
  k_pack_winx<<<4096,320,0,stream>>>(in_Wih, Win_x);
  for (int i = 0; i < 4; ++i)
    k_pack_ca<<<4096,256,0,stream>>>(cA_W + (size_t)i*1024*1024, Wcell + (size_t)i*64*81920);

  for (int i = 0; i < 4; ++i){
    k_tr<<<dim3(16,16),256,0,stream>>>(hA_W + (size_t)i*1024*1024, Tbuf, 1024, 1024);
    k_fuse<<<dim3(64,16,4),256,0,stream>>>(r_Whh + (size_t)i*4096*1024,
                                           r_Wih + (size_t)i*4096*1024,
                                           Tbuf, 1024, 0, Wcell + (size_t)i*64*81920);
  }
  k_tr<<<dim3(5,16),256,0,stream>>>(lastH_W, Tbuf, 320, 1024);
  k_fuse<<<dim3(20,16,4),256,0,stream>>>(out_Whh, out_Wih, Tbuf, 320, 1, Wout);
  k_tr<<<dim3(16,16),256,0,stream>>>(cA_W + (size_t)3*1024*1024, Tbuf, 1024, 1024);
  k_fuse<<<dim3(20,16,1),256,0,stream>>>(lastC_W, nullptr, Tbuf, 1024, 2, WccA);

  k_bias<<<1024,256,0,stream>>>(nullptr, nullptr, in_bih, in_bhh, b_in, 4096, 0);
  for (int i = 0; i < 4; ++i)
    k_bias<<<1024,256,0,stream>>>(r_Whh + (size_t)i*4096*1024, hA_b + i*1024,
                                  r_bih + i*4096, r_bhh + i*4096, b_cell + i*4096, 4096, 1024);
  k_bias<<<320,256,0,stream>>>(out_Whh, lastH_b, out_bih, out_bhh, b_out, 1280, 320);
  k_bias<<<80 ,256,0,stream>>>(lastC_W, cA_b + 3*1024, lastC_b, nullptr, b_cc, 320, 1024);

  k_scan<<<NWG,128,0,stream>>>(m_true, Wcell, Win_h, Win_x, Wout, WccA,
                               b_in, b_cell, cA_b, b_out, b_cc,
                               hS, cS, cF, ccB, out, bar);
}

// Round 7
// 12196.371 us; speedup vs baseline: 3.2374x; 1.2279x over previous
//
#include <hip/hip_runtime.h>

// BigARDecoder: persistent-kernel LSTM scan on MI355X.
// B=64, T=256, IN=256, H=1024, G=256, O=64, D=4, GO=320.
//
// R7: 4-wave (256-thread) WGs with K-split compute. Wave w = btile (w&1),
// K-half (w>>1); each wave stages ONE weight chunk, all 4 chunks issued
// inside gsync (160KB in flight/CU, arrival hidden under the barrier wait).
// Partial accumulators pair-reduced via LDS (2 syncthreads). Biases read
// directly from global (LDS = 100% weights: 4x40KB cell / 5x32KB incell).
// Distributed RELAXED barrier + agent fence + frag-layout state kept.

typedef unsigned int u32;
typedef unsigned long long u64;
typedef unsigned short u16;
typedef __attribute__((ext_vector_type(8))) __bf16 bf16x8;
typedef __attribute__((ext_vector_type(4))) float f32x4;

#define DEVI __device__ __forceinline__

union FRAG { bf16x8 v; u16 s[8]; u64 q[2]; };
union P4 { u64 q; u16 s[4]; };
union F4 { u64 q[2]; float f[4]; };

DEVI u16 f2bf(float x){ u32 u = __float_as_uint(x); return (u16)((u + 0x7fffu + ((u>>16)&1u)) >> 16); }
DEVI float sigm(float x){ return 1.0f/(1.0f + __expf(-x)); }
DEVI float tanh_(float x){ return 2.0f/(1.0f + __expf(-2.0f*x)) - 1.0f; }
DEVI void ast(void* p, u64 v){ __hip_atomic_store((u64*)p, v, __ATOMIC_RELAXED, __HIP_MEMORY_SCOPE_AGENT); }

#define MFMA16(a,b,c) __builtin_amdgcn_mfma_f32_16x16x32_bf16(a, b, c, 0, 0, 0)

#define NARR 168          // compute WGs (arrive lines)
#define NWG 169           // + master
#define NREP 21
#define NEPOCH 1276

#define SCHEDB() __builtin_amdgcn_sched_barrier(0)
#define WAITV(n) do{ SCHEDB(); \
  asm volatile("s_waitcnt vmcnt(" #n ")" ::: "memory"); \
  SCHEDB(); }while(0)

#if __has_builtin(__builtin_amdgcn_fence)
#define FENCE_ACQ() __builtin_amdgcn_fence(__ATOMIC_ACQUIRE, "agent")
#else
#define FENCE_ACQ() __hip_atomic_fence(__ATOMIC_ACQUIRE, __HIP_MEMORY_SCOPE_AGENT)
#endif

// ---------------------------------------------------------------------------
// Persistent scan kernel. 169 WGs x 256 threads. WG168 = barrier master.
// wg -> (pipe, lw): twins 8 apart (same XCD). lw 0..63: hidden tiles;
// lw 64..83: out-cell / ccA tiles.
// State frag layout (per buffer, 128KB): [btile(4)][ks(32)][bl(16)][kg(4)][8 bf16]
// LDS: 160KB = weight chunks only (4x40KB cell / 5x32KB incell / 4x32KB out).
// ---------------------------------------------------------------------------
__global__ __launch_bounds__(256, 1) void k_scan(
    const float* __restrict__ m_true,
    const u16* __restrict__ Wcell, const u16* __restrict__ Win_h,
    const u16* __restrict__ Win_x, const u16* __restrict__ Wout,
    const u16* __restrict__ WccA,
    const float* __restrict__ b_in, const float* __restrict__ b_cell,
    const float* __restrict__ cAb, const float* __restrict__ b_out,
    const float* __restrict__ b_cc,
    u16* hS, u16* cS, float* cF, float* ccB, float* outp, u32* bar)
{
  const int wg = blockIdx.x;
  const int tid = threadIdx.x;
  const int wave = tid >> 6, lane = tid & 63;

  // ---- master WG: flat-combining barrier server, all RELAXED ----
  if (wg == NARR){
    if (wave == 0){
      u32* arr = bar;
      u32* go  = bar + NARR*32;
      for (u32 ep = 1; ep <= NEPOCH; ++ep){
        for(;;){
          int ok = 1;
          if (lane < 56){
            u32 a0 = __hip_atomic_load(arr + lane*32,       __ATOMIC_RELAXED, __HIP_MEMORY_SCOPE_AGENT);
            u32 a1 = __hip_atomic_load(arr + (lane+56)*32,  __ATOMIC_RELAXED, __HIP_MEMORY_SCOPE_AGENT);
            u32 a2 = __hip_atomic_load(arr + (lane+112)*32, __ATOMIC_RELAXED, __HIP_MEMORY_SCOPE_AGENT);
            ok = (a0 >= ep) && (a1 >= ep) && (a2 >= ep);
          }
          if (__all(ok)) break;
          __builtin_amdgcn_s_sleep(1);
        }
        if (lane < NREP)
          __hip_atomic_store(go + lane*32, ep, __ATOMIC_RELAXED, __HIP_MEMORY_SCOPE_AGENT);
      }
    }
    return;
  }

  int pipe, lw;
  if (wg < 160){ pipe = (wg >> 3) & 1; lw = ((wg >> 4) << 3) | (wg & 7); }
  else         { pipe = (wg - 160) >> 2; lw = 80 + ((wg - 160) & 3); }

  const int bl = lane & 15, kg = lane >> 4;
  const int pair = wave >> 1;               // K-half this wave owns
  const int bt = (pipe << 1) + (wave & 1);  // btile this wave owns
  const int b  = (bt << 4) + bl;
  const int swz = (bl & 7) << 4;
  const int foff = ((bl << 2) + kg) << 4;
  const int woff = (bt << 15) + ((lw >> 1) << 10) + (bl << 6) + ((lw & 1) << 5) + (kg << 3);
  __shared__ __align__(16) u16 ldsW[81920];   // 160KB weight chunks

  // single-wave chunk stage: this wave copies `segs` KB linearly
  auto stage1 = [&](const u16* src, u16* lb, int segs){
    const u16* g = src + (lane << 3);
    u16* l = lb;
    for (int s = 0; s < segs; ++s){
      __builtin_amdgcn_global_load_lds(
          (const __attribute__((address_space(1))) void*)g,
          (__attribute__((address_space(3))) void*)l, 16, 0, 0);
      g += 512; l += 512;
    }
    SCHEDB();
  };
  auto afL = [&](const u16* lb, int row, int kb) -> bf16x8 {
    return *(const bf16x8*)((const char*)lb + row*512 + (kb ^ swz));
  };

  // distributed barrier; fence + WHOLE next-phase weight prefetch under wait
  auto gsync = [&](u32 ep, const u16* pfsrc, int cstride, int spw, const u16* xsrc){
    SCHEDB();
    __syncthreads();                  // drains vmcnt(0): state stores at MALL
    if (tid == 0)
      __hip_atomic_store(bar + wg*32, ep, __ATOMIC_RELAXED, __HIP_MEMORY_SCOPE_AGENT);
    if (wave == 0) FENCE_ACQ();
    SCHEDB();
    if (pfsrc) stage1(pfsrc + (size_t)wave*cstride, ldsW + wave*cstride, spw);
    if (xsrc)  stage1(xsrc + wave*4096, ldsW + 65536 + wave*4096, 8);
    SCHEDB();
    if (tid == 0){
      const u32* gp = bar + NARR*32 + (wg % NREP)*32;
      while (__hip_atomic_load(gp, __ATOMIC_RELAXED, __HIP_MEMORY_SCOPE_AGENT) < ep)
        __builtin_amdgcn_s_sleep(1);
      asm volatile("" ::: "memory");
    }
    __syncthreads();                  // drains prefetch; orders fence
    SCHEDB();
  };

  // ---- in-cell phase (lw<64). entry: ch0..3 = Win_h, ch4 = Win_x part1 ----
  auto phase_incell = [&](int t, const u16* hIn, u16* hOut, u16* cOut){
    f32x4 A0={0,0,0,0}, A1={0,0,0,0}, A2={0,0,0,0}, A3={0,0,0,0};
    const char* hf = (const char*)hIn + (bt << 15) + foff;
    const int ksb = pair << 4;
    int jl = (kg << 2), jj = (lw << 4) + jl;
    FRAG sh[2][8], xf[10], pa[8];
    f32x4 bg0, bg1, bg2, bg3, cpv;
    // issue order: state L1(8), L2(8), then per-wave extras
    #pragma unroll
    for (int ks = 0; ks < 8; ++ks) sh[0][ks].v = *(const bf16x8*)(hf + (ksb + ks)*1024);
    #pragma unroll
    for (int ks = 0; ks < 8; ++ks) sh[1][ks].v = *(const bf16x8*)(hf + (ksb + 8 + ks)*1024);
    SCHEDB();
    if (wave < 2){
      bg0 = *(const f32x4*)(b_in +        jj);
      bg1 = *(const f32x4*)(b_in + 1024 + jj);
      bg2 = *(const f32x4*)(b_in + 2048 + jj);
      bg3 = *(const f32x4*)(b_in + 3072 + jj);
      cpv = *(const f32x4*)((const char*)cF + ((size_t)b << 12) + (jj << 2));
    } else {
      const float* xr = m_true + (size_t)b*81920 + (size_t)(255 - t)*320;
      #pragma unroll
      for (int ks = 0; ks < 10; ++ks){
        int k = (ks << 5) + (kg << 3);
        f32x4 x0 = *(const f32x4*)(xr + k);
        f32x4 x1 = *(const f32x4*)(xr + k + 4);
        xf[ks].s[0]=f2bf(x0[0]); xf[ks].s[1]=f2bf(x0[1]); xf[ks].s[2]=f2bf(x0[2]); xf[ks].s[3]=f2bf(x0[3]);
        xf[ks].s[4]=f2bf(x1[0]); xf[ks].s[5]=f2bf(x1[1]); xf[ks].s[6]=f2bf(x1[2]); xf[ks].s[7]=f2bf(x1[3]);
      }
      const char* p2 = (const char*)(Win_x + (size_t)lw*20480 + 16384);
      #pragma unroll
      for (int k2 = 0; k2 < 2; ++k2)
        #pragma unroll
        for (int rb = 0; rb < 4; ++rb)
          pa[k2*4+rb].v = *(const bf16x8*)(p2 + (rb*16 + bl)*128 + (((k2<<6)+(kg<<4)) ^ swz));
    }
    SCHEDB();
    WAITV(8);
    const u16* lbA = ldsW + (pair*2)*16384;
    #pragma unroll
    for (int ks = 0; ks < 8; ++ks){
      int kb = (ks << 6) + (kg << 4);
      FRAG a;
      a.v = afL(lbA, bl, kb);      A0 = MFMA16(a.v, sh[0][ks].v, A0);
      a.v = afL(lbA, 16 + bl, kb); A1 = MFMA16(a.v, sh[0][ks].v, A1);
      a.v = afL(lbA, 32 + bl, kb); A2 = MFMA16(a.v, sh[0][ks].v, A2);
      a.v = afL(lbA, 48 + bl, kb); A3 = MFMA16(a.v, sh[0][ks].v, A3);
    }
    WAITV(0);
    const u16* lbB = ldsW + (pair*2+1)*16384;
    #pragma unroll
    for (int ks = 0; ks < 8; ++ks){
      int kb = (ks << 6) + (kg << 4);
      FRAG a;
      a.v = afL(lbB, bl, kb);      A0 = MFMA16(a.v, sh[1][ks].v, A0);
      a.v = afL(lbB, 16 + bl, kb); A1 = MFMA16(a.v, sh[1][ks].v, A1);
      a.v = afL(lbB, 32 + bl, kb); A2 = MFMA16(a.v, sh[1][ks].v, A2);
      a.v = afL(lbB, 48 + bl, kb); A3 = MFMA16(a.v, sh[1][ks].v, A3);
    }
    if (wave >= 2){                         // x contribution (pair B only)
      const u16* lb4 = ldsW + 65536;
      #pragma unroll
      for (int ks = 0; ks < 8; ++ks){
        int kb = (ks << 6) + (kg << 4);
        FRAG a;
        a.v = afL(lb4, bl, kb);      A0 = MFMA16(a.v, xf[ks].v, A0);
        a.v = afL(lb4, 16 + bl, kb); A1 = MFMA16(a.v, xf[ks].v, A1);
        a.v = afL(lb4, 32 + bl, kb); A2 = MFMA16(a.v, xf[ks].v, A2);
        a.v = afL(lb4, 48 + bl, kb); A3 = MFMA16(a.v, xf[ks].v, A3);
      }
      #pragma unroll
      for (int k2 = 0; k2 < 2; ++k2){
        A0 = MFMA16(pa[k2*4+0].v, xf[8+k2].v, A0);
        A1 = MFMA16(pa[k2*4+1].v, xf[8+k2].v, A1);
        A2 = MFMA16(pa[k2*4+2].v, xf[8+k2].v, A2);
        A3 = MFMA16(pa[k2*4+3].v, xf[8+k2].v, A3);
      }
    }
    __syncthreads();
    float* red = (float*)ldsW;
    if (wave >= 2){
      float* r = red + ((wave&1)*64 + lane)*20;
      *(f32x4*)(r+0) = A0; *(f32x4*)(r+4) = A1;
      *(f32x4*)(r+8) = A2; *(f32x4*)(r+12) = A3;
    }
    __syncthreads();
    if (wave < 2){
      const float* r = red + ((wave&1)*64 + lane)*20;
      A0 += *(const f32x4*)(r+0); A1 += *(const f32x4*)(r+4);
      A2 += *(const f32x4*)(r+8); A3 += *(const f32x4*)(r+12);
      P4 hw, cw;
      #pragma unroll
      for (int rr = 0; rr < 4; ++rr){
        float gi = A0[rr] + bg0[rr];
        float gf = A1[rr] + bg1[rr];
        float gg = A2[rr] + bg2[rr];
        float go = A3[rr] + bg3[rr];
        float cn = sigm(gf)*cpv[rr] + sigm(gi)*tanh_(gg);
        hw.s[rr] = f2bf(sigm(go)*tanh_(cn));
        cw.s[rr] = f2bf(cn);
      }
      ast((char*)hOut + woff, hw.q);
      ast((char*)cOut + woff, cw.q);
    }
  };

  // ---- inner cell phase i (lw<64). entry: ch0..3 = Wcell_i ----
  auto phase_cell = [&](int i, const u16* hIn, const u16* cIn, u16* hOut, u16* cOut, bool last){
    f32x4 A0={0,0,0,0}, A1={0,0,0,0}, A2={0,0,0,0}, A3={0,0,0,0}, A4={0,0,0,0};
    const char* hf  = (const char*)hIn + (bt << 15) + foff;
    const char* cfr = (const char*)cIn + (bt << 15) + foff;
    const int ksb = pair << 4;
    int jl = (kg << 2), jj = (lw << 4) + jl;
    FRAG sh[2][8], sc[2][8];
    f32x4 bg0, bg1, bg2, bg3, bca;
    #pragma unroll
    for (int ks = 0; ks < 8; ++ks){
      sh[0][ks].v = *(const bf16x8*)(hf  + (ksb + ks)*1024);
      sc[0][ks].v = *(const bf16x8*)(cfr + (ksb + ks)*1024);
    }
    #pragma unroll
    for (int ks = 0; ks < 8; ++ks){
      sh[1][ks].v = *(const bf16x8*)(hf  + (ksb + 8 + ks)*1024);
      sc[1][ks].v = *(const bf16x8*)(cfr + (ksb + 8 + ks)*1024);
    }
    SCHEDB();
    if (wave < 2){
      bg0 = *(const f32x4*)(b_cell + i*4096 +        jj);
      bg1 = *(const f32x4*)(b_cell + i*4096 + 1024 + jj);
      bg2 = *(const f32x4*)(b_cell + i*4096 + 2048 + jj);
      bg3 = *(const f32x4*)(b_cell + i*4096 + 3072 + jj);
      bca = *(const f32x4*)(cAb + i*1024 + jj);
    }
    SCHEDB();
    WAITV(16);
    const u16* lbA = ldsW + (pair*2)*20480;
    #pragma unroll
    for (int ks = 0; ks < 8; ++ks){
      int kb = (ks << 6) + (kg << 4);
      FRAG a;
      a.v = afL(lbA, bl, kb);      A0 = MFMA16(a.v, sh[0][ks].v, A0);
      a.v = afL(lbA, 16 + bl, kb); A1 = MFMA16(a.v, sh[0][ks].v, A1);
      a.v = afL(lbA, 32 + bl, kb); A2 = MFMA16(a.v, sh[0][ks].v, A2);
      a.v = afL(lbA, 48 + bl, kb); A3 = MFMA16(a.v, sh[0][ks].v, A3);
      a.v = afL(lbA, 64 + bl, kb); A4 = MFMA16(a.v, sc[0][ks].v, A4);
    }
    WAITV(0);
    const u16* lbB = ldsW + (pair*2+1)*20480;
    #pragma unroll
    for (int ks = 0; ks < 8; ++ks){
      int kb = (ks << 6) + (kg << 4);
      FRAG a;
      a.v = afL(lbB, bl, kb);      A0 = MFMA16(a.v, sh[1][ks].v, A0);
      a.v = afL(lbB, 16 + bl, kb); A1 = MFMA16(a.v, sh[1][ks].v, A1);
      a.v = afL(lbB, 32 + bl, kb); A2 = MFMA16(a.v, sh[1][ks].v, A2);
      a.v = afL(lbB, 48 + bl, kb); A3 = MFMA16(a.v, sh[1][ks].v, A3);
      a.v = afL(lbB, 64 + bl, kb); A4 = MFMA16(a.v, sc[1][ks].v, A4);
    }
    __syncthreads();
    float* red = (float*)ldsW;
    if (wave >= 2){
      float* r = red + ((wave&1)*64 + lane)*20;
      *(f32x4*)(r+0) = A0; *(f32x4*)(r+4) = A1;
      *(f32x4*)(r+8) = A2; *(f32x4*)(r+12) = A3; *(f32x4*)(r+16) = A4;
    }
    __syncthreads();
    if (wave < 2){
      const float* r = red + ((wave&1)*64 + lane)*20;
      A0 += *(const f32x4*)(r+0); A1 += *(const f32x4*)(r+4);
      A2 += *(const f32x4*)(r+8); A3 += *(const f32x4*)(r+12);
      A4 += *(const f32x4*)(r+16);
      P4 hw, cw; F4 cf4;
      #pragma unroll
      for (int rr = 0; rr < 4; ++rr){
        float gi = A0[rr] + bg0[rr];
        float gf = A1[rr] + bg1[rr];
        float gg = A2[rr] + bg2[rr];
        float go = A3[rr] + bg3[rr];
        float c1 = A4[rr] + bca[rr];
        float cn = sigm(gf)*c1 + sigm(gi)*tanh_(gg);
        hw.s[rr] = f2bf(sigm(go)*tanh_(cn));
        cw.s[rr] = f2bf(cn);
        cf4.f[rr] = cn;
      }
      ast((char*)hOut + woff, hw.q);
      ast((char*)cOut + woff, cw.q);
      if (last){
        char* cfp = (char*)cF + ((size_t)b << 12) + (jj << 2);
        ast(cfp, cf4.q[0]); ast(cfp + 8, cf4.q[1]);
      }
    }
  };

  // ---- ccA phase (lw 64..83, with cell i==3). entry: ch0..3 = WccA ----
  auto phase_ccA = [&](const u16* cIn){
    f32x4 A = {0,0,0,0};
    int w2 = lw - 64;
    const char* cfr = (const char*)cIn + (bt << 15) + foff;
    const int ksb = pair << 4;
    int jl = (kg << 2), jjo = (w2 << 4) + jl;
    FRAG sc[2][8];
    f32x4 bcc;
    #pragma unroll
    for (int ks = 0; ks < 8; ++ks) sc[0][ks].v = *(const bf16x8*)(cfr + (ksb + ks)*1024);
    #pragma unroll
    for (int ks = 0; ks < 8; ++ks) sc[1][ks].v = *(const bf16x8*)(cfr + (ksb + 8 + ks)*1024);
    SCHEDB();
    if (wave < 2) bcc = *(const f32x4*)(b_cc + jjo);
    SCHEDB();
    WAITV(8);
    const u16* lbA = ldsW + (pair*2)*4096;
    #pragma unroll
    for (int ks = 0; ks < 8; ++ks){
      int kb = (ks << 6) + (kg << 4);
      FRAG a; a.v = afL(lbA, bl, kb);
      A = MFMA16(a.v, sc[0][ks].v, A);
    }
    WAITV(0);
    const u16* lbB = ldsW + (pair*2+1)*4096;
    #pragma unroll
    for (int ks = 0; ks < 8; ++ks){
      int kb = (ks << 6) + (kg << 4);
      FRAG a; a.v = afL(lbB, bl, kb);
      A = MFMA16(a.v, sc[1][ks].v, A);
    }
    __syncthreads();
    float* red = (float*)ldsW;
    if (wave >= 2) *(f32x4*)(red + ((wave&1)*64 + lane)*20) = A;
    __syncthreads();
    if (wave < 2){
      A += *(const f32x4*)(red + ((wave&1)*64 + lane)*20);
      F4 v;
      #pragma unroll
      for (int rr = 0; rr < 4; ++rr) v.f[rr] = A[rr] + bcc[rr];
      char* cp2 = (char*)ccB + ((size_t)b*320 + jjo)*4;
      ast(cp2, v.q[0]); ast(cp2 + 8, v.q[1]);
    }
  };

  // ---- out-cell phase (lw 64..83). entry: ch0..3 = Wout ----
  auto phase_out = [&](int t, const u16* hIn){
    f32x4 A0={0,0,0,0}, A1={0,0,0,0}, A2={0,0,0,0}, A3={0,0,0,0};
    int w2 = lw - 64;
    const char* hf = (const char*)hIn + (bt << 15) + foff;
    const int ksb = pair << 4;
    int jl = (kg << 2), jjo = (w2 << 4) + jl;
    FRAG sh[2][8];
    f32x4 bg0, bg1, bg2, bg3, ccv;
    #pragma unroll
    for (int ks = 0; ks < 8; ++ks) sh[0][ks].v = *(const bf16x8*)(hf + (ksb + ks)*1024);
    #pragma unroll
    for (int ks = 0; ks < 8; ++ks) sh[1][ks].v = *(const bf16x8*)(hf + (ksb + 8 + ks)*1024);
    SCHEDB();
    if (wave < 2){
      bg0 = *(const f32x4*)(b_out +       jjo);
      bg1 = *(const f32x4*)(b_out + 320 + jjo);
      bg2 = *(const f32x4*)(b_out + 640 + jjo);
      bg3 = *(const f32x4*)(b_out + 960 + jjo);
      ccv = *(const f32x4*)((const char*)ccB + ((size_t)b*320 + jjo)*4);
    }
    SCHEDB();
    WAITV(8);
    const u16* lbA = ldsW + (pair*2)*16384;
    #pragma unroll
    for (int ks = 0; ks < 8; ++ks){
      int kb = (ks << 6) + (kg << 4);
      FRAG a;
      a.v = afL(lbA, bl, kb);      A0 = MFMA16(a.v, sh[0][ks].v, A0);
      a.v = afL(lbA, 16 + bl, kb); A1 = MFMA16(a.v, sh[0][ks].v, A1);
      a.v = afL(lbA, 32 + bl, kb); A2 = MFMA16(a.v, sh[0][ks].v, A2);
      a.v = afL(lbA, 48 + bl, kb); A3 = MFMA16(a.v, sh[0][ks].v, A3);
    }
    WAITV(0);
    const u16* lbB = ldsW + (pair*2+1)*16384;
    #pragma unroll
    for (int ks = 0; ks < 8; ++ks){
      int kb = (ks << 6) + (kg << 4);
      FRAG a;
      a.v = afL(lbB, bl, kb);      A0 = MFMA16(a.v, sh[1][ks].v, A0);
      a.v = afL(lbB, 16 + bl, kb); A1 = MFMA16(a.v, sh[1][ks].v, A1);
      a.v = afL(lbB, 32 + bl, kb); A2 = MFMA16(a.v, sh[1][ks].v, A2);
      a.v = afL(lbB, 48 + bl, kb); A3 = MFMA16(a.v, sh[1][ks].v, A3);
    }
    __syncthreads();
    float* red = (float*)ldsW;
    if (wave >= 2){
      float* r = red + ((wave&1)*64 + lane)*20;
      *(f32x4*)(r+0) = A0; *(f32x4*)(r+4) = A1;
      *(f32x4*)(r+8) = A2; *(f32x4*)(r+12) = A3;
    }
    __syncthreads();
    if (wave < 2){
      const float* r = red + ((wave&1)*64 + lane)*20;
      A0 += *(const f32x4*)(r+0); A1 += *(const f32x4*)(r+4);
      A2 += *(const f32x4*)(r+8); A3 += *(const f32x4*)(r+12);
      f32x4 ho;
      #pragma unroll
      for (int rr = 0; rr < 4; ++rr){
        float gi = A0[rr] + bg0[rr];
        float gf = A1[rr] + bg1[rr];
        float gg = A2[rr] + bg2[rr];
        float go = A3[rr] + bg3[rr];
        float cn = sigm(gf)*ccv[rr] + sigm(gi)*tanh_(gg);
        ho[rr] = sigm(go)*tanh_(cn);
      }
      *(f32x4*)(outp + (size_t)b*81920 + (size_t)(t+1)*320 + jjo) = ho;
    }
  };

  // ---- init: first incell weights (ch_w + x quarter per wave) ----
  if (lw < 64){
    stage1(Win_h + ((size_t)lw << 16) + wave*16384, ldsW + wave*16384, 32);
    stage1(Win_x + (size_t)lw*20480 + wave*4096, ldsW + 65536 + wave*4096, 8);
  }
  __syncthreads();
  SCHEDB();

  u16* hB0 = hS;        u16* hB1 = hS + 65536;
  u16* cB0 = cS;        u16* cB1 = cS + 65536;

  u32 ep = 1;
  if (lw < 64) phase_incell(0, hB1, hB0, cB0);
  gsync(ep++, (lw < 64) ? Wcell + (size_t)lw*81920 : nullptr, 20480, 40, nullptr);
  int p = 1;
  #pragma unroll 1
  for (int t = 0; t < 255; ++t){
    #pragma unroll 1
    for (int i = 0; i < 4; ++i){
      u16* hIn = (p & 1) ? hB0 : hB1;  u16* cIn = (p & 1) ? cB0 : cB1;
      u16* hOut = (p & 1) ? hB1 : hB0; u16* cOut = (p & 1) ? cB1 : cB0;
      if (lw < 64)      phase_cell(i, hIn, cIn, hOut, cOut, i == 3);
      else if (i == 3)  phase_ccA(cIn);
      const u16* pf = nullptr; const u16* xs = nullptr; int cstride = 0, spw = 0;
      if (lw < 64){
        if (i < 3){ pf = Wcell + (size_t)((i+1)*64 + lw)*81920; cstride = 20480; spw = 40; }
        else      { pf = Win_h + ((size_t)lw << 16); cstride = 16384; spw = 32;
                    xs = Win_x + (size_t)lw*20480; }
      } else {
        if (i == 2){ pf = WccA + ((size_t)(lw-64) << 14); cstride = 4096; spw = 8; }
        else if (i == 3){ pf = Wout + ((size_t)(lw-64) << 16); cstride = 16384; spw = 32; }
      }
      gsync(ep++, pf, cstride, spw, xs);
      ++p;
    }
    u16* hIn = (p & 1) ? hB0 : hB1;
    u16* hOut = (p & 1) ? hB1 : hB0; u16* cOut = (p & 1) ? cB1 : cB0;
    if (lw >= 64)       phase_out(t, hIn);
    else if (t < 254)   phase_incell(t + 1, hIn, hOut, cOut);
    gsync(ep++, (lw < 64 && t < 254) ? Wcell + (size_t)lw*81920 : nullptr, 20480, 40, nullptr);
    ++p;
  }
}

// ---------------------------------------------------------------------------
// Precompute kernels (unchanged)
// ---------------------------------------------------------------------------

__global__ __launch_bounds__(256) void k_dense(const float* __restrict__ X, int xmode,
    const float* __restrict__ W, const float* __restrict__ bias,
    int OD, int ID, int act, int omode, float* outF, u16* outB)
{
  int o = blockIdx.x*4 + (threadIdx.x >> 6);
  if (o >= OD) return;
  int lane = threadIdx.x & 63;
  const float* wr = W + (size_t)o*ID;
  float acc = 0.f;
  if (xmode == 0){ for (int k = 0; k < ID; ++k) acc = fmaf(wr[k], X[(size_t)lane*ID + k], acc); }
  else           { for (int k = 0; k < ID; ++k) acc = fmaf(wr[k], X[(size_t)k*64 + lane], acc); }
  acc += bias[o];
  if (act) acc = acc * sigm(acc);
  if (omode == 0)      outF[(size_t)o*64 + lane] = acc;
  else if (omode == 1){
    int bt = lane >> 4, blx = lane & 15;
    outB[(size_t)bt*16384 + (size_t)(o>>5)*512 + blx*32 + ((o&31)>>3)*8 + (o&7)] = f2bf(acc);
  }
  else if (omode == 2) outF[(size_t)lane*1024 + o] = acc;
  else                 outF[(size_t)lane*81920 + 256 + o] = acc;
}

__global__ void k_zero0(float* out){ out[(size_t)blockIdx.x*81920 + threadIdx.x] = 0.f; }

__global__ __launch_bounds__(256) void k_tr(const float* __restrict__ in, u16* __restrict__ out, int M, int N){
  __shared__ u16 t[64][65];
  int m0 = blockIdx.x << 6, n0 = blockIdx.y << 6;
  int c = threadIdx.x & 63, rq = threadIdx.x >> 6;
  for (int rr = 0; rr < 16; ++rr){
    int r = (rq << 4) + rr;
    t[r][c] = f2bf(in[(size_t)(m0 + r)*N + n0 + c]);
  }
  __syncthreads();
  for (int rr = 0; rr < 16; ++rr){
    int r = (rq << 4) + rr;
    out[(size_t)(n0 + r)*M + m0 + c] = t[c][r];
  }
}

__global__ __launch_bounds__(256) void k_fuse(const float* __restrict__ Whh, const float* __restrict__ Wih,
    const u16* __restrict__ BT, int KM, int mode, u16* __restrict__ dst)
{
  int bx = blockIdx.x, by = blockIdx.y, bz = blockIdx.z;
  int lane = threadIdx.x & 63, wv = threadIdx.x >> 6;
  int bl = lane & 15, kg = lane >> 4;
  int jbase = (mode == 0) ? bz*1024 : ((mode == 1) ? bz*320 : 0);
  int jrow = jbase + bx*16 + bl;
  int k2c = by*64 + wv*16 + bl;
  f32x4 acc = {0,0,0,0};
  for (int m0 = 0; m0 < KM; m0 += 32){
    f32x4 wa0 = *(const f32x4*)(Whh + (size_t)jrow*KM + m0 + (kg << 3));
    f32x4 wa1 = *(const f32x4*)(Whh + (size_t)jrow*KM + m0 + (kg << 3) + 4);
    FRAG a;
    a.s[0]=f2bf(wa0[0]); a.s[1]=f2bf(wa0[1]); a.s[2]=f2bf(wa0[2]); a.s[3]=f2bf(wa0[3]);
    a.s[4]=f2bf(wa1[0]); a.s[5]=f2bf(wa1[1]); a.s[6]=f2bf(wa1[2]); a.s[7]=f2bf(wa1[3]);
    FRAG bb; bb.v = *(const bf16x8*)(BT + (size_t)k2c*KM + m0 + (kg << 3));
    acc = MFMA16(a.v, bb.v, acc);
  }
  #pragma unroll
  for (int r = 0; r < 4; ++r){
    int jl = (kg << 2) + r;
    int jg = jbase + bx*16 + jl;
    float v = acc[r];
    if (mode < 2) v += Wih[(size_t)jg*1024 + k2c];
    int re = (mode == 2) ? jl : (bz*16 + jl);
    int c = k2c >> 8, kl = k2c & 255;
    size_t pos;
    if (mode == 0)      pos = (size_t)bx*81920 + c*20480 + re*256 + (kl ^ ((re&7)<<3));
    else if (mode == 1) pos = (size_t)bx*65536 + c*16384 + re*256 + (kl ^ ((re&7)<<3));
    else                pos = (size_t)bx*16384 + c*4096  + re*256 + (kl ^ ((re&7)<<3));
    dst[pos] = f2bf(v);
  }
}

__global__ void k_pack_winh(const float* __restrict__ src, u16* __restrict__ dst){
  int id = blockIdx.x*256 + threadIdx.x;
  int j = id >> 10, k = id & 1023;
  int g = j >> 10, jj = j & 1023;
  int w = jj >> 4, r = (g << 4) + (jj & 15);
  int c = k >> 8, kl = k & 255;
  dst[(size_t)w*65536 + c*16384 + r*256 + (kl ^ ((r&7)<<3))] = f2bf(src[id]);
}

__global__ void k_pack_winx(const float* __restrict__ src, u16* __restrict__ dst){
  int j = blockIdx.x, k = threadIdx.x;
  int g = j >> 10, jj = j & 1023;
  int w = jj >> 4, r = (g << 4) + (jj & 15);
  float v = src[(size_t)j*320 + k];
  size_t pos;
  if (k < 256) pos = (size_t)w*20480 + r*256 + (k ^ ((r&7)<<3));
  else         pos = (size_t)w*20480 + 16384 + r*64 + ((k - 256) ^ ((r&7)<<3));
  dst[pos] = f2bf(v);
}

__global__ void k_pack_ca(const float* __restrict__ src, u16* __restrict__ dst){
  int id = blockIdx.x*256 + threadIdx.x;
  int jj = id >> 10, k = id & 1023;
  int w = jj >> 4, r = 64 + (jj & 15);
  int c = k >> 8, kl = k & 255;
  dst[(size_t)w*81920 + c*20480 + r*256 + (kl ^ ((r&7)<<3))] = f2bf(src[id]);
}

__global__ __launch_bounds__(256) void k_bias(const float* __restrict__ A, const float* __restrict__ x,
    const float* __restrict__ a1, const float* __restrict__ a2, float* __restrict__ o, int NJ, int K)
{
  int j = blockIdx.x*4 + (threadIdx.x >> 6);
  if (j >= NJ) return;
  int lane = threadIdx.x & 63;
  float acc = 0.f;
  if (A) for (int k = lane; k < K; k += 64) acc += A[(size_t)j*K + k]*x[k];
  for (int off = 32; off; off >>= 1) acc += __shfl_down(acc, off);
  if (lane == 0) o[j] = acc + (a1 ? a1[j] : 0.f) + (a2 ? a2[j] : 0.f);
}

// ---------------------------------------------------------------------------
extern "C" void kernel_launch(void* const* d_in, const int* in_sizes, int n_in,
                              void* d_out, int out_size, void* d_ws, size_t ws_size,
                              hipStream_t stream)
{
  (void)in_sizes; (void)n_in; (void)out_size;
  const float* z      = (const float*)d_in[0];
  const float* m_true = (const float*)d_in[1];
  const float* eh_W1=(const float*)d_in[2],  *eh_b1=(const float*)d_in[3];
  const float* eh_W2=(const float*)d_in[4],  *eh_b2=(const float*)d_in[5];
  const float* eh_W3=(const float*)d_in[6],  *eh_b3=(const float*)d_in[7];
  const float* ec_W1=(const float*)d_in[8],  *ec_b1=(const float*)d_in[9];
  const float* ec_W2=(const float*)d_in[10], *ec_b2=(const float*)d_in[11];
  const float* ec_W3=(const float*)d_in[12], *ec_b3=(const float*)d_in[13];
  const float* ex_W1=(const float*)d_in[14], *ex_b1=(const float*)d_in[15];
  const float* ex_W2=(const float*)d_in[16], *ex_b2=(const float*)d_in[17];
  const float* ex_W3=(const float*)d_in[18], *ex_b3=(const float*)d_in[19];
  const float* in_Wih=(const float*)d_in[20], *in_Whh=(const float*)d_in[21];
  const float* in_bih=(const float*)d_in[22], *in_bhh=(const float*)d_in[23];
  const float* r_Wih=(const float*)d_in[24],  *r_Whh=(const float*)d_in[25];
  const float* r_bih=(const float*)d_in[26],  *r_bhh=(const float*)d_in[27];
  const float* hA_W=(const float*)d_in[28],   *hA_b=(const float*)d_in[29];
  const float* cA_W=(const float*)d_in[30],   *cA_b=(const float*)d_in[31];
  const float* lastH_W=(const float*)d_in[32], *lastH_b=(const float*)d_in[33];
  const float* lastC_W=(const float*)d_in[34], *lastC_b=(const float*)d_in[35];
  const float* out_Wih=(const float*)d_in[36], *out_Whh=(const float*)d_in[37];
  const float* out_bih=(const float*)d_in[38], *out_bhh=(const float*)d_in[39];
  float* out = (float*)d_out;

  char* wsb = (char*)d_ws;
  size_t off = 0;
  auto alloc = [&](size_t bytes)->char*{
    char* p = wsb + off; off = (off + bytes + 255) & ~(size_t)255; return p;
  };
  u32* bar    = (u32*)alloc(256*32*4);
  u16* hS     = (u16*)alloc(2*64*1024*2);
  u16* cS     = (u16*)alloc(2*64*1024*2);
  float* cF   = (float*)alloc(64*1024*4);
  float* ccB  = (float*)alloc(64*320*4);
  float* b_in = (float*)alloc(4096*4);
  float* b_cell=(float*)alloc(4*4096*4);
  float* b_out= (float*)alloc(1280*4);
  float* b_cc = (float*)alloc(320*4);
  float* t1   = (float*)alloc(1024*64*4);
  float* t2   = (float*)alloc(1024*64*4);
  u16* Tbuf   = (u16*)alloc((size_t)1024*1024*2);
  u16* Win_h  = (u16*)alloc((size_t)64*65536*2);
  u16* Win_x  = (u16*)alloc((size_t)64*20480*2);
  u16* Wcell  = (u16*)alloc((size_t)4*64*81920*2);
  u16* Wout   = (u16*)alloc((size_t)20*65536*2);
  u16* WccA   = (u16*)alloc((size_t)20*16384*2);
  if (off > ws_size) return;

  hipMemsetAsync(bar, 0, 256*32*4, stream);

  k_dense<<<256,256,0,stream>>>(z, 0, eh_W1, eh_b1, 1024, 256, 1, 0, t1, nullptr);
  k_dense<<<256,256,0,stream>>>(t1,1, eh_W2, eh_b2, 1024,1024, 1, 0, t2, nullptr);
  k_dense<<<256,256,0,stream>>>(t2,1, eh_W3, eh_b3, 1024,1024, 0, 1, nullptr, hS + 65536);
  k_dense<<<256,256,0,stream>>>(z, 0, ec_W1, ec_b1, 1024, 256, 1, 0, t1, nullptr);
  k_dense<<<256,256,0,stream>>>(t1,1, ec_W2, ec_b2, 1024,1024, 1, 0, t2, nullptr);
  k_dense<<<256,256,0,stream>>>(t2,1, ec_W3, ec_b3, 1024,1024, 0, 2, cF, nullptr);
  k_dense<<<256,256,0,stream>>>(z, 0, ex_W1, ex_b1, 1024, 256, 1, 0, t1, nullptr);
  k_dense<<<256,256,0,stream>>>(t1,1, ex_W2, ex_b2, 1024,1024, 1, 0, t2, nullptr);
  k_dense<<<16 ,256,0,stream>>>(t2,1, ex_W3, ex_b3,   64,1024, 0, 3, out, nullptr);
  k_zero0<<<64,256,0,stream>>>(out);

  k_pack_winh<<<16384,256,0,stream>>>(in_Whh, Win_h);
  k_pack_winx<<<4096,320,0,stream>>>(in_Wih, Win_x);
  for (int i = 0; i < 4; ++i)
    k_pack_ca<<<4096,256,0,stream>>>(cA_W + (size_t)i*1024*1024, Wcell + (size_t)i*64*81920);

  for (int i = 0; i < 4; ++i){
    k_tr<<<dim3(16,16),256,0,stream>>>(hA_W + (size_t)i*1024*1024, Tbuf, 1024, 1024);
    k_fuse<<<dim3(64,16,4),256,0,stream>>>(r_Whh + (size_t)i*4096*1024,
                                           r_Wih + (size_t)i*4096*1024,
                                           Tbuf, 1024, 0, Wcell + (size_t)i*64*81920);
  }
  k_tr<<<dim3(5,16),256,0,stream>>>(lastH_W, Tbuf, 320, 1024);
  k_fuse<<<dim3(20,16,4),256,0,stream>>>(out_Whh, out_Wih, Tbuf, 320, 1, Wout);
  k_tr<<<dim3(16,16),256,0,stream>>>(cA_W + (size_t)3*1024*1024, Tbuf, 1024, 1024);
  k_fuse<<<dim3(20,16,1),256,0,stream>>>(lastC_W, nullptr, Tbuf, 1024, 2, WccA);

  k_bias<<<1024,256,0,stream>>>(nullptr, nullptr, in_bih, in_bhh, b_in, 4096, 0);
  for (int i = 0; i < 4; ++i)
    k_bias<<<1024,256,0,stream>>>(r_Whh + (size_t)i*4096*1024, hA_b + i*1024,
                                  r_bih + i*4096, r_bhh + i*4096, b_cell + i*4096, 4096, 1024);
  k_bias<<<320,256,0,stream>>>(out_Whh, lastH_b, out_bih, out_bhh, b_out, 1280, 320);
  k_bias<<<80 ,256,0,stream>>>(lastC_W, cA_b + 3*1024, lastC_b, nullptr, b_cc, 320, 1024);

  k_scan<<<NWG,256,0,stream>>>(m_true, Wcell, Win_h, Win_x, Wout, WccA,
                               b_in, b_cell, cA_b, b_out, b_cc,
                               hS, cS, cF, ccB, out, bar);
}

// Round 8
// 11807.649 us; speedup vs baseline: 3.3440x; 1.0329x over previous
//
#include <hip/hip_runtime.h>

// BigARDecoder: persistent-kernel LSTM scan on MI355X.
// B=64, T=256, IN=256, H=1024, G=256, O=64, D=4, GO=320.
//
// R8: masterless barrier (direct 84-flag poll per pipeline), no agent fence
// (state via sc0/sc1 L2-bypass asm loads, manually counted vmcnt), cF/cc
// carried in registers (same-lane producer/consumer). R7's 4-wave K-split +
// whole-phase weight staging in the barrier window kept. Grid = 168 WGs.

typedef unsigned int u32;
typedef unsigned long long u64;
typedef unsigned short u16;
typedef __attribute__((ext_vector_type(8))) __bf16 bf16x8;
typedef __attribute__((ext_vector_type(4))) float f32x4;

#define DEVI __device__ __forceinline__

union FRAG { bf16x8 v; u16 s[8]; u64 q[2]; };
union P4 { u64 q; u16 s[4]; };
union F4 { u64 q[2]; float f[4]; };

DEVI u16 f2bf(float x){ u32 u = __float_as_uint(x); return (u16)((u + 0x7fffu + ((u>>16)&1u)) >> 16); }
DEVI float sigm(float x){ return 1.0f/(1.0f + __expf(-x)); }
DEVI float tanh_(float x){ return 2.0f/(1.0f + __expf(-2.0f*x)) - 1.0f; }
DEVI void ast(void* p, u64 v){ __hip_atomic_store((u64*)p, v, __ATOMIC_RELAXED, __HIP_MEMORY_SCOPE_AGENT); }

// counted asm loads (issue order == program order of volatiles == vmcnt FIFO)
DEVI void ld16sc(FRAG& d, const void* p){
  asm volatile("global_load_dwordx4 %0, %1, off sc0 sc1" : "=v"(d.v) : "v"(p));
}
DEVI void ld16(FRAG& d, const void* p){
  asm volatile("global_load_dwordx4 %0, %1, off" : "=v"(d.v) : "v"(p));
}
DEVI void ldf4(f32x4& d, const void* p){
  asm volatile("global_load_dwordx4 %0, %1, off" : "=v"(d) : "v"(p));
}

#define MFMA16(a,b,c) __builtin_amdgcn_mfma_f32_16x16x32_bf16(a, b, c, 0, 0, 0)

#define NWG 168

#define SCHEDB() __builtin_amdgcn_sched_barrier(0)
#define WAITV(n) do{ SCHEDB(); \
  asm volatile("s_waitcnt vmcnt(" #n ")" ::: "memory"); \
  SCHEDB(); }while(0)

// ---------------------------------------------------------------------------
// Persistent scan kernel. 168 WGs x 256 threads (no master).
// wg -> (pipe, lw): twins 8 apart (same XCD). lw 0..63: hidden tiles;
// lw 64..83: out-cell / ccA tiles. Wave w = (pair=w>>1 K-half, bt=(pipe<<1)+(w&1)).
// State frag layout (per buffer, 128KB): [btile(4)][ks(32)][bl(16)][kg(4)][8 bf16]
// LDS: 160KB weight chunks. Flags: bar + (pipe*128 + lw)*32 (128B lines).
// ---------------------------------------------------------------------------
__global__ __launch_bounds__(256, 1) void k_scan(
    const float* __restrict__ m_true,
    const u16* __restrict__ Wcell, const u16* __restrict__ Win_h,
    const u16* __restrict__ Win_x, const u16* __restrict__ Wout,
    const u16* __restrict__ WccA,
    const float* __restrict__ b_in, const float* __restrict__ b_cell,
    const float* __restrict__ cAb, const float* __restrict__ b_out,
    const float* __restrict__ b_cc,
    u16* hS, u16* cS, float* cF, float* outp, u32* bar)
{
  const int wg = blockIdx.x;
  const int tid = threadIdx.x;
  const int wave = tid >> 6, lane = tid & 63;

  int pipe, lw;
  if (wg < 160){ pipe = (wg >> 3) & 1; lw = ((wg >> 4) << 3) | (wg & 7); }
  else         { pipe = (wg - 160) >> 2; lw = 80 + ((wg - 160) & 3); }

  const int bl = lane & 15, kg = lane >> 4;
  const int pair = wave >> 1;               // K-half this wave owns
  const int bt = (pipe << 1) + (wave & 1);  // btile this wave owns
  const int b  = (bt << 4) + bl;
  const int swz = (bl & 7) << 4;
  const int foff = ((bl << 2) + kg) << 4;
  const int woff = (bt << 15) + ((lw >> 1) << 10) + (bl << 6) + ((lw & 1) << 5) + (kg << 3);
  u32* flagp = bar + (pipe*128 + lw)*32;
  const u32* fbase = bar + pipe*128*32;
  const int i2 = (lane < 20) ? 64 + lane : lane;   // poll coverage 0..83
  __shared__ __align__(16) u16 ldsW[81920];   // 160KB weight chunks

  f32x4 cprev = {0,0,0,0};   // cell WGs (wave<2): c carry cell3 -> in-cell
  f32x4 ccreg = {0,0,0,0};   // out  WGs (wave<2): cc carry ccA -> out

  auto stage1 = [&](const u16* src, u16* lb, int segs){
    const u16* g = src + (lane << 3);
    u16* l = lb;
    for (int s = 0; s < segs; ++s){
      __builtin_amdgcn_global_load_lds(
          (const __attribute__((address_space(1))) void*)g,
          (__attribute__((address_space(3))) void*)l, 16, 0, 0);
      g += 512; l += 512;
    }
    SCHEDB();
  };
  auto afL = [&](const u16* lb, int row, int kb) -> bf16x8 {
    return *(const bf16x8*)((const char*)lb + row*512 + (kb ^ swz));
  };

  // masterless barrier: flag bump + whole next-phase weight stage + direct poll
  auto gsync = [&](u32 ep, const u16* pfsrc, int cstride, int spw, const u16* xsrc){
    SCHEDB();
    __syncthreads();                  // per-wave vmcnt(0): state stores acked
    if (tid == 0)
      __hip_atomic_store(flagp, ep, __ATOMIC_RELAXED, __HIP_MEMORY_SCOPE_AGENT);
    SCHEDB();
    if (pfsrc) stage1(pfsrc + (size_t)wave*cstride, ldsW + wave*cstride, spw);
    if (xsrc)  stage1(xsrc + wave*4096, ldsW + 65536 + wave*4096, 8);
    SCHEDB();
    if (wave == 0){
      for(;;){
        u32 a = __hip_atomic_load(fbase + lane*32, __ATOMIC_RELAXED, __HIP_MEMORY_SCOPE_AGENT);
        u32 c2 = __hip_atomic_load(fbase + i2*32, __ATOMIC_RELAXED, __HIP_MEMORY_SCOPE_AGENT);
        if (__all(a >= ep && c2 >= ep)) break;
        __builtin_amdgcn_s_sleep(1);
      }
    }
    __syncthreads();                  // broadcast + drain weight stage
    SCHEDB();
  };

  // ---- in-cell phase (lw<64). entry: ch0..3 = Win_h, ch4 = Win_x part1 ----
  auto phase_incell = [&](int t, const u16* hIn, u16* hOut, u16* cOut){
    f32x4 A0={0,0,0,0}, A1={0,0,0,0}, A2={0,0,0,0}, A3={0,0,0,0};
    const char* hf = (const char*)hIn + (bt << 15) + foff;
    const int ksb = pair << 4;
    int jl = (kg << 2), jj = (lw << 4) + jl;
    FRAG sh[2][8], pa[8];
    f32x4 bg0, bg1, bg2, bg3;
    // counted issue: L1(8) L2(8) pa(8) bias(4) = 28
    #pragma unroll
    for (int ks = 0; ks < 8; ++ks) ld16sc(sh[0][ks], hf + (ksb + ks)*1024);
    #pragma unroll
    for (int ks = 0; ks < 8; ++ks) ld16sc(sh[1][ks], hf + (ksb + 8 + ks)*1024);
    {
      const char* p2 = (const char*)(Win_x + (size_t)lw*20480 + 16384);
      #pragma unroll
      for (int k2 = 0; k2 < 2; ++k2)
        #pragma unroll
        for (int rb = 0; rb < 4; ++rb)
          ld16(pa[k2*4+rb], p2 + (rb*16 + bl)*128 + (((k2<<6)+(kg<<4)) ^ swz));
    }
    ldf4(bg0, b_in +        jj);
    ldf4(bg1, b_in + 1024 + jj);
    ldf4(bg2, b_in + 2048 + jj);
    ldf4(bg3, b_in + 3072 + jj);
    WAITV(20);
    const u16* lbA = ldsW + (pair*2)*16384;
    #pragma unroll
    for (int ks = 0; ks < 8; ++ks){
      int kb = (ks << 6) + (kg << 4);
      FRAG a;
      a.v = afL(lbA, bl, kb);      A0 = MFMA16(a.v, sh[0][ks].v, A0);
      a.v = afL(lbA, 16 + bl, kb); A1 = MFMA16(a.v, sh[0][ks].v, A1);
      a.v = afL(lbA, 32 + bl, kb); A2 = MFMA16(a.v, sh[0][ks].v, A2);
      a.v = afL(lbA, 48 + bl, kb); A3 = MFMA16(a.v, sh[0][ks].v, A3);
    }
    WAITV(12);
    const u16* lbB = ldsW + (pair*2+1)*16384;
    #pragma unroll
    for (int ks = 0; ks < 8; ++ks){
      int kb = (ks << 6) + (kg << 4);
      FRAG a;
      a.v = afL(lbB, bl, kb);      A0 = MFMA16(a.v, sh[1][ks].v, A0);
      a.v = afL(lbB, 16 + bl, kb); A1 = MFMA16(a.v, sh[1][ks].v, A1);
      a.v = afL(lbB, 32 + bl, kb); A2 = MFMA16(a.v, sh[1][ks].v, A2);
      a.v = afL(lbB, 48 + bl, kb); A3 = MFMA16(a.v, sh[1][ks].v, A3);
    }
    WAITV(4);                               // pa landed (bias 4 outstanding)
    if (wave >= 2){                         // x contribution (pair B only)
      FRAG xf[10];
      const float* xr = m_true + (size_t)b*81920 + (size_t)(255 - t)*320;
      #pragma unroll
      for (int ks = 0; ks < 10; ++ks){
        int k = (ks << 5) + (kg << 3);
        f32x4 x0 = *(const f32x4*)(xr + k);
        f32x4 x1 = *(const f32x4*)(xr + k + 4);
        xf[ks].s[0]=f2bf(x0[0]); xf[ks].s[1]=f2bf(x0[1]); xf[ks].s[2]=f2bf(x0[2]); xf[ks].s[3]=f2bf(x0[3]);
        xf[ks].s[4]=f2bf(x1[0]); xf[ks].s[5]=f2bf(x1[1]); xf[ks].s[6]=f2bf(x1[2]); xf[ks].s[7]=f2bf(x1[3]);
      }
      const u16* lb4 = ldsW + 65536;
      #pragma unroll
      for (int ks = 0; ks < 8; ++ks){
        int kb = (ks << 6) + (kg << 4);
        FRAG a;
        a.v = afL(lb4, bl, kb);      A0 = MFMA16(a.v, xf[ks].v, A0);
        a.v = afL(lb4, 16 + bl, kb); A1 = MFMA16(a.v, xf[ks].v, A1);
        a.v = afL(lb4, 32 + bl, kb); A2 = MFMA16(a.v, xf[ks].v, A2);
        a.v = afL(lb4, 48 + bl, kb); A3 = MFMA16(a.v, xf[ks].v, A3);
      }
      #pragma unroll
      for (int k2 = 0; k2 < 2; ++k2){
        A0 = MFMA16(pa[k2*4+0].v, xf[8+k2].v, A0);
        A1 = MFMA16(pa[k2*4+1].v, xf[8+k2].v, A1);
        A2 = MFMA16(pa[k2*4+2].v, xf[8+k2].v, A2);
        A3 = MFMA16(pa[k2*4+3].v, xf[8+k2].v, A3);
      }
    }
    __syncthreads();                        // also drains bias/xf
    float* red = (float*)ldsW;
    if (wave >= 2){
      float* r = red + ((wave&1)*64 + lane)*20;
      *(f32x4*)(r+0) = A0; *(f32x4*)(r+4) = A1;
      *(f32x4*)(r+8) = A2; *(f32x4*)(r+12) = A3;
    }
    __syncthreads();
    if (wave < 2){
      const float* r = red + ((wave&1)*64 + lane)*20;
      A0 += *(const f32x4*)(r+0); A1 += *(const f32x4*)(r+4);
      A2 += *(const f32x4*)(r+8); A3 += *(const f32x4*)(r+12);
      P4 hw, cw;
      #pragma unroll
      for (int rr = 0; rr < 4; ++rr){
        float gi = A0[rr] + bg0[rr];
        float gf = A1[rr] + bg1[rr];
        float gg = A2[rr] + bg2[rr];
        float go = A3[rr] + bg3[rr];
        float cn = sigm(gf)*cprev[rr] + sigm(gi)*tanh_(gg);
        hw.s[rr] = f2bf(sigm(go)*tanh_(cn));
        cw.s[rr] = f2bf(cn);
      }
      ast((char*)hOut + woff, hw.q);
      ast((char*)cOut + woff, cw.q);
    }
  };

  // ---- inner cell phase i (lw<64). entry: ch0..3 = Wcell_i ----
  auto phase_cell = [&](int i, const u16* hIn, const u16* cIn, u16* hOut, u16* cOut, bool last){
    f32x4 A0={0,0,0,0}, A1={0,0,0,0}, A2={0,0,0,0}, A3={0,0,0,0}, A4={0,0,0,0};
    const char* hf  = (const char*)hIn + (bt << 15) + foff;
    const char* cfr = (const char*)cIn + (bt << 15) + foff;
    const int ksb = pair << 4;
    int jl = (kg << 2), jj = (lw << 4) + jl;
    FRAG sh[2][8], sc[2][8];
    f32x4 bg0, bg1, bg2, bg3, bca;
    // counted issue: L1(16) L2(16) bias(5) = 37
    #pragma unroll
    for (int ks = 0; ks < 8; ++ks) ld16sc(sh[0][ks], hf  + (ksb + ks)*1024);
    #pragma unroll
    for (int ks = 0; ks < 8; ++ks) ld16sc(sc[0][ks], cfr + (ksb + ks)*1024);
    #pragma unroll
    for (int ks = 0; ks < 8; ++ks) ld16sc(sh[1][ks], hf  + (ksb + 8 + ks)*1024);
    #pragma unroll
    for (int ks = 0; ks < 8; ++ks) ld16sc(sc[1][ks], cfr + (ksb + 8 + ks)*1024);
    ldf4(bg0, b_cell + i*4096 +        jj);
    ldf4(bg1, b_cell + i*4096 + 1024 + jj);
    ldf4(bg2, b_cell + i*4096 + 2048 + jj);
    ldf4(bg3, b_cell + i*4096 + 3072 + jj);
    ldf4(bca, cAb + i*1024 + jj);
    WAITV(21);
    const u16* lbA = ldsW + (pair*2)*20480;
    #pragma unroll
    for (int ks = 0; ks < 8; ++ks){
      int kb = (ks << 6) + (kg << 4);
      FRAG a;
      a.v = afL(lbA, bl, kb);      A0 = MFMA16(a.v, sh[0][ks].v, A0);
      a.v = afL(lbA, 16 + bl, kb); A1 = MFMA16(a.v, sh[0][ks].v, A1);
      a.v = afL(lbA, 32 + bl, kb); A2 = MFMA16(a.v, sh[0][ks].v, A2);
      a.v = afL(lbA, 48 + bl, kb); A3 = MFMA16(a.v, sh[0][ks].v, A3);
      a.v = afL(lbA, 64 + bl, kb); A4 = MFMA16(a.v, sc[0][ks].v, A4);
    }
    WAITV(5);
    const u16* lbB = ldsW + (pair*2+1)*20480;
    #pragma unroll
    for (int ks = 0; ks < 8; ++ks){
      int kb = (ks << 6) + (kg << 4);
      FRAG a;
      a.v = afL(lbB, bl, kb);      A0 = MFMA16(a.v, sh[1][ks].v, A0);
      a.v = afL(lbB, 16 + bl, kb); A1 = MFMA16(a.v, sh[1][ks].v, A1);
      a.v = afL(lbB, 32 + bl, kb); A2 = MFMA16(a.v, sh[1][ks].v, A2);
      a.v = afL(lbB, 48 + bl, kb); A3 = MFMA16(a.v, sh[1][ks].v, A3);
      a.v = afL(lbB, 64 + bl, kb); A4 = MFMA16(a.v, sc[1][ks].v, A4);
    }
    __syncthreads();
    float* red = (float*)ldsW;
    if (wave >= 2){
      float* r = red + ((wave&1)*64 + lane)*20;
      *(f32x4*)(r+0) = A0; *(f32x4*)(r+4) = A1;
      *(f32x4*)(r+8) = A2; *(f32x4*)(r+12) = A3; *(f32x4*)(r+16) = A4;
    }
    __syncthreads();
    if (wave < 2){
      const float* r = red + ((wave&1)*64 + lane)*20;
      A0 += *(const f32x4*)(r+0); A1 += *(const f32x4*)(r+4);
      A2 += *(const f32x4*)(r+8); A3 += *(const f32x4*)(r+12);
      A4 += *(const f32x4*)(r+16);
      P4 hw, cw; F4 cf4;
      #pragma unroll
      for (int rr = 0; rr < 4; ++rr){
        float gi = A0[rr] + bg0[rr];
        float gf = A1[rr] + bg1[rr];
        float gg = A2[rr] + bg2[rr];
        float go = A3[rr] + bg3[rr];
        float c1 = A4[rr] + bca[rr];
        float cn = sigm(gf)*c1 + sigm(gi)*tanh_(gg);
        hw.s[rr] = f2bf(sigm(go)*tanh_(cn));
        cw.s[rr] = f2bf(cn);
        cf4.f[rr] = cn;
      }
      ast((char*)hOut + woff, hw.q);
      ast((char*)cOut + woff, cw.q);
      if (last){ cprev[0]=cf4.f[0]; cprev[1]=cf4.f[1]; cprev[2]=cf4.f[2]; cprev[3]=cf4.f[3]; }
    }
  };

  // ---- ccA phase (lw 64..83, with cell i==3). entry: ch0..3 = WccA ----
  auto phase_ccA = [&](const u16* cIn){
    f32x4 A = {0,0,0,0};
    const char* cfr = (const char*)cIn + (bt << 15) + foff;
    const int ksb = pair << 4;
    int jl = (kg << 2), jjo = ((lw - 64) << 4) + jl;
    FRAG sc[2][8];
    f32x4 bcc;
    // counted issue: L1(8) L2(8) bcc(1) = 17
    #pragma unroll
    for (int ks = 0; ks < 8; ++ks) ld16sc(sc[0][ks], cfr + (ksb + ks)*1024);
    #pragma unroll
    for (int ks = 0; ks < 8; ++ks) ld16sc(sc[1][ks], cfr + (ksb + 8 + ks)*1024);
    ldf4(bcc, b_cc + jjo);
    WAITV(9);
    const u16* lbA = ldsW + (pair*2)*4096;
    #pragma unroll
    for (int ks = 0; ks < 8; ++ks){
      int kb = (ks << 6) + (kg << 4);
      FRAG a; a.v = afL(lbA, bl, kb);
      A = MFMA16(a.v, sc[0][ks].v, A);
    }
    WAITV(1);
    const u16* lbB = ldsW + (pair*2+1)*4096;
    #pragma unroll
    for (int ks = 0; ks < 8; ++ks){
      int kb = (ks << 6) + (kg << 4);
      FRAG a; a.v = afL(lbB, bl, kb);
      A = MFMA16(a.v, sc[1][ks].v, A);
    }
    __syncthreads();
    float* red = (float*)ldsW;
    if (wave >= 2) *(f32x4*)(red + ((wave&1)*64 + lane)*20) = A;
    __syncthreads();
    if (wave < 2){
      A += *(const f32x4*)(red + ((wave&1)*64 + lane)*20);
      #pragma unroll
      for (int rr = 0; rr < 4; ++rr) ccreg[rr] = A[rr] + bcc[rr];
    }
  };

  // ---- out-cell phase (lw 64..83). entry: ch0..3 = Wout ----
  auto phase_out = [&](int t, const u16* hIn){
    f32x4 A0={0,0,0,0}, A1={0,0,0,0}, A2={0,0,0,0}, A3={0,0,0,0};
    const char* hf = (const char*)hIn + (bt << 15) + foff;
    const int ksb = pair << 4;
    int jl = (kg << 2), jjo = ((lw - 64) << 4) + jl;
    FRAG sh[2][8];
    f32x4 bg0, bg1, bg2, bg3;
    // counted issue: L1(8) L2(8) bias(4) = 20
    #pragma unroll
    for (int ks = 0; ks < 8; ++ks) ld16sc(sh[0][ks], hf + (ksb + ks)*1024);
    #pragma unroll
    for (int ks = 0; ks < 8; ++ks) ld16sc(sh[1][ks], hf + (ksb + 8 + ks)*1024);
    ldf4(bg0, b_out +       jjo);
    ldf4(bg1, b_out + 320 + jjo);
    ldf4(bg2, b_out + 640 + jjo);
    ldf4(bg3, b_out + 960 + jjo);
    WAITV(12);
    const u16* lbA = ldsW + (pair*2)*16384;
    #pragma unroll
    for (int ks = 0; ks < 8; ++ks){
      int kb = (ks << 6) + (kg << 4);
      FRAG a;
      a.v = afL(lbA, bl, kb);      A0 = MFMA16(a.v, sh[0][ks].v, A0);
      a.v = afL(lbA, 16 + bl, kb); A1 = MFMA16(a.v, sh[0][ks].v, A1);
      a.v = afL(lbA, 32 + bl, kb); A2 = MFMA16(a.v, sh[0][ks].v, A2);
      a.v = afL(lbA, 48 + bl, kb); A3 = MFMA16(a.v, sh[0][ks].v, A3);
    }
    WAITV(4);
    const u16* lbB = ldsW + (pair*2+1)*16384;
    #pragma unroll
    for (int ks = 0; ks < 8; ++ks){
      int kb = (ks << 6) + (kg << 4);
      FRAG a;
      a.v = afL(lbB, bl, kb);      A0 = MFMA16(a.v, sh[1][ks].v, A0);
      a.v = afL(lbB, 16 + bl, kb); A1 = MFMA16(a.v, sh[1][ks].v, A1);
      a.v = afL(lbB, 32 + bl, kb); A2 = MFMA16(a.v, sh[1][ks].v, A2);
      a.v = afL(lbB, 48 + bl, kb); A3 = MFMA16(a.v, sh[1][ks].v, A3);
    }
    __syncthreads();
    float* red = (float*)ldsW;
    if (wave >= 2){
      float* r = red + ((wave&1)*64 + lane)*20;
      *(f32x4*)(r+0) = A0; *(f32x4*)(r+4) = A1;
      *(f32x4*)(r+8) = A2; *(f32x4*)(r+12) = A3;
    }
    __syncthreads();
    if (wave < 2){
      const float* r = red + ((wave&1)*64 + lane)*20;
      A0 += *(const f32x4*)(r+0); A1 += *(const f32x4*)(r+4);
      A2 += *(const f32x4*)(r+8); A3 += *(const f32x4*)(r+12);
      f32x4 ho;
      #pragma unroll
      for (int rr = 0; rr < 4; ++rr){
        float gi = A0[rr] + bg0[rr];
        float gf = A1[rr] + bg1[rr];
        float gg = A2[rr] + bg2[rr];
        float go = A3[rr] + bg3[rr];
        float cn = sigm(gf)*ccreg[rr] + sigm(gi)*tanh_(gg);
        ho[rr] = sigm(go)*tanh_(cn);
      }
      *(f32x4*)(outp + (size_t)b*81920 + (size_t)(t+1)*320 + jjo) = ho;
    }
  };

  // ---- init: cprev from cF (written by k_dense), first incell weights ----
  if (lw < 64){
    if (wave < 2){
      int jj = (lw << 4) + (kg << 2);
      cprev = *(const f32x4*)(cF + (size_t)b*1024 + jj);
    }
    stage1(Win_h + ((size_t)lw << 16) + wave*16384, ldsW + wave*16384, 32);
    stage1(Win_x + (size_t)lw*20480 + wave*4096, ldsW + 65536 + wave*4096, 8);
  }
  __syncthreads();
  SCHEDB();

  u16* hB0 = hS;        u16* hB1 = hS + 65536;
  u16* cB0 = cS;        u16* cB1 = cS + 65536;

  u32 ep = 1;
  if (lw < 64) phase_incell(0, hB1, hB0, cB0);
  gsync(ep++, (lw < 64) ? Wcell + (size_t)lw*81920 : nullptr, 20480, 40, nullptr);
  int p = 1;
  #pragma unroll 1
  for (int t = 0; t < 255; ++t){
    #pragma unroll 1
    for (int i = 0; i < 4; ++i){
      u16* hIn = (p & 1) ? hB0 : hB1;  u16* cIn = (p & 1) ? cB0 : cB1;
      u16* hOut = (p & 1) ? hB1 : hB0; u16* cOut = (p & 1) ? cB1 : cB0;
      if (lw < 64)      phase_cell(i, hIn, cIn, hOut, cOut, i == 3);
      else if (i == 3)  phase_ccA(cIn);
      const u16* pf = nullptr; const u16* xs = nullptr; int cstride = 0, spw = 0;
      if (lw < 64){
        if (i < 3){ pf = Wcell + (size_t)((i+1)*64 + lw)*81920; cstride = 20480; spw = 40; }
        else      { pf = Win_h + ((size_t)lw << 16); cstride = 16384; spw = 32;
                    xs = Win_x + (size_t)lw*20480; }
      } else {
        if (i == 2){ pf = WccA + ((size_t)(lw-64) << 14); cstride = 4096; spw = 8; }
        else if (i == 3){ pf = Wout + ((size_t)(lw-64) << 16); cstride = 16384; spw = 32; }
      }
      gsync(ep++, pf, cstride, spw, xs);
      ++p;
    }
    u16* hIn = (p & 1) ? hB0 : hB1;
    u16* hOut = (p & 1) ? hB1 : hB0; u16* cOut = (p & 1) ? cB1 : cB0;
    if (lw >= 64)       phase_out(t, hIn);
    else if (t < 254)   phase_incell(t + 1, hIn, hOut, cOut);
    gsync(ep++, (lw < 64 && t < 254) ? Wcell + (size_t)lw*81920 : nullptr, 20480, 40, nullptr);
    ++p;
  }
}

// ---------------------------------------------------------------------------
// Precompute kernels (unchanged)
// ---------------------------------------------------------------------------

__global__ __launch_bounds__(256) void k_dense(const float* __restrict__ X, int xmode,
    const float* __restrict__ W, const float* __restrict__ bias,
    int OD, int ID, int act, int omode, float* outF, u16* outB)
{
  int o = blockIdx.x*4 + (threadIdx.x >> 6);
  if (o >= OD) return;
  int lane = threadIdx.x & 63;
  const float* wr = W + (size_t)o*ID;
  float acc = 0.f;
  if (xmode == 0){ for (int k = 0; k < ID; ++k) acc = fmaf(wr[k], X[(size_t)lane*ID + k], acc); }
  else           { for (int k = 0; k < ID; ++k) acc = fmaf(wr[k], X[(size_t)k*64 + lane], acc); }
  acc += bias[o];
  if (act) acc = acc * sigm(acc);
  if (omode == 0)      outF[(size_t)o*64 + lane] = acc;
  else if (omode == 1){
    int bt = lane >> 4, blx = lane & 15;
    outB[(size_t)bt*16384 + (size_t)(o>>5)*512 + blx*32 + ((o&31)>>3)*8 + (o&7)] = f2bf(acc);
  }
  else if (omode == 2) outF[(size_t)lane*1024 + o] = acc;
  else                 outF[(size_t)lane*81920 + 256 + o] = acc;
}

__global__ void k_zero0(float* out){ out[(size_t)blockIdx.x*81920 + threadIdx.x] = 0.f; }

__global__ __launch_bounds__(256) void k_tr(const float* __restrict__ in, u16* __restrict__ out, int M, int N){
  __shared__ u16 t[64][65];
  int m0 = blockIdx.x << 6, n0 = blockIdx.y << 6;
  int c = threadIdx.x & 63, rq = threadIdx.x >> 6;
  for (int rr = 0; rr < 16; ++rr){
    int r = (rq << 4) + rr;
    t[r][c] = f2bf(in[(size_t)(m0 + r)*N + n0 + c]);
  }
  __syncthreads();
  for (int rr = 0; rr < 16; ++rr){
    int r = (rq << 4) + rr;
    out[(size_t)(n0 + r)*M + m0 + c] = t[c][r];
  }
}

__global__ __launch_bounds__(256) void k_fuse(const float* __restrict__ Whh, const float* __restrict__ Wih,
    const u16* __restrict__ BT, int KM, int mode, u16* __restrict__ dst)
{
  int bx = blockIdx.x, by = blockIdx.y, bz = blockIdx.z;
  int lane = threadIdx.x & 63, wv = threadIdx.x >> 6;
  int bl = lane & 15, kg = lane >> 4;
  int jbase = (mode == 0) ? bz*1024 : ((mode == 1) ? bz*320 : 0);
  int jrow = jbase + bx*16 + bl;
  int k2c = by*64 + wv*16 + bl;
  f32x4 acc = {0,0,0,0};
  for (int m0 = 0; m0 < KM; m0 += 32){
    f32x4 wa0 = *(const f32x4*)(Whh + (size_t)jrow*KM + m0 + (kg << 3));
    f32x4 wa1 = *(const f32x4*)(Whh + (size_t)jrow*KM + m0 + (kg << 3) + 4);
    FRAG a;
    a.s[0]=f2bf(wa0[0]); a.s[1]=f2bf(wa0[1]); a.s[2]=f2bf(wa0[2]); a.s[3]=f2bf(wa0[3]);
    a.s[4]=f2bf(wa1[0]); a.s[5]=f2bf(wa1[1]); a.s[6]=f2bf(wa1[2]); a.s[7]=f2bf(wa1[3]);
    FRAG bb; bb.v = *(const bf16x8*)(BT + (size_t)k2c*KM + m0 + (kg << 3));
    acc = MFMA16(a.v, bb.v, acc);
  }
  #pragma unroll
  for (int r = 0; r < 4; ++r){
    int jl = (kg << 2) + r;
    int jg = jbase + bx*16 + jl;
    float v = acc[r];
    if (mode < 2) v += Wih[(size_t)jg*1024 + k2c];
    int re = (mode == 2) ? jl : (bz*16 + jl);
    int c = k2c >> 8, kl = k2c & 255;
    size_t pos;
    if (mode == 0)      pos = (size_t)bx*81920 + c*20480 + re*256 + (kl ^ ((re&7)<<3));
    else if (mode == 1) pos = (size_t)bx*65536 + c*16384 + re*256 + (kl ^ ((re&7)<<3));
    else                pos = (size_t)bx*16384 + c*4096  + re*256 + (kl ^ ((re&7)<<3));
    dst[pos] = f2bf(v);
  }
}

__global__ void k_pack_winh(const float* __restrict__ src, u16* __restrict__ dst){
  int id = blockIdx.x*256 + threadIdx.x;
  int j = id >> 10, k = id & 1023;
  int g = j >> 10, jj = j & 1023;
  int w = jj >> 4, r = (g << 4) + (jj & 15);
  int c = k >> 8, kl = k & 255;
  dst[(size_t)w*65536 + c*16384 + r*256 + (kl ^ ((r&7)<<3))] = f2bf(src[id]);
}

__global__ void k_pack_winx(const float* __restrict__ src, u16* __restrict__ dst){
  int j = blockIdx.x, k = threadIdx.x;
  int g = j >> 10, jj = j & 1023;
  int w = jj >> 4, r = (g << 4) + (jj & 15);
  float v = src[(size_t)j*320 + k];
  size_t pos;
  if (k < 256) pos = (size_t)w*20480 + r*256 + (k ^ ((r&7)<<3));
  else         pos = (size_t)w*20480 + 16384 + r*64 + ((k - 256) ^ ((r&7)<<3));
  dst[pos] = f2bf(v);
}

__global__ void k_pack_ca(const float* __restrict__ src, u16* __restrict__ dst){
  int id = blockIdx.x*256 + threadIdx.x;
  int jj = id >> 10, k = id & 1023;
  int w = jj >> 4, r = 64 + (jj & 15);
  int c = k >> 8, kl = k & 255;
  dst[(size_t)w*81920 + c*20480 + r*256 + (kl ^ ((r&7)<<3))] = f2bf(src[id]);
}

__global__ __launch_bounds__(256) void k_bias(const float* __restrict__ A, const float* __restrict__ x,
    const float* __restrict__ a1, const float* __restrict__ a2, float* __restrict__ o, int NJ, int K)
{
  int j = blockIdx.x*4 + (threadIdx.x >> 6);
  if (j >= NJ) return;
  int lane = threadIdx.x & 63;
  float acc = 0.f;
  if (A) for (int k = lane; k < K; k += 64) acc += A[(size_t)j*K + k]*x[k];
  for (int off = 32; off; off >>= 1) acc += __shfl_down(acc, off);
  if (lane == 0) o[j] = acc + (a1 ? a1[j] : 0.f) + (a2 ? a2[j] : 0.f);
}

// ---------------------------------------------------------------------------
extern "C" void kernel_launch(void* const* d_in, const int* in_sizes, int n_in,
                              void* d_out, int out_size, void* d_ws, size_t ws_size,
                              hipStream_t stream)
{
  (void)in_sizes; (void)n_in; (void)out_size;
  const float* z      = (const float*)d_in[0];
  const float* m_true = (const float*)d_in[1];
  const float* eh_W1=(const float*)d_in[2],  *eh_b1=(const float*)d_in[3];
  const float* eh_W2=(const float*)d_in[4],  *eh_b2=(const float*)d_in[5];
  const float* eh_W3=(const float*)d_in[6],  *eh_b3=(const float*)d_in[7];
  const float* ec_W1=(const float*)d_in[8],  *ec_b1=(const float*)d_in[9];
  const float* ec_W2=(const float*)d_in[10], *ec_b2=(const float*)d_in[11];
  const float* ec_W3=(const float*)d_in[12], *ec_b3=(const float*)d_in[13];
  const float* ex_W1=(const float*)d_in[14], *ex_b1=(const float*)d_in[15];
  const float* ex_W2=(const float*)d_in[16], *ex_b2=(const float*)d_in[17];
  const float* ex_W3=(const float*)d_in[18], *ex_b3=(const float*)d_in[19];
  const float* in_Wih=(const float*)d_in[20], *in_Whh=(const float*)d_in[21];
  const float* in_bih=(const float*)d_in[22], *in_bhh=(const float*)d_in[23];
  const float* r_Wih=(const float*)d_in[24],  *r_Whh=(const float*)d_in[25];
  const float* r_bih=(const float*)d_in[26],  *r_bhh=(const float*)d_in[27];
  const float* hA_W=(const float*)d_in[28],   *hA_b=(const float*)d_in[29];
  const float* cA_W=(const float*)d_in[30],   *cA_b=(const float*)d_in[31];
  const float* lastH_W=(const float*)d_in[32], *lastH_b=(const float*)d_in[33];
  const float* lastC_W=(const float*)d_in[34], *lastC_b=(const float*)d_in[35];
  const float* out_Wih=(const float*)d_in[36], *out_Whh=(const float*)d_in[37];
  const float* out_bih=(const float*)d_in[38], *out_bhh=(const float*)d_in[39];
  float* out = (float*)d_out;

  char* wsb = (char*)d_ws;
  size_t off = 0;
  auto alloc = [&](size_t bytes)->char*{
    char* p = wsb + off; off = (off + bytes + 255) & ~(size_t)255; return p;
  };
  u32* bar    = (u32*)alloc(256*32*4);
  u16* hS     = (u16*)alloc(2*64*1024*2);
  u16* cS     = (u16*)alloc(2*64*1024*2);
  float* cF   = (float*)alloc(64*1024*4);
  float* b_in = (float*)alloc(4096*4);
  float* b_cell=(float*)alloc(4*4096*4);
  float* b_out= (float*)alloc(1280*4);
  float* b_cc = (float*)alloc(320*4);
  float* t1   = (float*)alloc(1024*64*4);
  float* t2   = (float*)alloc(1024*64*4);
  u16* Tbuf   = (u16*)alloc((size_t)1024*1024*2);
  u16* Win_h  = (u16*)alloc((size_t)64*65536*2);
  u16* Win_x  = (u16*)alloc((size_t)64*20480*2);
  u16* Wcell  = (u16*)alloc((size_t)4*64*81920*2);
  u16* Wout   = (u16*)alloc((size_t)20*65536*2);
  u16* WccA   = (u16*)alloc((size_t)20*16384*2);
  if (off > ws_size) return;

  hipMemsetAsync(bar, 0, 256*32*4, stream);

  k_dense<<<256,256,0,stream>>>(z, 0, eh_W1, eh_b1, 1024, 256, 1, 0, t1, nullptr);
  k_dense<<<256,256,0,stream>>>(t1,1, eh_W2, eh_b2, 1024,1024, 1, 0, t2, nullptr);
  k_dense<<<256,256,0,stream>>>(t2,1, eh_W3, eh_b3, 1024,1024, 0, 1, nullptr, hS + 65536);
  k_dense<<<256,256,0,stream>>>(z, 0, ec_W1, ec_b1, 1024, 256, 1, 0, t1, nullptr);
  k_dense<<<256,256,0,stream>>>(t1,1, ec_W2, ec_b2, 1024,1024, 1, 0, t2, nullptr);
  k_dense<<<256,256,0,stream>>>(t2,1, ec_W3, ec_b3, 1024,1024, 0, 2, cF, nullptr);
  k_dense<<<256,256,0,stream>>>(z, 0, ex_W1, ex_b1, 1024, 256, 1, 0, t1, nullptr);
  k_dense<<<256,256,0,stream>>>(t1,1, ex_W2, ex_b2, 1024,1024, 1, 0, t2, nullptr);
  k_dense<<<16 ,256,0,stream>>>(t2,1, ex_W3, ex_b3,   64,1024, 0, 3, out, nullptr);
  k_zero0<<<64,256,0,stream>>>(out);

  k_pack_winh<<<16384,256,0,stream>>>(in_Whh, Win_h);
  k_pack_winx<<<4096,320,0,stream>>>(in_Wih, Win_x);
  for (int i = 0; i < 4; ++i)
    k_pack_ca<<<4096,256,0,stream>>>(cA_W + (size_t)i*1024*1024, Wcell + (size_t)i*64*81920);

  for (int i = 0; i < 4; ++i){
    k_tr<<<dim3(16,16),256,0,stream>>>(hA_W + (size_t)i*1024*1024, Tbuf, 1024, 1024);
    k_fuse<<<dim3(64,16,4),256,0,stream>>>(r_Whh + (size_t)i*4096*1024,
                                           r_Wih + (size_t)i*4096*1024,
                                           Tbuf, 1024, 0, Wcell + (size_t)i*64*81920);
  }
  k_tr<<<dim3(5,16),256,0,stream>>>(lastH_W, Tbuf, 320, 1024);
  k_fuse<<<dim3(20,16,4),256,0,stream>>>(out_Whh, out_Wih, Tbuf, 320, 1, Wout);
  k_tr<<<dim3(16,16),256,0,stream>>>(cA_W + (size_t)3*1024*1024, Tbuf, 1024, 1024);
  k_fuse<<<dim3(20,16,1),256,0,stream>>>(lastC_W, nullptr, Tbuf, 1024, 2, WccA);

  k_bias<<<1024,256,0,stream>>>(nullptr, nullptr, in_bih, in_bhh, b_in, 4096, 0);
  for (int i = 0; i < 4; ++i)
    k_bias<<<1024,256,0,stream>>>(r_Whh + (size_t)i*4096*1024, hA_b + i*1024,
                                  r_bih + i*4096, r_bhh + i*4096, b_cell + i*4096, 4096, 1024);
  k_bias<<<320,256,0,stream>>>(out_Whh, lastH_b, out_bih, out_bhh, b_out, 1280, 320);
  k_bias<<<80 ,256,0,stream>>>(lastC_W, cA_b + 3*1024, lastC_b, nullptr, b_cc, 320, 1024);

  k_scan<<<NWG,256,0,stream>>>(m_true, Wcell, Win_h, Win_x, Wout, WccA,
                               b_in, b_cell, cA_b, b_out, b_cc,
                               hS, cS, cF, out, bar);
}